// Round 1
// baseline (12522.910 us; speedup 1.0000x reference)
//
#include <hip/hip_runtime.h>
#include <cstdint>
#include <cstddef>

namespace {

constexpr int B_ = 4;
constexpr int N0 = 4096;   // vertices per batch
constexpr int N1 = 1024;   // after pool1
constexpr int N2 = 256;    // after pool2

// ---------------------------------------------------------------- KNN ------
// One thread per query point. Candidates staged through LDS tiles. Per-thread
// sorted top-K kept in registers (all indices static via full unroll).
// Self is excluded by candidate index == self index (matches ref's drop-first
// since self distance ~0 is always rank-0). Strict '<' everywhere -> ties
// break to lower index, matching lax.top_k.
template<int K, int TILE>
__global__ void knn_kernel(const float* __restrict__ pts,   // (B, C, 3) candidates
                           const int*   __restrict__ qidx,  // Q indices into C, or null (query q = cand q)
                           int Q, int C,
                           int* __restrict__ out)           // (B, Q, K)
{
  __shared__ float sx[TILE], sy[TILE], sz[TILE];
  const int b = blockIdx.y;
  const int q = blockIdx.x * blockDim.x + threadIdx.x;   // Q % blockDim == 0
  const int self = qidx ? qidx[q] : q;
  const float* pb = pts + (size_t)b * C * 3;
  const float qx = pb[self * 3 + 0];
  const float qy = pb[self * 3 + 1];
  const float qz = pb[self * 3 + 2];

  float nd[K]; int ni[K];
#pragma unroll
  for (int j = 0; j < K; ++j) { nd[j] = INFINITY; ni[j] = 0; }

  for (int t0 = 0; t0 < C; t0 += TILE) {
    const int nt = (C - t0 < TILE) ? (C - t0) : TILE;
    for (int i = threadIdx.x; i < nt; i += blockDim.x) {
      sx[i] = pb[(t0 + i) * 3 + 0];
      sy[i] = pb[(t0 + i) * 3 + 1];
      sz[i] = pb[(t0 + i) * 3 + 2];
    }
    __syncthreads();
    for (int i = 0; i < nt; ++i) {
      const float dx = qx - sx[i], dy = qy - sy[i], dz = qz - sz[i];
      const float d = dx * dx + dy * dy + dz * dz;
      const int idx = t0 + i;
      if (d < nd[K - 1] && idx != self) {
        nd[K - 1] = d; ni[K - 1] = idx;
#pragma unroll
        for (int j = K - 1; j > 0; --j) {
          if (nd[j] < nd[j - 1]) {
            float td = nd[j]; nd[j] = nd[j - 1]; nd[j - 1] = td;
            int   ti = ni[j]; ni[j] = ni[j - 1]; ni[j - 1] = ti;
          }
        }
      }
    }
    __syncthreads();
  }
  int* o = out + ((size_t)b * Q + q) * K;
#pragma unroll
  for (int j = 0; j < K; ++j) o[j] = ni[j];
}

// ------------------------------------------------------------- nearest -----
__global__ void nearest_kernel(const float* __restrict__ qpts,  // (B, Q, 3)
                               const float* __restrict__ cpts,  // (B, C, 3)
                               int Q, int C, int* __restrict__ out) // (B, Q)
{
  const int i = blockIdx.x * blockDim.x + threadIdx.x;
  if (i >= B_ * Q) return;
  const int b = i / Q;
  const float qx = qpts[(size_t)i * 3 + 0];
  const float qy = qpts[(size_t)i * 3 + 1];
  const float qz = qpts[(size_t)i * 3 + 2];
  const float* cb = cpts + (size_t)b * C * 3;
  float best = INFINITY; int bi = 0;
  for (int j = 0; j < C; ++j) {
    const float dx = qx - cb[j * 3 + 0];
    const float dy = qy - cb[j * 3 + 1];
    const float dz = qz - cb[j * 3 + 2];
    const float d = dx * dx + dy * dy + dz * dz;
    if (d < best) { best = d; bi = j; }
  }
  out[i] = bi;
}

// -------------------------------------------------------- conv_surface -----
// out[b,v,o] = relu( max_n relu( dot(unit(nbr_n - v), unit(dir[:,o])) ) )
__global__ void conv_surface_kernel(const float* __restrict__ verts, // (B, V, 3)
                                    const int*   __restrict__ nb,    // (B, V, 32)
                                    const float* __restrict__ dir,   // (3, C)
                                    int V, int C, float* __restrict__ out) // (B,V,C)
{
  __shared__ float ux[32], uy[32], uz[32];
  const int bv = blockIdx.x;
  const int b = bv / V;
  const int v = bv - b * V;
  const float* vb = verts + (size_t)b * V * 3;
  if (threadIdx.x < 32) {
    const float cx = vb[v * 3 + 0], cy = vb[v * 3 + 1], cz = vb[v * 3 + 2];
    const int nidx = nb[(size_t)bv * 32 + threadIdx.x];
    const float dx = vb[nidx * 3 + 0] - cx;
    const float dy = vb[nidx * 3 + 1] - cy;
    const float dz = vb[nidx * 3 + 2] - cz;
    const float rn = 1.0f / fmaxf(sqrtf(dx * dx + dy * dy + dz * dz), 1e-12f);
    ux[threadIdx.x] = dx * rn; uy[threadIdx.x] = dy * rn; uz[threadIdx.x] = dz * rn;
  }
  __syncthreads();
  const int o = threadIdx.x;
  float d0 = dir[o], d1 = dir[C + o], d2 = dir[2 * C + o];
  const float rn = 1.0f / fmaxf(sqrtf(d0 * d0 + d1 * d1 + d2 * d2), 1e-12f);
  d0 *= rn; d1 *= rn; d2 *= rn;
  float m = -INFINITY;
#pragma unroll
  for (int n = 0; n < 32; ++n) {
    const float t = fmaxf(0.0f, fmaf(d2, uz[n], fmaf(d1, uy[n], d0 * ux[n])));
    m = fmaxf(m, t);
  }
  out[(size_t)bv * C + o] = fmaxf(0.0f, m);
}

// -------------------------------------------------------- conv_combine -----
// out[b,v,o] = act( f[b,v,o] + max_n( theta[n,o] * f[b, nb[n], C+o] ) )
__global__ void conv_combine_kernel(const float* __restrict__ f,     // (B, V, 2C)
                                    const int*   __restrict__ nb,    // (B, V, 32)
                                    const float* __restrict__ dir,   // (3, C)
                                    const float* __restrict__ verts, // (B, V, 3)
                                    int V, int C, int relu,
                                    float* __restrict__ out)         // (B, V, C)
{
  __shared__ float ux[32], uy[32], uz[32];
  __shared__ int snb[32];
  const int bv = blockIdx.x;
  const int b = bv / V;
  const int v = bv - b * V;
  const float* vb = verts + (size_t)b * V * 3;
  if (threadIdx.x < 32) {
    const float cx = vb[v * 3 + 0], cy = vb[v * 3 + 1], cz = vb[v * 3 + 2];
    const int nidx = nb[(size_t)bv * 32 + threadIdx.x];
    snb[threadIdx.x] = nidx;
    const float dx = vb[nidx * 3 + 0] - cx;
    const float dy = vb[nidx * 3 + 1] - cy;
    const float dz = vb[nidx * 3 + 2] - cz;
    const float rn = 1.0f / fmaxf(sqrtf(dx * dx + dy * dy + dz * dz), 1e-12f);
    ux[threadIdx.x] = dx * rn; uy[threadIdx.x] = dy * rn; uz[threadIdx.x] = dz * rn;
  }
  __syncthreads();
  const int o = threadIdx.x;
  float d0 = dir[o], d1 = dir[C + o], d2 = dir[2 * C + o];
  const float rn = 1.0f / fmaxf(sqrtf(d0 * d0 + d1 * d1 + d2 * d2), 1e-12f);
  d0 *= rn; d1 *= rn; d2 *= rn;
  const float* fb = f + (size_t)b * V * 2 * C;
  float m = -INFINITY;
#pragma unroll 8
  for (int n = 0; n < 32; ++n) {
    const float t = fmaxf(0.0f, fmaf(d2, uz[n], fmaf(d1, uy[n], d0 * ux[n])));
    const float s = fb[(size_t)snb[n] * 2 * C + C + o];
    m = fmaxf(m, t * s);
  }
  const float r = fb[(size_t)v * 2 * C + o] + m;
  out[(size_t)bv * C + o] = relu ? fmaxf(r, 0.0f) : r;
}

// ---------------------------------------------------------------- pool -----
__global__ void pool_kernel(const float* __restrict__ fm,  // (B, Vsrc, C)
                            const int*   __restrict__ nbp, // (B, Q, 4)
                            int Q, int Vsrc, int C, float* __restrict__ out) // (B,Q,C)
{
  const int i = blockIdx.x * blockDim.x + threadIdx.x;
  if (i >= B_ * Q * C) return;
  const int c = i % C;
  const int q = (i / C) % Q;
  const int b = i / (C * Q);
  const int* nn = nbp + ((size_t)b * Q + q) * 4;
  const float* fb = fm + (size_t)b * Vsrc * C;
  const float m = fmaxf(fmaxf(fb[(size_t)nn[0] * C + c], fb[(size_t)nn[1] * C + c]),
                        fmaxf(fb[(size_t)nn[2] * C + c], fb[(size_t)nn[3] * C + c]));
  out[i] = m;
}

__global__ void gather_verts_kernel(const float* __restrict__ src, // (B, Vsrc, 3)
                                    const int* __restrict__ idx,   // (Q,)
                                    int Vsrc, int Q, float* __restrict__ dst) // (B,Q,3)
{
  const int i = blockIdx.x * blockDim.x + threadIdx.x;
  if (i >= B_ * Q * 3) return;
  const int c = i % 3;
  const int q = (i / 3) % Q;
  const int b = i / (3 * Q);
  dst[i] = src[((size_t)b * Vsrc + idx[q]) * 3 + c];
}

__global__ void global_max_kernel(const float* __restrict__ fm4, // (B, 256, 512)
                                  float* __restrict__ out)       // (B, 512)
{
  const int i = blockIdx.x * blockDim.x + threadIdx.x;
  if (i >= B_ * 512) return;
  const int c = i % 512;
  const int b = i / 512;
  const float* p = fm4 + (size_t)b * 256 * 512 + c;
  float m = -INFINITY;
  for (int v = 0; v < 256; ++v) m = fmaxf(m, p[(size_t)v * 512]);
  out[i] = m;
}

// ---------------------------------------------------------------- GEMM -----
// C[m,n] = sum_k A[m,k] * B[k,n]  (BT: B stored (N,K) row-major, i.e. B[n,k])
// 64x64 block tile, 256 threads, 4x4 per thread, K-tile 16. Dims must be
// multiples of (64, 64, 16) -- true for every call here.
template<bool BT, bool RELU, bool BIAS>
__global__ void gemm_kernel(const float* __restrict__ A,
                            const float* __restrict__ Bm,
                            const float* __restrict__ bias,
                            int M, int Nn, int K,
                            float* __restrict__ Cout)
{
  __shared__ float As[16 * 65];
  __shared__ float Bs[16 * 65];
  const int tid = threadIdx.x;
  const int tx = tid % 16, ty = tid / 16;
  const int m0 = blockIdx.y * 64, n0 = blockIdx.x * 64;
  float acc[4][4] = {};
  for (int k0 = 0; k0 < K; k0 += 16) {
#pragma unroll
    for (int i = 0; i < 4; ++i) {
      const int idx = tid + i * 256;
      const int kk = idx % 16, mm = idx / 16;
      As[kk * 65 + mm] = A[(size_t)(m0 + mm) * K + k0 + kk];
    }
#pragma unroll
    for (int i = 0; i < 4; ++i) {
      const int idx = tid + i * 256;
      if (BT) {
        const int kk = idx % 16, nn = idx / 16;
        Bs[kk * 65 + nn] = Bm[(size_t)(n0 + nn) * K + k0 + kk];
      } else {
        const int nn = idx % 64, kk = idx / 64;
        Bs[kk * 65 + nn] = Bm[(size_t)(k0 + kk) * Nn + n0 + nn];
      }
    }
    __syncthreads();
#pragma unroll
    for (int kk = 0; kk < 16; ++kk) {
      float a[4], bb[4];
#pragma unroll
      for (int i = 0; i < 4; ++i) a[i] = As[kk * 65 + ty + 16 * i];
#pragma unroll
      for (int j = 0; j < 4; ++j) bb[j] = Bs[kk * 65 + tx + 16 * j];
#pragma unroll
      for (int i = 0; i < 4; ++i)
#pragma unroll
        for (int j = 0; j < 4; ++j) acc[i][j] = fmaf(a[i], bb[j], acc[i][j]);
    }
    __syncthreads();
  }
#pragma unroll
  for (int i = 0; i < 4; ++i) {
    const int m = m0 + ty + 16 * i;
#pragma unroll
    for (int j = 0; j < 4; ++j) {
      const int n = n0 + tx + 16 * j;
      float r = acc[i][j];
      if (BIAS) r += bias[n];
      if (RELU) r = fmaxf(r, 0.0f);
      Cout[(size_t)m * Nn + n] = r;
    }
  }
}

// GEMM1 of the head MLP with the 1792-channel fuse gathered on the fly.
// h1[m, n] = relu( sum_c fuse[m, c] * cw1[n, c] + cb1[n] ),  m = b*4096 + v
// fuse segments: [0,128) fm0 | [128,256) fm1 | [256,512) fm2[near1]
//                [512,768) fm3[near1] | [768,1280) fm4[near2] | [1280,1792) fglob
__global__ void gemm_fuse_kernel(const float* __restrict__ fm0,
                                 const float* __restrict__ fm1,
                                 const float* __restrict__ fm2,
                                 const float* __restrict__ fm3,
                                 const float* __restrict__ fm4,
                                 const float* __restrict__ fglob,
                                 const int*   __restrict__ near1,
                                 const int*   __restrict__ near2,
                                 const float* __restrict__ Bm,   // cw1 (512, 1792)
                                 const float* __restrict__ bias, // cb1 (512,)
                                 float* __restrict__ Cout)       // (16384, 512)
{
  constexpr int K = 1792, Nn = 512;
  __shared__ float As[16 * 65];
  __shared__ float Bs[16 * 65];
  const int tid = threadIdx.x;
  const int tx = tid % 16, ty = tid / 16;
  const int m0 = blockIdx.y * 64, n0 = blockIdx.x * 64;
  float acc[4][4] = {};
  for (int k0 = 0; k0 < K; k0 += 16) {
#pragma unroll
    for (int i = 0; i < 4; ++i) {
      const int idx = tid + i * 256;
      const int kk = idx % 16, mm = idx / 16;
      const int m = m0 + mm;
      const int b = m >> 12;              // / 4096
      const int k = k0 + kk;
      float val;
      if (k < 128)       val = fm0[(size_t)m * 128 + k];
      else if (k < 256)  val = fm1[(size_t)m * 128 + (k - 128)];
      else if (k < 512)  val = fm2[((size_t)b * 1024 + near1[m]) * 256 + (k - 256)];
      else if (k < 768)  val = fm3[((size_t)b * 1024 + near1[m]) * 256 + (k - 512)];
      else if (k < 1280) val = fm4[((size_t)b * 256 + near2[m]) * 512 + (k - 768)];
      else               val = fglob[(size_t)b * 512 + (k - 1280)];
      As[kk * 65 + mm] = val;
    }
#pragma unroll
    for (int i = 0; i < 4; ++i) {
      const int idx = tid + i * 256;
      const int kk = idx % 16, nn = idx / 16;
      Bs[kk * 65 + nn] = Bm[(size_t)(n0 + nn) * K + k0 + kk];
    }
    __syncthreads();
#pragma unroll
    for (int kk = 0; kk < 16; ++kk) {
      float a[4], bb[4];
#pragma unroll
      for (int i = 0; i < 4; ++i) a[i] = As[kk * 65 + ty + 16 * i];
#pragma unroll
      for (int j = 0; j < 4; ++j) bb[j] = Bs[kk * 65 + tx + 16 * j];
#pragma unroll
      for (int i = 0; i < 4; ++i)
#pragma unroll
        for (int j = 0; j < 4; ++j) acc[i][j] = fmaf(a[i], bb[j], acc[i][j]);
    }
    __syncthreads();
  }
#pragma unroll
  for (int i = 0; i < 4; ++i) {
    const int m = m0 + ty + 16 * i;
#pragma unroll
    for (int j = 0; j < 4; ++j) {
      const int n = n0 + tx + 16 * j;
      Cout[(size_t)m * Nn + n] = fmaxf(acc[i][j] + bias[n], 0.0f);
    }
  }
}

// ---------------------------------------------------------------- head -----
// out[row, o] = sum_k h2[row, k] * cw3[o, k] + cb3[o],  o < 13
__global__ void head_kernel(const float* __restrict__ h,   // (16384, 512)
                            const float* __restrict__ cw,  // (13, 512)
                            const float* __restrict__ cb,  // (13,)
                            float* __restrict__ out)       // (16384, 13)
{
  const int i = blockIdx.x * blockDim.x + threadIdx.x;
  if (i >= B_ * N0 * 13) return;
  const int o = i % 13;
  const int row = i / 13;
  const float* hr = h + (size_t)row * 512;
  const float* wr = cw + (size_t)o * 512;
  float acc = cb[o];
  for (int k = 0; k < 512; ++k) acc = fmaf(hr[k], wr[k], acc);
  out[i] = acc;
}

} // namespace

extern "C" void kernel_launch(void* const* d_in, const int* in_sizes, int n_in,
                              void* d_out, int out_size, void* d_ws, size_t ws_size,
                              hipStream_t stream)
{
  const float* vertices = (const float*)d_in[0];
  const int*   sidx1    = (const int*)  d_in[1];
  const int*   sidx2    = (const int*)  d_in[2];
  const float* dir0     = (const float*)d_in[3];
  const float* w1 = (const float*)d_in[4];
  const float* b1 = (const float*)d_in[5];
  const float* d1 = (const float*)d_in[6];
  const float* w2 = (const float*)d_in[7];
  const float* b2 = (const float*)d_in[8];
  const float* d2 = (const float*)d_in[9];
  const float* w3 = (const float*)d_in[10];
  const float* b3 = (const float*)d_in[11];
  const float* d3 = (const float*)d_in[12];
  const float* w4 = (const float*)d_in[13];
  const float* b4 = (const float*)d_in[14];
  const float* d4 = (const float*)d_in[15];
  const float* cw1 = (const float*)d_in[16];
  const float* cb1 = (const float*)d_in[17];
  const float* cw2 = (const float*)d_in[18];
  const float* cb2 = (const float*)d_in[19];
  const float* cw3 = (const float*)d_in[20];
  const float* cb3 = (const float*)d_in[21];
  (void)in_sizes; (void)n_in; (void)out_size; (void)ws_size;

  char* ws = (char*)d_ws;
  size_t off = 0;
  auto alloc = [&](size_t bytes) -> void* {
    void* p = ws + off;
    off += (bytes + 255) & ~(size_t)255;
    return p;
  };

  int*   nb1   = (int*)  alloc((size_t)B_ * N0 * 32 * 4);   //  2 MB
  float* fm0   = (float*)alloc((size_t)B_ * N0 * 128 * 4);  //  8 MB
  float* fm1   = (float*)alloc((size_t)B_ * N0 * 128 * 4);  //  8 MB
  float* vp1   = (float*)alloc((size_t)B_ * N1 * 3 * 4);
  int*   nbp1  = (int*)  alloc((size_t)B_ * N1 * 4 * 4);
  float* fmp1  = (float*)alloc((size_t)B_ * N1 * 128 * 4);  //  2 MB
  int*   nb2   = (int*)  alloc((size_t)B_ * N1 * 32 * 4);
  float* fm2   = (float*)alloc((size_t)B_ * N1 * 256 * 4);  //  4 MB
  float* fm3   = (float*)alloc((size_t)B_ * N1 * 256 * 4);  //  4 MB
  float* vp2   = (float*)alloc((size_t)B_ * N2 * 3 * 4);
  int*   nbp2  = (int*)  alloc((size_t)B_ * N2 * 4 * 4);
  float* fmp2  = (float*)alloc((size_t)B_ * N2 * 256 * 4);  //  1 MB
  int*   nb3   = (int*)  alloc((size_t)B_ * N2 * 32 * 4);
  float* fm4   = (float*)alloc((size_t)B_ * N2 * 512 * 4);  //  2 MB
  float* fglob = (float*)alloc((size_t)B_ * 512 * 4);
  int*   near1 = (int*)  alloc((size_t)B_ * N0 * 4);
  int*   near2 = (int*)  alloc((size_t)B_ * N0 * 4);
  float* h1    = (float*)alloc((size_t)B_ * N0 * 512 * 4);  // 32 MB
  float* h2    = (float*)alloc((size_t)B_ * N0 * 512 * 4);  // 32 MB
  // shared scratch for f = fm@w+b (f1 16MB is the largest; f2/f3/f4 reuse it)
  float* fbuf  = (float*)alloc((size_t)B_ * N0 * 256 * 4);  // 16 MB
  // total ~112 MB

  const dim3 blk64(64), blk256(256);

  // ---- level 0 (4096 verts) ----
  knn_kernel<32, 256><<<dim3(N0 / 64, B_), blk64, 0, stream>>>(vertices, nullptr, N0, N0, nb1);
  conv_surface_kernel<<<dim3(B_ * N0), dim3(128), 0, stream>>>(vertices, nb1, dir0, N0, 128, fm0);
  gemm_kernel<false, false, true><<<dim3(256 / 64, (B_ * N0) / 64), blk256, 0, stream>>>(
      fm0, w1, b1, B_ * N0, 256, 128, fbuf);
  conv_combine_kernel<<<dim3(B_ * N0), dim3(128), 0, stream>>>(
      fbuf, nb1, d1, vertices, N0, 128, 1, fm1);

  // ---- pool 1 -> 1024 ----
  gather_verts_kernel<<<dim3((B_ * N1 * 3 + 255) / 256), blk256, 0, stream>>>(vertices, sidx1, N0, N1, vp1);
  knn_kernel<4, 256><<<dim3(N1 / 64, B_), blk64, 0, stream>>>(vertices, sidx1, N1, N0, nbp1);
  pool_kernel<<<dim3((B_ * N1 * 128 + 255) / 256), blk256, 0, stream>>>(fm1, nbp1, N1, N0, 128, fmp1);

  // ---- level 1 (1024 verts) ----
  knn_kernel<32, 256><<<dim3(N1 / 64, B_), blk64, 0, stream>>>(vp1, nullptr, N1, N1, nb2);
  gemm_kernel<false, false, true><<<dim3(512 / 64, (B_ * N1) / 64), blk256, 0, stream>>>(
      fmp1, w2, b2, B_ * N1, 512, 128, fbuf);
  conv_combine_kernel<<<dim3(B_ * N1), dim3(256), 0, stream>>>(
      fbuf, nb2, d2, vp1, N1, 256, 1, fm2);
  gemm_kernel<false, false, true><<<dim3(512 / 64, (B_ * N1) / 64), blk256, 0, stream>>>(
      fm2, w3, b3, B_ * N1, 512, 256, fbuf);
  conv_combine_kernel<<<dim3(B_ * N1), dim3(256), 0, stream>>>(
      fbuf, nb2, d3, vp1, N1, 256, 1, fm3);

  // ---- pool 2 -> 256 ----
  gather_verts_kernel<<<dim3((B_ * N2 * 3 + 255) / 256), blk256, 0, stream>>>(vp1, sidx2, N1, N2, vp2);
  knn_kernel<4, 256><<<dim3(N2 / 64, B_), blk64, 0, stream>>>(vp1, sidx2, N2, N1, nbp2);
  pool_kernel<<<dim3((B_ * N2 * 256 + 255) / 256), blk256, 0, stream>>>(fm3, nbp2, N2, N1, 256, fmp2);

  // ---- level 2 (256 verts) ----
  knn_kernel<32, 256><<<dim3(N2 / 64, B_), blk64, 0, stream>>>(vp2, nullptr, N2, N2, nb3);
  gemm_kernel<false, false, true><<<dim3(1024 / 64, (B_ * N2) / 64), blk256, 0, stream>>>(
      fmp2, w4, b4, B_ * N2, 1024, 256, fbuf);
  conv_combine_kernel<<<dim3(B_ * N2), dim3(512), 0, stream>>>(
      fbuf, nb3, d4, vp2, N2, 512, 0, fm4);          // NOTE: no relu on fm_4
  global_max_kernel<<<dim3((B_ * 512 + 255) / 256), blk256, 0, stream>>>(fm4, fglob);

  // ---- upsample indices ----
  nearest_kernel<<<dim3((B_ * N0 + 255) / 256), blk256, 0, stream>>>(vertices, vp1, N0, N1, near1);
  nearest_kernel<<<dim3((B_ * N0 + 255) / 256), blk256, 0, stream>>>(vertices, vp2, N0, N2, near2);

  // ---- head MLP ----
  gemm_fuse_kernel<<<dim3(512 / 64, (B_ * N0) / 64), blk256, 0, stream>>>(
      fm0, fm1, fm2, fm3, fm4, fglob, near1, near2, cw1, cb1, h1);
  gemm_kernel<true, true, true><<<dim3(512 / 64, (B_ * N0) / 64), blk256, 0, stream>>>(
      h1, cw2, cb2, B_ * N0, 512, 512, h2);
  head_kernel<<<dim3((B_ * N0 * 13 + 255) / 256), blk256, 0, stream>>>(h2, cw3, cb3, (float*)d_out);
}

// Round 2
// 3248.425 us; speedup vs baseline: 3.8551x; 3.8551x over previous
//
#include <hip/hip_runtime.h>
#include <cstdint>
#include <cstddef>

namespace {

constexpr int B_ = 4;
constexpr int N0 = 4096;   // vertices per batch
constexpr int N1 = 1024;   // after pool1
constexpr int N2 = 256;    // after pool2
constexpr int SEG = 8;     // KNN candidate segments

// ------------------------------------------------------- segmented KNN -----
// Block = 256 queries, one candidate segment (blockIdx.y) of length C/SEG.
// Each thread keeps a sorted top-K of its segment in registers (static
// indices via full unroll). Strict '<' -> ties break to lower index within a
// segment; segments partition the index range in order, so the merge below
// preserves global lowest-index tie-breaking (matches lax.top_k).
// Self is excluded by index (self dist ~0 is always rank-0 in the ref).
template<int K>
__launch_bounds__(256)
__global__ void knn_seg_kernel(const float* __restrict__ pts,   // (B, C, 3)
                               const int*   __restrict__ qidx,  // (Q,) or null
                               int Q, int C, int segLen,
                               float* __restrict__ segd,        // (B,Q,SEG,K)
                               int*   __restrict__ segi)        // (B,Q,SEG,K)
{
  __shared__ float sx[256], sy[256], sz[256];
  const int b = blockIdx.z;
  const int s = blockIdx.y;
  const int q = blockIdx.x * 256 + threadIdx.x;
  const int self = qidx ? qidx[q] : q;
  const float* pb = pts + (size_t)b * C * 3;
  const float qx = pb[self * 3 + 0];
  const float qy = pb[self * 3 + 1];
  const float qz = pb[self * 3 + 2];

  float nd[K]; int ni[K];
#pragma unroll
  for (int j = 0; j < K; ++j) { nd[j] = INFINITY; ni[j] = 0; }

  const int c0 = s * segLen;
  for (int t0 = 0; t0 < segLen; t0 += 256) {
    const int nt = (segLen - t0 < 256) ? (segLen - t0) : 256;
    __syncthreads();
    if (threadIdx.x < nt) {
      sx[threadIdx.x] = pb[(c0 + t0 + threadIdx.x) * 3 + 0];
      sy[threadIdx.x] = pb[(c0 + t0 + threadIdx.x) * 3 + 1];
      sz[threadIdx.x] = pb[(c0 + t0 + threadIdx.x) * 3 + 2];
    }
    __syncthreads();
    for (int i = 0; i < nt; ++i) {
      const float dx = qx - sx[i], dy = qy - sy[i], dz = qz - sz[i];
      const float d = dx * dx + dy * dy + dz * dz;
      const int idx = c0 + t0 + i;
      if (d < nd[K - 1] && idx != self) {
        nd[K - 1] = d; ni[K - 1] = idx;
#pragma unroll
        for (int j = K - 1; j > 0; --j) {
          if (nd[j] < nd[j - 1]) {
            float td = nd[j]; nd[j] = nd[j - 1]; nd[j - 1] = td;
            int   ti = ni[j]; ni[j] = ni[j - 1]; ni[j - 1] = ti;
          }
        }
      }
    }
  }
  float* od = segd + (((size_t)b * Q + q) * SEG + s) * K;
  int*   oi = segi + (((size_t)b * Q + q) * SEG + s) * K;
#pragma unroll
  for (int j = 0; j < K; ++j) { od[j] = nd[j]; oi[j] = ni[j]; }
}

// 8-way ordered merge of the per-segment sorted lists -> global top-K.
// One thread per query. Ascending segment scan with strict '<' keeps the
// lowest-index winner on distance ties.
template<int K>
__global__ void knn_merge_kernel(const float* __restrict__ segd,
                                 const int*   __restrict__ segi,
                                 int total,                      // B*Q
                                 int* __restrict__ out)          // (B,Q,K)
{
  const int t = blockIdx.x * blockDim.x + threadIdx.x;
  if (t >= total) return;
  const float* db = segd + (size_t)t * SEG * K;
  const int*   ib = segi + (size_t)t * SEG * K;
  float hd[SEG]; int hi[SEG]; int cur[SEG];
#pragma unroll
  for (int s = 0; s < SEG; ++s) { hd[s] = db[s * K]; hi[s] = ib[s * K]; cur[s] = 1; }
  int* o = out + (size_t)t * K;
#pragma unroll
  for (int j = 0; j < K; ++j) {
    float best = hd[0]; int bs = 0;
#pragma unroll
    for (int s = 1; s < SEG; ++s)
      if (hd[s] < best) { best = hd[s]; bs = s; }
    o[j] = hi[bs];
#pragma unroll
    for (int s = 0; s < SEG; ++s)
      if (s == bs) {
        const bool more = cur[s] < K;
        hd[s] = more ? db[s * K + cur[s]] : INFINITY;
        hi[s] = more ? ib[s * K + cur[s]] : 0;
        cur[s]++;
      }
  }
}

// ------------------------------------------------------------- nearest -----
__global__ void nearest_kernel(const float* __restrict__ qpts,  // (B, Q, 3)
                               const float* __restrict__ cpts,  // (B, C, 3)
                               int Q, int C, int* __restrict__ out) // (B, Q)
{
  const int i = blockIdx.x * blockDim.x + threadIdx.x;
  if (i >= B_ * Q) return;
  const int b = i / Q;
  const float qx = qpts[(size_t)i * 3 + 0];
  const float qy = qpts[(size_t)i * 3 + 1];
  const float qz = qpts[(size_t)i * 3 + 2];
  const float* cb = cpts + (size_t)b * C * 3;
  float best = INFINITY; int bi = 0;
  for (int j = 0; j < C; ++j) {
    const float dx = qx - cb[j * 3 + 0];
    const float dy = qy - cb[j * 3 + 1];
    const float dz = qz - cb[j * 3 + 2];
    const float d = dx * dx + dy * dy + dz * dz;
    if (d < best) { best = d; bi = j; }
  }
  out[i] = bi;
}

// -------------------------------------------------------- conv_surface -----
__global__ void conv_surface_kernel(const float* __restrict__ verts, // (B, V, 3)
                                    const int*   __restrict__ nb,    // (B, V, 32)
                                    const float* __restrict__ dir,   // (3, C)
                                    int V, int C, float* __restrict__ out) // (B,V,C)
{
  __shared__ float ux[32], uy[32], uz[32];
  const int bv = blockIdx.x;
  const int b = bv / V;
  const int v = bv - b * V;
  const float* vb = verts + (size_t)b * V * 3;
  if (threadIdx.x < 32) {
    const float cx = vb[v * 3 + 0], cy = vb[v * 3 + 1], cz = vb[v * 3 + 2];
    const int nidx = nb[(size_t)bv * 32 + threadIdx.x];
    const float dx = vb[nidx * 3 + 0] - cx;
    const float dy = vb[nidx * 3 + 1] - cy;
    const float dz = vb[nidx * 3 + 2] - cz;
    const float rn = 1.0f / fmaxf(sqrtf(dx * dx + dy * dy + dz * dz), 1e-12f);
    ux[threadIdx.x] = dx * rn; uy[threadIdx.x] = dy * rn; uz[threadIdx.x] = dz * rn;
  }
  __syncthreads();
  const int o = threadIdx.x;
  float d0 = dir[o], d1 = dir[C + o], d2 = dir[2 * C + o];
  const float rn = 1.0f / fmaxf(sqrtf(d0 * d0 + d1 * d1 + d2 * d2), 1e-12f);
  d0 *= rn; d1 *= rn; d2 *= rn;
  float m = -INFINITY;
#pragma unroll
  for (int n = 0; n < 32; ++n) {
    const float t = fmaxf(0.0f, fmaf(d2, uz[n], fmaf(d1, uy[n], d0 * ux[n])));
    m = fmaxf(m, t);
  }
  out[(size_t)bv * C + o] = fmaxf(0.0f, m);
}

// -------------------------------------------------------- conv_combine -----
__global__ void conv_combine_kernel(const float* __restrict__ f,     // (B, V, 2C)
                                    const int*   __restrict__ nb,    // (B, V, 32)
                                    const float* __restrict__ dir,   // (3, C)
                                    const float* __restrict__ verts, // (B, V, 3)
                                    int V, int C, int relu,
                                    float* __restrict__ out)         // (B, V, C)
{
  __shared__ float ux[32], uy[32], uz[32];
  __shared__ int snb[32];
  const int bv = blockIdx.x;
  const int b = bv / V;
  const int v = bv - b * V;
  const float* vb = verts + (size_t)b * V * 3;
  if (threadIdx.x < 32) {
    const float cx = vb[v * 3 + 0], cy = vb[v * 3 + 1], cz = vb[v * 3 + 2];
    const int nidx = nb[(size_t)bv * 32 + threadIdx.x];
    snb[threadIdx.x] = nidx;
    const float dx = vb[nidx * 3 + 0] - cx;
    const float dy = vb[nidx * 3 + 1] - cy;
    const float dz = vb[nidx * 3 + 2] - cz;
    const float rn = 1.0f / fmaxf(sqrtf(dx * dx + dy * dy + dz * dz), 1e-12f);
    ux[threadIdx.x] = dx * rn; uy[threadIdx.x] = dy * rn; uz[threadIdx.x] = dz * rn;
  }
  __syncthreads();
  const int o = threadIdx.x;
  float d0 = dir[o], d1 = dir[C + o], d2 = dir[2 * C + o];
  const float rn = 1.0f / fmaxf(sqrtf(d0 * d0 + d1 * d1 + d2 * d2), 1e-12f);
  d0 *= rn; d1 *= rn; d2 *= rn;
  const float* fb = f + (size_t)b * V * 2 * C;
  float m = -INFINITY;
#pragma unroll 8
  for (int n = 0; n < 32; ++n) {
    const float t = fmaxf(0.0f, fmaf(d2, uz[n], fmaf(d1, uy[n], d0 * ux[n])));
    const float s = fb[(size_t)snb[n] * 2 * C + C + o];
    m = fmaxf(m, t * s);
  }
  const float r = fb[(size_t)v * 2 * C + o] + m;
  out[(size_t)bv * C + o] = relu ? fmaxf(r, 0.0f) : r;
}

// ---------------------------------------------------------------- pool -----
__global__ void pool_kernel(const float* __restrict__ fm,  // (B, Vsrc, C)
                            const int*   __restrict__ nbp, // (B, Q, 4)
                            int Q, int Vsrc, int C, float* __restrict__ out) // (B,Q,C)
{
  const int i = blockIdx.x * blockDim.x + threadIdx.x;
  if (i >= B_ * Q * C) return;
  const int c = i % C;
  const int q = (i / C) % Q;
  const int b = i / (C * Q);
  const int* nn = nbp + ((size_t)b * Q + q) * 4;
  const float* fb = fm + (size_t)b * Vsrc * C;
  const float m = fmaxf(fmaxf(fb[(size_t)nn[0] * C + c], fb[(size_t)nn[1] * C + c]),
                        fmaxf(fb[(size_t)nn[2] * C + c], fb[(size_t)nn[3] * C + c]));
  out[i] = m;
}

__global__ void gather_verts_kernel(const float* __restrict__ src, // (B, Vsrc, 3)
                                    const int* __restrict__ idx,   // (Q,)
                                    int Vsrc, int Q, float* __restrict__ dst) // (B,Q,3)
{
  const int i = blockIdx.x * blockDim.x + threadIdx.x;
  if (i >= B_ * Q * 3) return;
  const int c = i % 3;
  const int q = (i / 3) % Q;
  const int b = i / (3 * Q);
  dst[i] = src[((size_t)b * Vsrc + idx[q]) * 3 + c];
}

__global__ void global_max_kernel(const float* __restrict__ fm4, // (B, 256, 512)
                                  float* __restrict__ out)       // (B, 512)
{
  const int i = blockIdx.x * blockDim.x + threadIdx.x;
  if (i >= B_ * 512) return;
  const int c = i % 512;
  const int b = i / 512;
  const float* p = fm4 + (size_t)b * 256 * 512 + c;
  float m = -INFINITY;
  for (int v = 0; v < 256; ++v) m = fmaxf(m, p[(size_t)v * 512]);
  out[i] = m;
}

// ---------------------------------------------------------------- GEMM -----
// C[m,n] = sum_k A[m,k] * B[k,n]  (BT: B stored (N,K) row-major, i.e. B[n,k])
// 64x64 block tile, 256 threads, 4x4 per thread, K-tile 16.
template<bool BT, bool RELU, bool BIAS>
__global__ void gemm_kernel(const float* __restrict__ A,
                            const float* __restrict__ Bm,
                            const float* __restrict__ bias,
                            int M, int Nn, int K,
                            float* __restrict__ Cout)
{
  __shared__ float As[16 * 65];
  __shared__ float Bs[16 * 65];
  const int tid = threadIdx.x;
  const int tx = tid % 16, ty = tid / 16;
  const int m0 = blockIdx.y * 64, n0 = blockIdx.x * 64;
  float acc[4][4] = {};
  for (int k0 = 0; k0 < K; k0 += 16) {
#pragma unroll
    for (int i = 0; i < 4; ++i) {
      const int idx = tid + i * 256;
      const int kk = idx % 16, mm = idx / 16;
      As[kk * 65 + mm] = A[(size_t)(m0 + mm) * K + k0 + kk];
    }
#pragma unroll
    for (int i = 0; i < 4; ++i) {
      const int idx = tid + i * 256;
      if (BT) {
        const int kk = idx % 16, nn = idx / 16;
        Bs[kk * 65 + nn] = Bm[(size_t)(n0 + nn) * K + k0 + kk];
      } else {
        const int nn = idx % 64, kk = idx / 64;
        Bs[kk * 65 + nn] = Bm[(size_t)(k0 + kk) * Nn + n0 + nn];
      }
    }
    __syncthreads();
#pragma unroll
    for (int kk = 0; kk < 16; ++kk) {
      float a[4], bb[4];
#pragma unroll
      for (int i = 0; i < 4; ++i) a[i] = As[kk * 65 + ty + 16 * i];
#pragma unroll
      for (int j = 0; j < 4; ++j) bb[j] = Bs[kk * 65 + tx + 16 * j];
#pragma unroll
      for (int i = 0; i < 4; ++i)
#pragma unroll
        for (int j = 0; j < 4; ++j) acc[i][j] = fmaf(a[i], bb[j], acc[i][j]);
    }
    __syncthreads();
  }
#pragma unroll
  for (int i = 0; i < 4; ++i) {
    const int m = m0 + ty + 16 * i;
#pragma unroll
    for (int j = 0; j < 4; ++j) {
      const int n = n0 + tx + 16 * j;
      float r = acc[i][j];
      if (BIAS) r += bias[n];
      if (RELU) r = fmaxf(r, 0.0f);
      Cout[(size_t)m * Nn + n] = r;
    }
  }
}

// GEMM1 of the head MLP with the 1792-channel fuse gathered on the fly.
__global__ void gemm_fuse_kernel(const float* __restrict__ fm0,
                                 const float* __restrict__ fm1,
                                 const float* __restrict__ fm2,
                                 const float* __restrict__ fm3,
                                 const float* __restrict__ fm4,
                                 const float* __restrict__ fglob,
                                 const int*   __restrict__ near1,
                                 const int*   __restrict__ near2,
                                 const float* __restrict__ Bm,   // cw1 (512, 1792)
                                 const float* __restrict__ bias, // cb1 (512,)
                                 float* __restrict__ Cout)       // (16384, 512)
{
  constexpr int K = 1792, Nn = 512;
  __shared__ float As[16 * 65];
  __shared__ float Bs[16 * 65];
  const int tid = threadIdx.x;
  const int tx = tid % 16, ty = tid / 16;
  const int m0 = blockIdx.y * 64, n0 = blockIdx.x * 64;
  float acc[4][4] = {};
  for (int k0 = 0; k0 < K; k0 += 16) {
#pragma unroll
    for (int i = 0; i < 4; ++i) {
      const int idx = tid + i * 256;
      const int kk = idx % 16, mm = idx / 16;
      const int m = m0 + mm;
      const int b = m >> 12;              // / 4096
      const int k = k0 + kk;
      float val;
      if (k < 128)       val = fm0[(size_t)m * 128 + k];
      else if (k < 256)  val = fm1[(size_t)m * 128 + (k - 128)];
      else if (k < 512)  val = fm2[((size_t)b * 1024 + near1[m]) * 256 + (k - 256)];
      else if (k < 768)  val = fm3[((size_t)b * 1024 + near1[m]) * 256 + (k - 512)];
      else if (k < 1280) val = fm4[((size_t)b * 256 + near2[m]) * 512 + (k - 768)];
      else               val = fglob[(size_t)b * 512 + (k - 1280)];
      As[kk * 65 + mm] = val;
    }
#pragma unroll
    for (int i = 0; i < 4; ++i) {
      const int idx = tid + i * 256;
      const int kk = idx % 16, nn = idx / 16;
      Bs[kk * 65 + nn] = Bm[(size_t)(n0 + nn) * K + k0 + kk];
    }
    __syncthreads();
#pragma unroll
    for (int kk = 0; kk < 16; ++kk) {
      float a[4], bb[4];
#pragma unroll
      for (int i = 0; i < 4; ++i) a[i] = As[kk * 65 + ty + 16 * i];
#pragma unroll
      for (int j = 0; j < 4; ++j) bb[j] = Bs[kk * 65 + tx + 16 * j];
#pragma unroll
      for (int i = 0; i < 4; ++i)
#pragma unroll
        for (int j = 0; j < 4; ++j) acc[i][j] = fmaf(a[i], bb[j], acc[i][j]);
    }
    __syncthreads();
  }
#pragma unroll
  for (int i = 0; i < 4; ++i) {
    const int m = m0 + ty + 16 * i;
#pragma unroll
    for (int j = 0; j < 4; ++j) {
      const int n = n0 + tx + 16 * j;
      Cout[(size_t)m * Nn + n] = fmaxf(acc[i][j] + bias[n], 0.0f);
    }
  }
}

// ---------------------------------------------------------------- head -----
__global__ void head_kernel(const float* __restrict__ h,   // (16384, 512)
                            const float* __restrict__ cw,  // (13, 512)
                            const float* __restrict__ cb,  // (13,)
                            float* __restrict__ out)       // (16384, 13)
{
  const int i = blockIdx.x * blockDim.x + threadIdx.x;
  if (i >= B_ * N0 * 13) return;
  const int o = i % 13;
  const int row = i / 13;
  const float* hr = h + (size_t)row * 512;
  const float* wr = cw + (size_t)o * 512;
  float acc = cb[o];
  for (int k = 0; k < 512; ++k) acc = fmaf(hr[k], wr[k], acc);
  out[i] = acc;
}

} // namespace

extern "C" void kernel_launch(void* const* d_in, const int* in_sizes, int n_in,
                              void* d_out, int out_size, void* d_ws, size_t ws_size,
                              hipStream_t stream)
{
  const float* vertices = (const float*)d_in[0];
  const int*   sidx1    = (const int*)  d_in[1];
  const int*   sidx2    = (const int*)  d_in[2];
  const float* dir0     = (const float*)d_in[3];
  const float* w1 = (const float*)d_in[4];
  const float* b1 = (const float*)d_in[5];
  const float* d1 = (const float*)d_in[6];
  const float* w2 = (const float*)d_in[7];
  const float* b2 = (const float*)d_in[8];
  const float* d2 = (const float*)d_in[9];
  const float* w3 = (const float*)d_in[10];
  const float* b3 = (const float*)d_in[11];
  const float* d3 = (const float*)d_in[12];
  const float* w4 = (const float*)d_in[13];
  const float* b4 = (const float*)d_in[14];
  const float* d4 = (const float*)d_in[15];
  const float* cw1 = (const float*)d_in[16];
  const float* cb1 = (const float*)d_in[17];
  const float* cw2 = (const float*)d_in[18];
  const float* cb2 = (const float*)d_in[19];
  const float* cw3 = (const float*)d_in[20];
  const float* cb3 = (const float*)d_in[21];
  (void)in_sizes; (void)n_in; (void)out_size; (void)ws_size;

  char* ws = (char*)d_ws;
  size_t off = 0;
  auto alloc = [&](size_t bytes) -> void* {
    void* p = ws + off;
    off += (bytes + 255) & ~(size_t)255;
    return p;
  };

  int*   nb1   = (int*)  alloc((size_t)B_ * N0 * 32 * 4);   //  2 MB
  float* fm0   = (float*)alloc((size_t)B_ * N0 * 128 * 4);  //  8 MB
  float* fm1   = (float*)alloc((size_t)B_ * N0 * 128 * 4);  //  8 MB
  float* vp1   = (float*)alloc((size_t)B_ * N1 * 3 * 4);
  int*   nbp1  = (int*)  alloc((size_t)B_ * N1 * 4 * 4);
  float* fmp1  = (float*)alloc((size_t)B_ * N1 * 128 * 4);  //  2 MB
  int*   nb2   = (int*)  alloc((size_t)B_ * N1 * 32 * 4);
  float* fm2   = (float*)alloc((size_t)B_ * N1 * 256 * 4);  //  4 MB
  float* fm3   = (float*)alloc((size_t)B_ * N1 * 256 * 4);  //  4 MB
  float* vp2   = (float*)alloc((size_t)B_ * N2 * 3 * 4);
  int*   nbp2  = (int*)  alloc((size_t)B_ * N2 * 4 * 4);
  float* fmp2  = (float*)alloc((size_t)B_ * N2 * 256 * 4);  //  1 MB
  int*   nb3   = (int*)  alloc((size_t)B_ * N2 * 32 * 4);
  float* fm4   = (float*)alloc((size_t)B_ * N2 * 512 * 4);  //  2 MB
  float* fglob = (float*)alloc((size_t)B_ * 512 * 4);
  int*   near1 = (int*)  alloc((size_t)B_ * N0 * 4);
  int*   near2 = (int*)  alloc((size_t)B_ * N0 * 4);
  float* h1    = (float*)alloc((size_t)B_ * N0 * 512 * 4);  // 32 MB
  float* h2    = (float*)alloc((size_t)B_ * N0 * 512 * 4);  // 32 MB
  float* fbuf  = (float*)alloc((size_t)B_ * N0 * 256 * 4);  // 16 MB

  // KNN segment scratch ALIASES h1+h2 (64 MB): every knn_seg/knn_merge
  // completes before gemm_fuse_kernel first writes h1 (same-stream order).
  // Max need: B*N0*SEG*32 entries = 16.8 MB each.
  float* segd = h1;
  int*   segi = (int*)h2;

  const dim3 blk256(256);

  // ---- level 0 (4096 verts) ----
  knn_seg_kernel<32><<<dim3(N0 / 256, SEG, B_), blk256, 0, stream>>>(
      vertices, nullptr, N0, N0, N0 / SEG, segd, segi);
  knn_merge_kernel<32><<<dim3((B_ * N0 + 255) / 256), blk256, 0, stream>>>(
      segd, segi, B_ * N0, nb1);
  conv_surface_kernel<<<dim3(B_ * N0), dim3(128), 0, stream>>>(vertices, nb1, dir0, N0, 128, fm0);
  gemm_kernel<false, false, true><<<dim3(256 / 64, (B_ * N0) / 64), blk256, 0, stream>>>(
      fm0, w1, b1, B_ * N0, 256, 128, fbuf);
  conv_combine_kernel<<<dim3(B_ * N0), dim3(128), 0, stream>>>(
      fbuf, nb1, d1, vertices, N0, 128, 1, fm1);

  // ---- pool 1 -> 1024 ----
  gather_verts_kernel<<<dim3((B_ * N1 * 3 + 255) / 256), blk256, 0, stream>>>(vertices, sidx1, N0, N1, vp1);
  knn_seg_kernel<4><<<dim3(N1 / 256, SEG, B_), blk256, 0, stream>>>(
      vertices, sidx1, N1, N0, N0 / SEG, segd, segi);
  knn_merge_kernel<4><<<dim3((B_ * N1 + 255) / 256), blk256, 0, stream>>>(
      segd, segi, B_ * N1, nbp1);
  pool_kernel<<<dim3((B_ * N1 * 128 + 255) / 256), blk256, 0, stream>>>(fm1, nbp1, N1, N0, 128, fmp1);

  // ---- level 1 (1024 verts) ----
  knn_seg_kernel<32><<<dim3(N1 / 256, SEG, B_), blk256, 0, stream>>>(
      vp1, nullptr, N1, N1, N1 / SEG, segd, segi);
  knn_merge_kernel<32><<<dim3((B_ * N1 + 255) / 256), blk256, 0, stream>>>(
      segd, segi, B_ * N1, nb2);
  gemm_kernel<false, false, true><<<dim3(512 / 64, (B_ * N1) / 64), blk256, 0, stream>>>(
      fmp1, w2, b2, B_ * N1, 512, 128, fbuf);
  conv_combine_kernel<<<dim3(B_ * N1), dim3(256), 0, stream>>>(
      fbuf, nb2, d2, vp1, N1, 256, 1, fm2);
  gemm_kernel<false, false, true><<<dim3(512 / 64, (B_ * N1) / 64), blk256, 0, stream>>>(
      fm2, w3, b3, B_ * N1, 512, 256, fbuf);
  conv_combine_kernel<<<dim3(B_ * N1), dim3(256), 0, stream>>>(
      fbuf, nb2, d3, vp1, N1, 256, 1, fm3);

  // ---- pool 2 -> 256 ----
  gather_verts_kernel<<<dim3((B_ * N2 * 3 + 255) / 256), blk256, 0, stream>>>(vp1, sidx2, N1, N2, vp2);
  knn_seg_kernel<4><<<dim3(1, SEG, B_), blk256, 0, stream>>>(
      vp1, sidx2, N2, N1, N1 / SEG, segd, segi);
  knn_merge_kernel<4><<<dim3((B_ * N2 + 255) / 256), blk256, 0, stream>>>(
      segd, segi, B_ * N2, nbp2);
  pool_kernel<<<dim3((B_ * N2 * 256 + 255) / 256), blk256, 0, stream>>>(fm3, nbp2, N2, N1, 256, fmp2);

  // ---- level 2 (256 verts) ----
  knn_seg_kernel<32><<<dim3(1, SEG, B_), blk256, 0, stream>>>(
      vp2, nullptr, N2, N2, N2 / SEG, segd, segi);
  knn_merge_kernel<32><<<dim3((B_ * N2 + 255) / 256), blk256, 0, stream>>>(
      segd, segi, B_ * N2, nb3);
  gemm_kernel<false, false, true><<<dim3(1024 / 64, (B_ * N2) / 64), blk256, 0, stream>>>(
      fmp2, w4, b4, B_ * N2, 1024, 256, fbuf);
  conv_combine_kernel<<<dim3(B_ * N2), dim3(512), 0, stream>>>(
      fbuf, nb3, d4, vp2, N2, 512, 0, fm4);          // no relu on fm_4
  global_max_kernel<<<dim3((B_ * 512 + 255) / 256), blk256, 0, stream>>>(fm4, fglob);

  // ---- upsample indices ----
  nearest_kernel<<<dim3((B_ * N0 + 255) / 256), blk256, 0, stream>>>(vertices, vp1, N0, N1, near1);
  nearest_kernel<<<dim3((B_ * N0 + 255) / 256), blk256, 0, stream>>>(vertices, vp2, N0, N2, near2);

  // ---- head MLP ----
  gemm_fuse_kernel<<<dim3(512 / 64, (B_ * N0) / 64), blk256, 0, stream>>>(
      fm0, fm1, fm2, fm3, fm4, fglob, near1, near2, cw1, cb1, h1);
  gemm_kernel<true, true, true><<<dim3(512 / 64, (B_ * N0) / 64), blk256, 0, stream>>>(
      h1, cw2, cb2, B_ * N0, 512, 512, h2);
  head_kernel<<<dim3((B_ * N0 * 13 + 255) / 256), blk256, 0, stream>>>(h2, cw3, cb3, (float*)d_out);
}

// Round 3
// 1777.923 us; speedup vs baseline: 7.0436x; 1.8271x over previous
//
#include <hip/hip_runtime.h>
#include <cstdint>
#include <cstddef>

namespace {

constexpr int B_ = 4;
constexpr int N0 = 4096;   // vertices per batch
constexpr int N1 = 1024;   // after pool1
constexpr int N2 = 256;    // after pool2

// ------------------------------------------------- wave-cooperative KNN ----
// One 64-lane wave per query. Lanes evaluate 64 candidates in parallel;
// ballot(d < tau) filters to the ~K+K*ln(C/K) candidates that can enter the
// top-K; each is inserted with O(1) wave-parallel work (ballot popcount for
// position + shfl_up shift). The sorted top-K list lives distributed across
// lanes 0..K-1 (ld = dist, li = index, ascending).
// Tie-breaking matches lax.top_k: bits processed in ascending candidate
// order; position counts entries <= d (equals keep lower index first);
// strict d < tau excludes equal-to-worst. Self excluded by index.
template<int K>
__launch_bounds__(256)
__global__ void knn_wave_kernel(const float* __restrict__ pts,   // (B, C, 3)
                                const int*   __restrict__ qidx,  // (Q,) or null
                                int Q, int C,
                                int* __restrict__ out)           // (B, Q, K)
{
  constexpr int TILE = 256;
  __shared__ float sx[TILE], sy[TILE], sz[TILE];
  const int b    = blockIdx.y;
  const int lane = threadIdx.x & 63;
  const int wid  = threadIdx.x >> 6;
  const int q    = blockIdx.x * 4 + wid;          // Q % 4 == 0
  const int self = qidx ? qidx[q] : q;
  const float* pb = pts + (size_t)b * C * 3;
  const float qx = pb[self * 3 + 0];
  const float qy = pb[self * 3 + 1];
  const float qz = pb[self * 3 + 2];

  float ld = INFINITY;   // lane i < K holds i-th smallest distance
  int   li = 0;
  float tau = INFINITY;  // wave-uniform: current K-th best

  for (int t0 = 0; t0 < C; t0 += TILE) {
    const int nt = (C - t0 < TILE) ? (C - t0) : TILE;
    __syncthreads();
    for (int i = threadIdx.x; i < nt; i += 256) {
      sx[i] = pb[(t0 + i) * 3 + 0];
      sy[i] = pb[(t0 + i) * 3 + 1];
      sz[i] = pb[(t0 + i) * 3 + 2];
    }
    __syncthreads();
    for (int base = 0; base < nt; base += 64) {
      const int ci = t0 + base + lane;
      const float dx = qx - sx[base + lane];
      const float dy = qy - sy[base + lane];
      const float dz = qz - sz[base + lane];
      const float d = dx * dx + dy * dy + dz * dz;
      const bool cand = (base + lane < nt) && (ci != self) && (d < tau);
      unsigned long long m = __ballot(cand);
      while (m) {
        const int l = __ffsll((long long)m) - 1;
        m &= m - 1;
        const float dd = __shfl(d, l);           // wave-uniform
        if (dd < tau) {                          // tau may have tightened
          const int ii = t0 + base + l;
          const bool le = (lane < K) && (ld <= dd);
          const int p = __popcll(__ballot(le));  // insert position
          const float pld = __shfl_up(ld, 1);
          const int   pli = __shfl_up(li, 1);
          if (lane == p)                { ld = dd;  li = ii;  }
          else if (lane > p && lane < K){ ld = pld; li = pli; }
          tau = __shfl(ld, K - 1);
        }
      }
    }
  }
  if (lane < K) out[((size_t)b * Q + q) * K + lane] = li;
}

// ------------------------------------------------------------- nearest -----
__global__ void nearest_kernel(const float* __restrict__ qpts,  // (B, Q, 3)
                               const float* __restrict__ cpts,  // (B, C, 3)
                               int Q, int C, int* __restrict__ out) // (B, Q)
{
  const int i = blockIdx.x * blockDim.x + threadIdx.x;
  if (i >= B_ * Q) return;
  const int b = i / Q;
  const float qx = qpts[(size_t)i * 3 + 0];
  const float qy = qpts[(size_t)i * 3 + 1];
  const float qz = qpts[(size_t)i * 3 + 2];
  const float* cb = cpts + (size_t)b * C * 3;
  float best = INFINITY; int bi = 0;
  for (int j = 0; j < C; ++j) {
    const float dx = qx - cb[j * 3 + 0];
    const float dy = qy - cb[j * 3 + 1];
    const float dz = qz - cb[j * 3 + 2];
    const float d = dx * dx + dy * dy + dz * dz;
    if (d < best) { best = d; bi = j; }
  }
  out[i] = bi;
}

// -------------------------------------------------------- conv_surface -----
__global__ void conv_surface_kernel(const float* __restrict__ verts, // (B, V, 3)
                                    const int*   __restrict__ nb,    // (B, V, 32)
                                    const float* __restrict__ dir,   // (3, C)
                                    int V, int C, float* __restrict__ out) // (B,V,C)
{
  __shared__ float ux[32], uy[32], uz[32];
  const int bv = blockIdx.x;
  const int b = bv / V;
  const int v = bv - b * V;
  const float* vb = verts + (size_t)b * V * 3;
  if (threadIdx.x < 32) {
    const float cx = vb[v * 3 + 0], cy = vb[v * 3 + 1], cz = vb[v * 3 + 2];
    const int nidx = nb[(size_t)bv * 32 + threadIdx.x];
    const float dx = vb[nidx * 3 + 0] - cx;
    const float dy = vb[nidx * 3 + 1] - cy;
    const float dz = vb[nidx * 3 + 2] - cz;
    const float rn = 1.0f / fmaxf(sqrtf(dx * dx + dy * dy + dz * dz), 1e-12f);
    ux[threadIdx.x] = dx * rn; uy[threadIdx.x] = dy * rn; uz[threadIdx.x] = dz * rn;
  }
  __syncthreads();
  const int o = threadIdx.x;
  float d0 = dir[o], d1 = dir[C + o], d2 = dir[2 * C + o];
  const float rn = 1.0f / fmaxf(sqrtf(d0 * d0 + d1 * d1 + d2 * d2), 1e-12f);
  d0 *= rn; d1 *= rn; d2 *= rn;
  float m = -INFINITY;
#pragma unroll
  for (int n = 0; n < 32; ++n) {
    const float t = fmaxf(0.0f, fmaf(d2, uz[n], fmaf(d1, uy[n], d0 * ux[n])));
    m = fmaxf(m, t);
  }
  out[(size_t)bv * C + o] = fmaxf(0.0f, m);
}

// -------------------------------------------------------- conv_combine -----
__global__ void conv_combine_kernel(const float* __restrict__ f,     // (B, V, 2C)
                                    const int*   __restrict__ nb,    // (B, V, 32)
                                    const float* __restrict__ dir,   // (3, C)
                                    const float* __restrict__ verts, // (B, V, 3)
                                    int V, int C, int relu,
                                    float* __restrict__ out)         // (B, V, C)
{
  __shared__ float ux[32], uy[32], uz[32];
  __shared__ int snb[32];
  const int bv = blockIdx.x;
  const int b = bv / V;
  const int v = bv - b * V;
  const float* vb = verts + (size_t)b * V * 3;
  if (threadIdx.x < 32) {
    const float cx = vb[v * 3 + 0], cy = vb[v * 3 + 1], cz = vb[v * 3 + 2];
    const int nidx = nb[(size_t)bv * 32 + threadIdx.x];
    snb[threadIdx.x] = nidx;
    const float dx = vb[nidx * 3 + 0] - cx;
    const float dy = vb[nidx * 3 + 1] - cy;
    const float dz = vb[nidx * 3 + 2] - cz;
    const float rn = 1.0f / fmaxf(sqrtf(dx * dx + dy * dy + dz * dz), 1e-12f);
    ux[threadIdx.x] = dx * rn; uy[threadIdx.x] = dy * rn; uz[threadIdx.x] = dz * rn;
  }
  __syncthreads();
  const int o = threadIdx.x;
  float d0 = dir[o], d1 = dir[C + o], d2 = dir[2 * C + o];
  const float rn = 1.0f / fmaxf(sqrtf(d0 * d0 + d1 * d1 + d2 * d2), 1e-12f);
  d0 *= rn; d1 *= rn; d2 *= rn;
  const float* fb = f + (size_t)b * V * 2 * C;
  float m = -INFINITY;
#pragma unroll 8
  for (int n = 0; n < 32; ++n) {
    const float t = fmaxf(0.0f, fmaf(d2, uz[n], fmaf(d1, uy[n], d0 * ux[n])));
    const float s = fb[(size_t)snb[n] * 2 * C + C + o];
    m = fmaxf(m, t * s);
  }
  const float r = fb[(size_t)v * 2 * C + o] + m;
  out[(size_t)bv * C + o] = relu ? fmaxf(r, 0.0f) : r;
}

// ---------------------------------------------------------------- pool -----
__global__ void pool_kernel(const float* __restrict__ fm,  // (B, Vsrc, C)
                            const int*   __restrict__ nbp, // (B, Q, 4)
                            int Q, int Vsrc, int C, float* __restrict__ out) // (B,Q,C)
{
  const int i = blockIdx.x * blockDim.x + threadIdx.x;
  if (i >= B_ * Q * C) return;
  const int c = i % C;
  const int q = (i / C) % Q;
  const int b = i / (C * Q);
  const int* nn = nbp + ((size_t)b * Q + q) * 4;
  const float* fb = fm + (size_t)b * Vsrc * C;
  const float m = fmaxf(fmaxf(fb[(size_t)nn[0] * C + c], fb[(size_t)nn[1] * C + c]),
                        fmaxf(fb[(size_t)nn[2] * C + c], fb[(size_t)nn[3] * C + c]));
  out[i] = m;
}

__global__ void gather_verts_kernel(const float* __restrict__ src, // (B, Vsrc, 3)
                                    const int* __restrict__ idx,   // (Q,)
                                    int Vsrc, int Q, float* __restrict__ dst) // (B,Q,3)
{
  const int i = blockIdx.x * blockDim.x + threadIdx.x;
  if (i >= B_ * Q * 3) return;
  const int c = i % 3;
  const int q = (i / 3) % Q;
  const int b = i / (3 * Q);
  dst[i] = src[((size_t)b * Vsrc + idx[q]) * 3 + c];
}

__global__ void global_max_kernel(const float* __restrict__ fm4, // (B, 256, 512)
                                  float* __restrict__ out)       // (B, 512)
{
  const int i = blockIdx.x * blockDim.x + threadIdx.x;
  if (i >= B_ * 512) return;
  const int c = i % 512;
  const int b = i / 512;
  const float* p = fm4 + (size_t)b * 256 * 512 + c;
  float m = -INFINITY;
  for (int v = 0; v < 256; ++v) m = fmaxf(m, p[(size_t)v * 512]);
  out[i] = m;
}

// ---------------------------------------------------------------- GEMM -----
// C[m,n] = sum_k A[m,k] * B[k,n]  (BT: B stored (N,K) row-major, i.e. B[n,k])
// 64x64 block tile, 256 threads, 4x4 per thread, K-tile 16.
template<bool BT, bool RELU, bool BIAS>
__global__ void gemm_kernel(const float* __restrict__ A,
                            const float* __restrict__ Bm,
                            const float* __restrict__ bias,
                            int M, int Nn, int K,
                            float* __restrict__ Cout)
{
  __shared__ float As[16 * 65];
  __shared__ float Bs[16 * 65];
  const int tid = threadIdx.x;
  const int tx = tid % 16, ty = tid / 16;
  const int m0 = blockIdx.y * 64, n0 = blockIdx.x * 64;
  float acc[4][4] = {};
  for (int k0 = 0; k0 < K; k0 += 16) {
#pragma unroll
    for (int i = 0; i < 4; ++i) {
      const int idx = tid + i * 256;
      const int kk = idx % 16, mm = idx / 16;
      As[kk * 65 + mm] = A[(size_t)(m0 + mm) * K + k0 + kk];
    }
#pragma unroll
    for (int i = 0; i < 4; ++i) {
      const int idx = tid + i * 256;
      if (BT) {
        const int kk = idx % 16, nn = idx / 16;
        Bs[kk * 65 + nn] = Bm[(size_t)(n0 + nn) * K + k0 + kk];
      } else {
        const int nn = idx % 64, kk = idx / 64;
        Bs[kk * 65 + nn] = Bm[(size_t)(k0 + kk) * Nn + n0 + nn];
      }
    }
    __syncthreads();
#pragma unroll
    for (int kk = 0; kk < 16; ++kk) {
      float a[4], bb[4];
#pragma unroll
      for (int i = 0; i < 4; ++i) a[i] = As[kk * 65 + ty + 16 * i];
#pragma unroll
      for (int j = 0; j < 4; ++j) bb[j] = Bs[kk * 65 + tx + 16 * j];
#pragma unroll
      for (int i = 0; i < 4; ++i)
#pragma unroll
        for (int j = 0; j < 4; ++j) acc[i][j] = fmaf(a[i], bb[j], acc[i][j]);
    }
    __syncthreads();
  }
#pragma unroll
  for (int i = 0; i < 4; ++i) {
    const int m = m0 + ty + 16 * i;
#pragma unroll
    for (int j = 0; j < 4; ++j) {
      const int n = n0 + tx + 16 * j;
      float r = acc[i][j];
      if (BIAS) r += bias[n];
      if (RELU) r = fmaxf(r, 0.0f);
      Cout[(size_t)m * Nn + n] = r;
    }
  }
}

// GEMM1 of the head MLP with the 1792-channel fuse gathered on the fly.
__global__ void gemm_fuse_kernel(const float* __restrict__ fm0,
                                 const float* __restrict__ fm1,
                                 const float* __restrict__ fm2,
                                 const float* __restrict__ fm3,
                                 const float* __restrict__ fm4,
                                 const float* __restrict__ fglob,
                                 const int*   __restrict__ near1,
                                 const int*   __restrict__ near2,
                                 const float* __restrict__ Bm,   // cw1 (512, 1792)
                                 const float* __restrict__ bias, // cb1 (512,)
                                 float* __restrict__ Cout)       // (16384, 512)
{
  constexpr int K = 1792, Nn = 512;
  __shared__ float As[16 * 65];
  __shared__ float Bs[16 * 65];
  const int tid = threadIdx.x;
  const int tx = tid % 16, ty = tid / 16;
  const int m0 = blockIdx.y * 64, n0 = blockIdx.x * 64;
  float acc[4][4] = {};
  for (int k0 = 0; k0 < K; k0 += 16) {
#pragma unroll
    for (int i = 0; i < 4; ++i) {
      const int idx = tid + i * 256;
      const int kk = idx % 16, mm = idx / 16;
      const int m = m0 + mm;
      const int b = m >> 12;              // / 4096
      const int k = k0 + kk;
      float val;
      if (k < 128)       val = fm0[(size_t)m * 128 + k];
      else if (k < 256)  val = fm1[(size_t)m * 128 + (k - 128)];
      else if (k < 512)  val = fm2[((size_t)b * 1024 + near1[m]) * 256 + (k - 256)];
      else if (k < 768)  val = fm3[((size_t)b * 1024 + near1[m]) * 256 + (k - 512)];
      else if (k < 1280) val = fm4[((size_t)b * 256 + near2[m]) * 512 + (k - 768)];
      else               val = fglob[(size_t)b * 512 + (k - 1280)];
      As[kk * 65 + mm] = val;
    }
#pragma unroll
    for (int i = 0; i < 4; ++i) {
      const int idx = tid + i * 256;
      const int kk = idx % 16, nn = idx / 16;
      Bs[kk * 65 + nn] = Bm[(size_t)(n0 + nn) * K + k0 + kk];
    }
    __syncthreads();
#pragma unroll
    for (int kk = 0; kk < 16; ++kk) {
      float a[4], bb[4];
#pragma unroll
      for (int i = 0; i < 4; ++i) a[i] = As[kk * 65 + ty + 16 * i];
#pragma unroll
      for (int j = 0; j < 4; ++j) bb[j] = Bs[kk * 65 + tx + 16 * j];
#pragma unroll
      for (int i = 0; i < 4; ++i)
#pragma unroll
        for (int j = 0; j < 4; ++j) acc[i][j] = fmaf(a[i], bb[j], acc[i][j]);
    }
    __syncthreads();
  }
#pragma unroll
  for (int i = 0; i < 4; ++i) {
    const int m = m0 + ty + 16 * i;
#pragma unroll
    for (int j = 0; j < 4; ++j) {
      const int n = n0 + tx + 16 * j;
      Cout[(size_t)m * Nn + n] = fmaxf(acc[i][j] + bias[n], 0.0f);
    }
  }
}

// ---------------------------------------------------------------- head -----
__global__ void head_kernel(const float* __restrict__ h,   // (16384, 512)
                            const float* __restrict__ cw,  // (13, 512)
                            const float* __restrict__ cb,  // (13,)
                            float* __restrict__ out)       // (16384, 13)
{
  const int i = blockIdx.x * blockDim.x + threadIdx.x;
  if (i >= B_ * N0 * 13) return;
  const int o = i % 13;
  const int row = i / 13;
  const float* hr = h + (size_t)row * 512;
  const float* wr = cw + (size_t)o * 512;
  float acc = cb[o];
  for (int k = 0; k < 512; ++k) acc = fmaf(hr[k], wr[k], acc);
  out[i] = acc;
}

} // namespace

extern "C" void kernel_launch(void* const* d_in, const int* in_sizes, int n_in,
                              void* d_out, int out_size, void* d_ws, size_t ws_size,
                              hipStream_t stream)
{
  const float* vertices = (const float*)d_in[0];
  const int*   sidx1    = (const int*)  d_in[1];
  const int*   sidx2    = (const int*)  d_in[2];
  const float* dir0     = (const float*)d_in[3];
  const float* w1 = (const float*)d_in[4];
  const float* b1 = (const float*)d_in[5];
  const float* d1 = (const float*)d_in[6];
  const float* w2 = (const float*)d_in[7];
  const float* b2 = (const float*)d_in[8];
  const float* d2 = (const float*)d_in[9];
  const float* w3 = (const float*)d_in[10];
  const float* b3 = (const float*)d_in[11];
  const float* d3 = (const float*)d_in[12];
  const float* w4 = (const float*)d_in[13];
  const float* b4 = (const float*)d_in[14];
  const float* d4 = (const float*)d_in[15];
  const float* cw1 = (const float*)d_in[16];
  const float* cb1 = (const float*)d_in[17];
  const float* cw2 = (const float*)d_in[18];
  const float* cb2 = (const float*)d_in[19];
  const float* cw3 = (const float*)d_in[20];
  const float* cb3 = (const float*)d_in[21];
  (void)in_sizes; (void)n_in; (void)out_size; (void)ws_size;

  char* ws = (char*)d_ws;
  size_t off = 0;
  auto alloc = [&](size_t bytes) -> void* {
    void* p = ws + off;
    off += (bytes + 255) & ~(size_t)255;
    return p;
  };

  int*   nb1   = (int*)  alloc((size_t)B_ * N0 * 32 * 4);   //  2 MB
  float* fm0   = (float*)alloc((size_t)B_ * N0 * 128 * 4);  //  8 MB
  float* fm1   = (float*)alloc((size_t)B_ * N0 * 128 * 4);  //  8 MB
  float* vp1   = (float*)alloc((size_t)B_ * N1 * 3 * 4);
  int*   nbp1  = (int*)  alloc((size_t)B_ * N1 * 4 * 4);
  float* fmp1  = (float*)alloc((size_t)B_ * N1 * 128 * 4);  //  2 MB
  int*   nb2   = (int*)  alloc((size_t)B_ * N1 * 32 * 4);
  float* fm2   = (float*)alloc((size_t)B_ * N1 * 256 * 4);  //  4 MB
  float* fm3   = (float*)alloc((size_t)B_ * N1 * 256 * 4);  //  4 MB
  float* vp2   = (float*)alloc((size_t)B_ * N2 * 3 * 4);
  int*   nbp2  = (int*)  alloc((size_t)B_ * N2 * 4 * 4);
  float* fmp2  = (float*)alloc((size_t)B_ * N2 * 256 * 4);  //  1 MB
  int*   nb3   = (int*)  alloc((size_t)B_ * N2 * 32 * 4);
  float* fm4   = (float*)alloc((size_t)B_ * N2 * 512 * 4);  //  2 MB
  float* fglob = (float*)alloc((size_t)B_ * 512 * 4);
  int*   near1 = (int*)  alloc((size_t)B_ * N0 * 4);
  int*   near2 = (int*)  alloc((size_t)B_ * N0 * 4);
  float* h1    = (float*)alloc((size_t)B_ * N0 * 512 * 4);  // 32 MB
  float* h2    = (float*)alloc((size_t)B_ * N0 * 512 * 4);  // 32 MB
  float* fbuf  = (float*)alloc((size_t)B_ * N0 * 256 * 4);  // 16 MB

  const dim3 blk256(256);

  // ---- level 0 (4096 verts) ----
  knn_wave_kernel<32><<<dim3(N0 / 4, B_), blk256, 0, stream>>>(vertices, nullptr, N0, N0, nb1);
  conv_surface_kernel<<<dim3(B_ * N0), dim3(128), 0, stream>>>(vertices, nb1, dir0, N0, 128, fm0);
  gemm_kernel<false, false, true><<<dim3(256 / 64, (B_ * N0) / 64), blk256, 0, stream>>>(
      fm0, w1, b1, B_ * N0, 256, 128, fbuf);
  conv_combine_kernel<<<dim3(B_ * N0), dim3(128), 0, stream>>>(
      fbuf, nb1, d1, vertices, N0, 128, 1, fm1);

  // ---- pool 1 -> 1024 ----
  gather_verts_kernel<<<dim3((B_ * N1 * 3 + 255) / 256), blk256, 0, stream>>>(vertices, sidx1, N0, N1, vp1);
  knn_wave_kernel<4><<<dim3(N1 / 4, B_), blk256, 0, stream>>>(vertices, sidx1, N1, N0, nbp1);
  pool_kernel<<<dim3((B_ * N1 * 128 + 255) / 256), blk256, 0, stream>>>(fm1, nbp1, N1, N0, 128, fmp1);

  // ---- level 1 (1024 verts) ----
  knn_wave_kernel<32><<<dim3(N1 / 4, B_), blk256, 0, stream>>>(vp1, nullptr, N1, N1, nb2);
  gemm_kernel<false, false, true><<<dim3(512 / 64, (B_ * N1) / 64), blk256, 0, stream>>>(
      fmp1, w2, b2, B_ * N1, 512, 128, fbuf);
  conv_combine_kernel<<<dim3(B_ * N1), dim3(256), 0, stream>>>(
      fbuf, nb2, d2, vp1, N1, 256, 1, fm2);
  gemm_kernel<false, false, true><<<dim3(512 / 64, (B_ * N1) / 64), blk256, 0, stream>>>(
      fm2, w3, b3, B_ * N1, 512, 256, fbuf);
  conv_combine_kernel<<<dim3(B_ * N1), dim3(256), 0, stream>>>(
      fbuf, nb2, d3, vp1, N1, 256, 1, fm3);

  // ---- pool 2 -> 256 ----
  gather_verts_kernel<<<dim3((B_ * N2 * 3 + 255) / 256), blk256, 0, stream>>>(vp1, sidx2, N1, N2, vp2);
  knn_wave_kernel<4><<<dim3(N2 / 4, B_), blk256, 0, stream>>>(vp1, sidx2, N2, N1, nbp2);
  pool_kernel<<<dim3((B_ * N2 * 256 + 255) / 256), blk256, 0, stream>>>(fm3, nbp2, N2, N1, 256, fmp2);

  // ---- level 2 (256 verts) ----
  knn_wave_kernel<32><<<dim3(N2 / 4, B_), blk256, 0, stream>>>(vp2, nullptr, N2, N2, nb3);
  gemm_kernel<false, false, true><<<dim3(1024 / 64, (B_ * N2) / 64), blk256, 0, stream>>>(
      fmp2, w4, b4, B_ * N2, 1024, 256, fbuf);
  conv_combine_kernel<<<dim3(B_ * N2), dim3(512), 0, stream>>>(
      fbuf, nb3, d4, vp2, N2, 512, 0, fm4);          // no relu on fm_4
  global_max_kernel<<<dim3((B_ * 512 + 255) / 256), blk256, 0, stream>>>(fm4, fglob);

  // ---- upsample indices ----
  nearest_kernel<<<dim3((B_ * N0 + 255) / 256), blk256, 0, stream>>>(vertices, vp1, N0, N1, near1);
  nearest_kernel<<<dim3((B_ * N0 + 255) / 256), blk256, 0, stream>>>(vertices, vp2, N0, N2, near2);

  // ---- head MLP ----
  gemm_fuse_kernel<<<dim3(512 / 64, (B_ * N0) / 64), blk256, 0, stream>>>(
      fm0, fm1, fm2, fm3, fm4, fglob, near1, near2, cw1, cb1, h1);
  gemm_kernel<true, true, true><<<dim3(512 / 64, (B_ * N0) / 64), blk256, 0, stream>>>(
      h1, cw2, cb2, B_ * N0, 512, 512, h2);
  head_kernel<<<dim3((B_ * N0 * 13 + 255) / 256), blk256, 0, stream>>>(h2, cw3, cb3, (float*)d_out);
}

// Round 4
// 1002.013 us; speedup vs baseline: 12.4978x; 1.7744x over previous
//
#include <hip/hip_runtime.h>
#include <cstdint>
#include <cstddef>

namespace {

typedef unsigned short ushort_t;
typedef __bf16 bf16x8 __attribute__((ext_vector_type(8)));
typedef float  f32x4  __attribute__((ext_vector_type(4)));

constexpr int B_ = 4;
constexpr int N0 = 4096;   // vertices per batch
constexpr int N1 = 1024;   // after pool1
constexpr int N2 = 256;    // after pool2

// ----------------------------------------------------- bf16 split utils ----
__device__ __forceinline__ ushort_t f2bf_rne(float x) {
  uint32_t b = __float_as_uint(x);
  b += 0x7FFFu + ((b >> 16) & 1u);
  return (ushort_t)(b >> 16);
}
__device__ __forceinline__ float bf2f(ushort_t h) {
  return __uint_as_float(((uint32_t)h) << 16);
}

// src fp32 -> hi/lo bf16 planes (x = hi + lo up to ~2^-18 rel)
__global__ void split_kernel(const float* __restrict__ src,
                             ushort_t* __restrict__ hi, ushort_t* __restrict__ lo,
                             int n) {
  const int i = blockIdx.x * blockDim.x + threadIdx.x;
  if (i >= n) return;
  const float x = src[i];
  const ushort_t h = f2bf_rne(x);
  hi[i] = h;
  lo[i] = f2bf_rne(x - bf2f(h));
}

// ------------------------------------------------- wave-cooperative KNN ----
template<int K>
__launch_bounds__(256)
__global__ void knn_wave_kernel(const float* __restrict__ pts,   // (B, C, 3)
                                const int*   __restrict__ qidx,  // (Q,) or null
                                int Q, int C,
                                int* __restrict__ out)           // (B, Q, K)
{
  constexpr int TILE = 256;
  __shared__ float sx[TILE], sy[TILE], sz[TILE];
  const int b    = blockIdx.y;
  const int lane = threadIdx.x & 63;
  const int wid  = threadIdx.x >> 6;
  const int q    = blockIdx.x * 4 + wid;
  const int self = qidx ? qidx[q] : q;
  const float* pb = pts + (size_t)b * C * 3;
  const float qx = pb[self * 3 + 0];
  const float qy = pb[self * 3 + 1];
  const float qz = pb[self * 3 + 2];

  float ld = INFINITY; int li = 0;
  float tau = INFINITY;

  for (int t0 = 0; t0 < C; t0 += TILE) {
    const int nt = (C - t0 < TILE) ? (C - t0) : TILE;
    __syncthreads();
    for (int i = threadIdx.x; i < nt; i += 256) {
      sx[i] = pb[(t0 + i) * 3 + 0];
      sy[i] = pb[(t0 + i) * 3 + 1];
      sz[i] = pb[(t0 + i) * 3 + 2];
    }
    __syncthreads();
    for (int base = 0; base < nt; base += 64) {
      const int ci = t0 + base + lane;
      const float dx = qx - sx[base + lane];
      const float dy = qy - sy[base + lane];
      const float dz = qz - sz[base + lane];
      const float d = dx * dx + dy * dy + dz * dz;
      const bool cand = (base + lane < nt) && (ci != self) && (d < tau);
      unsigned long long m = __ballot(cand);
      while (m) {
        const int l = __ffsll((long long)m) - 1;
        m &= m - 1;
        const float dd = __shfl(d, l);
        if (dd < tau) {
          const int ii = t0 + base + l;
          const bool le = (lane < K) && (ld <= dd);
          const int p = __popcll(__ballot(le));
          const float pld = __shfl_up(ld, 1);
          const int   pli = __shfl_up(li, 1);
          if (lane == p)                { ld = dd;  li = ii;  }
          else if (lane > p && lane < K){ ld = pld; li = pli; }
          tau = __shfl(ld, K - 1);
        }
      }
    }
  }
  if (lane < K) out[((size_t)b * Q + q) * K + lane] = li;
}

// ------------------------------------------------------------- nearest -----
__global__ void nearest_kernel(const float* __restrict__ qpts,
                               const float* __restrict__ cpts,
                               int Q, int C, int* __restrict__ out) {
  const int i = blockIdx.x * blockDim.x + threadIdx.x;
  if (i >= B_ * Q) return;
  const int b = i / Q;
  const float qx = qpts[(size_t)i * 3 + 0];
  const float qy = qpts[(size_t)i * 3 + 1];
  const float qz = qpts[(size_t)i * 3 + 2];
  const float* cb = cpts + (size_t)b * C * 3;
  float best = INFINITY; int bi = 0;
  for (int j = 0; j < C; ++j) {
    const float dx = qx - cb[j * 3 + 0];
    const float dy = qy - cb[j * 3 + 1];
    const float dz = qz - cb[j * 3 + 2];
    const float d = dx * dx + dy * dy + dz * dz;
    if (d < best) { best = d; bi = j; }
  }
  out[i] = bi;
}

// -------------------------------------------------------- conv_surface -----
__global__ void conv_surface_kernel(const float* __restrict__ verts,
                                    const int*   __restrict__ nb,
                                    const float* __restrict__ dir,
                                    int V, int C, float* __restrict__ out) {
  __shared__ float ux[32], uy[32], uz[32];
  const int bv = blockIdx.x;
  const int b = bv / V;
  const int v = bv - b * V;
  const float* vb = verts + (size_t)b * V * 3;
  if (threadIdx.x < 32) {
    const float cx = vb[v * 3 + 0], cy = vb[v * 3 + 1], cz = vb[v * 3 + 2];
    const int nidx = nb[(size_t)bv * 32 + threadIdx.x];
    const float dx = vb[nidx * 3 + 0] - cx;
    const float dy = vb[nidx * 3 + 1] - cy;
    const float dz = vb[nidx * 3 + 2] - cz;
    const float rn = 1.0f / fmaxf(sqrtf(dx * dx + dy * dy + dz * dz), 1e-12f);
    ux[threadIdx.x] = dx * rn; uy[threadIdx.x] = dy * rn; uz[threadIdx.x] = dz * rn;
  }
  __syncthreads();
  const int o = threadIdx.x;
  float d0 = dir[o], d1 = dir[C + o], d2 = dir[2 * C + o];
  const float rn = 1.0f / fmaxf(sqrtf(d0 * d0 + d1 * d1 + d2 * d2), 1e-12f);
  d0 *= rn; d1 *= rn; d2 *= rn;
  float m = -INFINITY;
#pragma unroll
  for (int n = 0; n < 32; ++n) {
    const float t = fmaxf(0.0f, fmaf(d2, uz[n], fmaf(d1, uy[n], d0 * ux[n])));
    m = fmaxf(m, t);
  }
  out[(size_t)bv * C + o] = fmaxf(0.0f, m);
}

// -------------------------------------------------------- conv_combine -----
__global__ void conv_combine_kernel(const float* __restrict__ f,     // (B, V, 2C)
                                    const int*   __restrict__ nb,
                                    const float* __restrict__ dir,
                                    const float* __restrict__ verts,
                                    int V, int C, int relu,
                                    float* __restrict__ out) {
  __shared__ float ux[32], uy[32], uz[32];
  __shared__ int snb[32];
  const int bv = blockIdx.x;
  const int b = bv / V;
  const int v = bv - b * V;
  const float* vb = verts + (size_t)b * V * 3;
  if (threadIdx.x < 32) {
    const float cx = vb[v * 3 + 0], cy = vb[v * 3 + 1], cz = vb[v * 3 + 2];
    const int nidx = nb[(size_t)bv * 32 + threadIdx.x];
    snb[threadIdx.x] = nidx;
    const float dx = vb[nidx * 3 + 0] - cx;
    const float dy = vb[nidx * 3 + 1] - cy;
    const float dz = vb[nidx * 3 + 2] - cz;
    const float rn = 1.0f / fmaxf(sqrtf(dx * dx + dy * dy + dz * dz), 1e-12f);
    ux[threadIdx.x] = dx * rn; uy[threadIdx.x] = dy * rn; uz[threadIdx.x] = dz * rn;
  }
  __syncthreads();
  const int o = threadIdx.x;
  float d0 = dir[o], d1 = dir[C + o], d2 = dir[2 * C + o];
  const float rn = 1.0f / fmaxf(sqrtf(d0 * d0 + d1 * d1 + d2 * d2), 1e-12f);
  d0 *= rn; d1 *= rn; d2 *= rn;
  const float* fb = f + (size_t)b * V * 2 * C;
  float m = -INFINITY;
#pragma unroll 8
  for (int n = 0; n < 32; ++n) {
    const float t = fmaxf(0.0f, fmaf(d2, uz[n], fmaf(d1, uy[n], d0 * ux[n])));
    const float s = fb[(size_t)snb[n] * 2 * C + C + o];
    m = fmaxf(m, t * s);
  }
  const float r = fb[(size_t)v * 2 * C + o] + m;
  out[(size_t)bv * C + o] = relu ? fmaxf(r, 0.0f) : r;
}

// ---------------------------------------------------------------- pool -----
__global__ void pool_kernel(const float* __restrict__ fm,
                            const int*   __restrict__ nbp,
                            int Q, int Vsrc, int C, float* __restrict__ out) {
  const int i = blockIdx.x * blockDim.x + threadIdx.x;
  if (i >= B_ * Q * C) return;
  const int c = i % C;
  const int q = (i / C) % Q;
  const int b = i / (C * Q);
  const int* nn = nbp + ((size_t)b * Q + q) * 4;
  const float* fb = fm + (size_t)b * Vsrc * C;
  const float m = fmaxf(fmaxf(fb[(size_t)nn[0] * C + c], fb[(size_t)nn[1] * C + c]),
                        fmaxf(fb[(size_t)nn[2] * C + c], fb[(size_t)nn[3] * C + c]));
  out[i] = m;
}

__global__ void gather_verts_kernel(const float* __restrict__ src,
                                    const int* __restrict__ idx,
                                    int Vsrc, int Q, float* __restrict__ dst) {
  const int i = blockIdx.x * blockDim.x + threadIdx.x;
  if (i >= B_ * Q * 3) return;
  const int c = i % 3;
  const int q = (i / 3) % Q;
  const int b = i / (3 * Q);
  dst[i] = src[((size_t)b * Vsrc + idx[q]) * 3 + c];
}

__global__ void global_max_kernel(const float* __restrict__ fm4,
                                  float* __restrict__ out) {
  const int i = blockIdx.x * blockDim.x + threadIdx.x;
  if (i >= B_ * 512) return;
  const int c = i % 512;
  const int b = i / 512;
  const float* p = fm4 + (size_t)b * 256 * 512 + c;
  float m = -INFINITY;
  for (int v = 0; v < 256; ++v) m = fmaxf(m, p[(size_t)v * 512]);
  out[i] = m;
}

// --------------------------------------------- fp32 GEMM (conv layers) -----
template<bool BT, bool RELU, bool BIAS>
__global__ void gemm_kernel(const float* __restrict__ A,
                            const float* __restrict__ Bm,
                            const float* __restrict__ bias,
                            int M, int Nn, int K,
                            float* __restrict__ Cout) {
  __shared__ float As[16 * 65];
  __shared__ float Bs[16 * 65];
  const int tid = threadIdx.x;
  const int tx = tid % 16, ty = tid / 16;
  const int m0 = blockIdx.y * 64, n0 = blockIdx.x * 64;
  float acc[4][4] = {};
  for (int k0 = 0; k0 < K; k0 += 16) {
#pragma unroll
    for (int i = 0; i < 4; ++i) {
      const int idx = tid + i * 256;
      const int kk = idx % 16, mm = idx / 16;
      As[kk * 65 + mm] = A[(size_t)(m0 + mm) * K + k0 + kk];
    }
#pragma unroll
    for (int i = 0; i < 4; ++i) {
      const int idx = tid + i * 256;
      if (BT) {
        const int kk = idx % 16, nn = idx / 16;
        Bs[kk * 65 + nn] = Bm[(size_t)(n0 + nn) * K + k0 + kk];
      } else {
        const int nn = idx % 64, kk = idx / 64;
        Bs[kk * 65 + nn] = Bm[(size_t)(k0 + kk) * Nn + n0 + nn];
      }
    }
    __syncthreads();
#pragma unroll
    for (int kk = 0; kk < 16; ++kk) {
      float a[4], bb[4];
#pragma unroll
      for (int i = 0; i < 4; ++i) a[i] = As[kk * 65 + ty + 16 * i];
#pragma unroll
      for (int j = 0; j < 4; ++j) bb[j] = Bs[kk * 65 + tx + 16 * j];
#pragma unroll
      for (int i = 0; i < 4; ++i)
#pragma unroll
        for (int j = 0; j < 4; ++j) acc[i][j] = fmaf(a[i], bb[j], acc[i][j]);
    }
    __syncthreads();
  }
#pragma unroll
  for (int i = 0; i < 4; ++i) {
    const int m = m0 + ty + 16 * i;
#pragma unroll
    for (int j = 0; j < 4; ++j) {
      const int n = n0 + tx + 16 * j;
      float r = acc[i][j];
      if (BIAS) r += bias[n];
      if (RELU) r = fmaxf(r, 0.0f);
      Cout[(size_t)m * Nn + n] = r;
    }
  }
}

// ------------------------------------------- split-bf16 MFMA head GEMM -----
// C = relu(A @ B^T + bias), A (M,K) as hi/lo bf16 planes, B (N,K) row-major
// hi/lo planes. acc += Ah*Bh + Ah*Bl + Al*Bh (3 MFMA, shared accumulator) ->
// ~2^-18 relative error vs fp32.
// 128x128 tile, BK=32, 256 thr = 4 waves in 2x2, each wave 4x4 16x16x32 MFMAs.
// FUSE: A rows gathered on the fly from the 1792-ch concat (all segment
// boundaries are multiples of 16, so each 16-elem slice is segment-uniform).
// SPLITOUT: write result as hi/lo bf16 planes (for the next split GEMM);
// else fp32.
constexpr int LDT = 40;  // LDS row stride in ushorts (32 + 8 pad: bank spread)

template<bool FUSE, bool SPLITOUT>
__launch_bounds__(256)
__global__ void mfma_gemm_kernel(
    const ushort_t* __restrict__ Ahi, const ushort_t* __restrict__ Alo, // plain
    const ushort_t* __restrict__ f0h, const ushort_t* __restrict__ f0l,
    const ushort_t* __restrict__ f1h, const ushort_t* __restrict__ f1l,
    const ushort_t* __restrict__ f2h, const ushort_t* __restrict__ f2l,
    const ushort_t* __restrict__ f3h, const ushort_t* __restrict__ f3l,
    const ushort_t* __restrict__ f4h, const ushort_t* __restrict__ f4l,
    const ushort_t* __restrict__ fgh, const ushort_t* __restrict__ fgl,
    const int* __restrict__ near1, const int* __restrict__ near2,
    const ushort_t* __restrict__ Bhi, const ushort_t* __restrict__ Blo,
    const float* __restrict__ bias, int K,
    float* __restrict__ outF, ushort_t* __restrict__ outHi,
    ushort_t* __restrict__ outLo, int Nn)
{
  __shared__ ushort_t As_h[128 * LDT];
  __shared__ ushort_t As_l[128 * LDT];
  __shared__ ushort_t Bs_h[128 * LDT];
  __shared__ ushort_t Bs_l[128 * LDT];

  const int tid  = threadIdx.x;
  const int lane = tid & 63;
  const int wv   = tid >> 6;
  const int wr   = wv >> 1, wc = wv & 1;
  const int quad = lane >> 4, ml = lane & 15;
  const int m0 = blockIdx.y * 128, n0 = blockIdx.x * 128;

  const int r   = tid >> 1;        // staging row 0..127
  const int seg = tid & 1;         // 16-elem k-segment within BK=32

  f32x4 acc[4][4];
#pragma unroll
  for (int i = 0; i < 4; ++i)
#pragma unroll
    for (int j = 0; j < 4; ++j) acc[i][j] = f32x4{0.f, 0.f, 0.f, 0.f};

  for (int k0 = 0; k0 < K; k0 += 32) {
    // ---- gather A slice (16 bf16 from hi & lo planes) ----
    uint4 avh0, avh1, avl0, avl1;
    {
      const int m = m0 + r;
      const int k = k0 + seg * 16;
      const ushort_t *sh, *sl; size_t off;
      if (FUSE) {
        const int b = m >> 12;
        if (k < 128)       { sh = f0h; sl = f0l; off = (size_t)m * 128 + k; }
        else if (k < 256)  { sh = f1h; sl = f1l; off = (size_t)m * 128 + (k - 128); }
        else if (k < 512)  { const size_t row = (size_t)b * 1024 + near1[m];
                             sh = f2h; sl = f2l; off = row * 256 + (k - 256); }
        else if (k < 768)  { const size_t row = (size_t)b * 1024 + near1[m];
                             sh = f3h; sl = f3l; off = row * 256 + (k - 512); }
        else if (k < 1280) { const size_t row = (size_t)b * 256 + near2[m];
                             sh = f4h; sl = f4l; off = row * 512 + (k - 768); }
        else               { sh = fgh; sl = fgl; off = (size_t)b * 512 + (k - 1280); }
      } else {
        sh = Ahi; sl = Alo; off = (size_t)m * K + k;
      }
      const uint4* ph = (const uint4*)(sh + off);
      const uint4* pl = (const uint4*)(sl + off);
      avh0 = ph[0]; avh1 = ph[1];
      avl0 = pl[0]; avl1 = pl[1];
    }
    // ---- B slice ((N,K) row-major planes) ----
    uint4 bvh0, bvh1, bvl0, bvl1;
    {
      const size_t off = (size_t)(n0 + r) * K + k0 + seg * 16;
      const uint4* ph = (const uint4*)(Bhi + off);
      const uint4* pl = (const uint4*)(Blo + off);
      bvh0 = ph[0]; bvh1 = ph[1];
      bvl0 = pl[0]; bvl1 = pl[1];
    }
    __syncthreads();   // previous iteration's frag reads complete
    {
      uint4* dAh = (uint4*)&As_h[r * LDT + seg * 16];
      uint4* dAl = (uint4*)&As_l[r * LDT + seg * 16];
      uint4* dBh = (uint4*)&Bs_h[r * LDT + seg * 16];
      uint4* dBl = (uint4*)&Bs_l[r * LDT + seg * 16];
      dAh[0] = avh0; dAh[1] = avh1;
      dAl[0] = avl0; dAl[1] = avl1;
      dBh[0] = bvh0; dBh[1] = bvh1;
      dBl[0] = bvl0; dBl[1] = bvl1;
    }
    __syncthreads();
    // ---- fragments + MFMA ----
    bf16x8 ah[4], al[4], bh[4], bl[4];
#pragma unroll
    for (int i = 0; i < 4; ++i) {
      const int row = wr * 64 + i * 16 + ml;
      ah[i] = *(const bf16x8*)&As_h[row * LDT + quad * 8];
      al[i] = *(const bf16x8*)&As_l[row * LDT + quad * 8];
    }
#pragma unroll
    for (int j = 0; j < 4; ++j) {
      const int row = wc * 64 + j * 16 + ml;
      bh[j] = *(const bf16x8*)&Bs_h[row * LDT + quad * 8];
      bl[j] = *(const bf16x8*)&Bs_l[row * LDT + quad * 8];
    }
#pragma unroll
    for (int i = 0; i < 4; ++i)
#pragma unroll
      for (int j = 0; j < 4; ++j) {
        acc[i][j] = __builtin_amdgcn_mfma_f32_16x16x32_bf16(al[i], bh[j], acc[i][j], 0, 0, 0);
        acc[i][j] = __builtin_amdgcn_mfma_f32_16x16x32_bf16(ah[i], bl[j], acc[i][j], 0, 0, 0);
        acc[i][j] = __builtin_amdgcn_mfma_f32_16x16x32_bf16(ah[i], bh[j], acc[i][j], 0, 0, 0);
      }
  }

  // ---- epilogue: C/D mapping col=lane&15, row=quad*4+reg (m89) ----
#pragma unroll
  for (int i = 0; i < 4; ++i)
#pragma unroll
    for (int j = 0; j < 4; ++j) {
      const int n = n0 + wc * 64 + j * 16 + ml;
      const float bv = bias[n];
#pragma unroll
      for (int reg = 0; reg < 4; ++reg) {
        const int m = m0 + wr * 64 + i * 16 + quad * 4 + reg;
        const float rres = fmaxf(acc[i][j][reg] + bv, 0.0f);
        if (SPLITOUT) {
          const ushort_t h = f2bf_rne(rres);
          outHi[(size_t)m * Nn + n] = h;
          outLo[(size_t)m * Nn + n] = f2bf_rne(rres - bf2f(h));
        } else {
          outF[(size_t)m * Nn + n] = rres;
        }
      }
    }
}

// ---------------------------------------------------------------- head -----
__global__ void head_kernel(const float* __restrict__ h,
                            const float* __restrict__ cw,
                            const float* __restrict__ cb,
                            float* __restrict__ out) {
  const int i = blockIdx.x * blockDim.x + threadIdx.x;
  if (i >= B_ * N0 * 13) return;
  const int o = i % 13;
  const int row = i / 13;
  const float* hr = h + (size_t)row * 512;
  const float* wr = cw + (size_t)o * 512;
  float acc = cb[o];
  for (int k = 0; k < 512; ++k) acc = fmaf(hr[k], wr[k], acc);
  out[i] = acc;
}

} // namespace

extern "C" void kernel_launch(void* const* d_in, const int* in_sizes, int n_in,
                              void* d_out, int out_size, void* d_ws, size_t ws_size,
                              hipStream_t stream)
{
  const float* vertices = (const float*)d_in[0];
  const int*   sidx1    = (const int*)  d_in[1];
  const int*   sidx2    = (const int*)  d_in[2];
  const float* dir0     = (const float*)d_in[3];
  const float* w1 = (const float*)d_in[4];
  const float* b1 = (const float*)d_in[5];
  const float* d1 = (const float*)d_in[6];
  const float* w2 = (const float*)d_in[7];
  const float* b2 = (const float*)d_in[8];
  const float* d2 = (const float*)d_in[9];
  const float* w3 = (const float*)d_in[10];
  const float* b3 = (const float*)d_in[11];
  const float* d3 = (const float*)d_in[12];
  const float* w4 = (const float*)d_in[13];
  const float* b4 = (const float*)d_in[14];
  const float* d4 = (const float*)d_in[15];
  const float* cw1 = (const float*)d_in[16];
  const float* cb1 = (const float*)d_in[17];
  const float* cw2 = (const float*)d_in[18];
  const float* cb2 = (const float*)d_in[19];
  const float* cw3 = (const float*)d_in[20];
  const float* cb3 = (const float*)d_in[21];
  (void)in_sizes; (void)n_in; (void)out_size; (void)ws_size;

  char* ws = (char*)d_ws;
  size_t off = 0;
  auto alloc = [&](size_t bytes) -> void* {
    void* p = ws + off;
    off += (bytes + 255) & ~(size_t)255;
    return p;
  };

  int*   nb1   = (int*)  alloc((size_t)B_ * N0 * 32 * 4);
  float* fm0   = (float*)alloc((size_t)B_ * N0 * 128 * 4);
  float* fm1   = (float*)alloc((size_t)B_ * N0 * 128 * 4);
  float* vp1   = (float*)alloc((size_t)B_ * N1 * 3 * 4);
  int*   nbp1  = (int*)  alloc((size_t)B_ * N1 * 4 * 4);
  float* fmp1  = (float*)alloc((size_t)B_ * N1 * 128 * 4);
  int*   nb2   = (int*)  alloc((size_t)B_ * N1 * 32 * 4);
  float* fm2   = (float*)alloc((size_t)B_ * N1 * 256 * 4);
  float* fm3   = (float*)alloc((size_t)B_ * N1 * 256 * 4);
  float* vp2   = (float*)alloc((size_t)B_ * N2 * 3 * 4);
  int*   nbp2  = (int*)  alloc((size_t)B_ * N2 * 4 * 4);
  float* fmp2  = (float*)alloc((size_t)B_ * N2 * 256 * 4);
  int*   nb3   = (int*)  alloc((size_t)B_ * N2 * 32 * 4);
  float* fm4   = (float*)alloc((size_t)B_ * N2 * 512 * 4);
  float* fglob = (float*)alloc((size_t)B_ * 512 * 4);
  int*   near1 = (int*)  alloc((size_t)B_ * N0 * 4);
  int*   near2 = (int*)  alloc((size_t)B_ * N0 * 4);
  float* h2    = (float*)alloc((size_t)B_ * N0 * 512 * 4);   // 32 MB
  float* fbuf  = (float*)alloc((size_t)B_ * N0 * 256 * 4);   // 16 MB

  // bf16 hi/lo planes
  const size_t nF0 = (size_t)B_ * N0 * 128;   // fm0 / fm1
  const size_t nF2 = (size_t)B_ * N1 * 256;   // fm2 / fm3
  const size_t nF4 = (size_t)B_ * N2 * 512;
  const size_t nFg = (size_t)B_ * 512;
  const size_t nW1 = (size_t)512 * 1792;
  const size_t nW2 = (size_t)512 * 512;
  const size_t nH1 = (size_t)B_ * N0 * 512;
  ushort_t* f0h = (ushort_t*)alloc(nF0 * 2); ushort_t* f0l = (ushort_t*)alloc(nF0 * 2);
  ushort_t* f1h = (ushort_t*)alloc(nF0 * 2); ushort_t* f1l = (ushort_t*)alloc(nF0 * 2);
  ushort_t* f2h = (ushort_t*)alloc(nF2 * 2); ushort_t* f2l = (ushort_t*)alloc(nF2 * 2);
  ushort_t* f3h = (ushort_t*)alloc(nF2 * 2); ushort_t* f3l = (ushort_t*)alloc(nF2 * 2);
  ushort_t* f4h = (ushort_t*)alloc(nF4 * 2); ushort_t* f4l = (ushort_t*)alloc(nF4 * 2);
  ushort_t* fgh = (ushort_t*)alloc(nFg * 2); ushort_t* fgl = (ushort_t*)alloc(nFg * 2);
  ushort_t* w1h = (ushort_t*)alloc(nW1 * 2); ushort_t* w1l = (ushort_t*)alloc(nW1 * 2);
  ushort_t* w2h = (ushort_t*)alloc(nW2 * 2); ushort_t* w2l = (ushort_t*)alloc(nW2 * 2);
  ushort_t* h1h = (ushort_t*)alloc(nH1 * 2); ushort_t* h1l = (ushort_t*)alloc(nH1 * 2);
  // total ws ≈ 148 MB

  const dim3 blk256(256);
  auto splitN = [&](const float* s, ushort_t* h, ushort_t* l, size_t n) {
    split_kernel<<<dim3((unsigned)((n + 255) / 256)), blk256, 0, stream>>>(s, h, l, (int)n);
  };

  // ---- level 0 (4096 verts) ----
  knn_wave_kernel<32><<<dim3(N0 / 4, B_), blk256, 0, stream>>>(vertices, nullptr, N0, N0, nb1);
  conv_surface_kernel<<<dim3(B_ * N0), dim3(128), 0, stream>>>(vertices, nb1, dir0, N0, 128, fm0);
  gemm_kernel<false, false, true><<<dim3(256 / 64, (B_ * N0) / 64), blk256, 0, stream>>>(
      fm0, w1, b1, B_ * N0, 256, 128, fbuf);
  conv_combine_kernel<<<dim3(B_ * N0), dim3(128), 0, stream>>>(
      fbuf, nb1, d1, vertices, N0, 128, 1, fm1);

  // ---- pool 1 -> 1024 ----
  gather_verts_kernel<<<dim3((B_ * N1 * 3 + 255) / 256), blk256, 0, stream>>>(vertices, sidx1, N0, N1, vp1);
  knn_wave_kernel<4><<<dim3(N1 / 4, B_), blk256, 0, stream>>>(vertices, sidx1, N1, N0, nbp1);
  pool_kernel<<<dim3((B_ * N1 * 128 + 255) / 256), blk256, 0, stream>>>(fm1, nbp1, N1, N0, 128, fmp1);

  // ---- level 1 (1024 verts) ----
  knn_wave_kernel<32><<<dim3(N1 / 4, B_), blk256, 0, stream>>>(vp1, nullptr, N1, N1, nb2);
  gemm_kernel<false, false, true><<<dim3(512 / 64, (B_ * N1) / 64), blk256, 0, stream>>>(
      fmp1, w2, b2, B_ * N1, 512, 128, fbuf);
  conv_combine_kernel<<<dim3(B_ * N1), dim3(256), 0, stream>>>(
      fbuf, nb2, d2, vp1, N1, 256, 1, fm2);
  gemm_kernel<false, false, true><<<dim3(512 / 64, (B_ * N1) / 64), blk256, 0, stream>>>(
      fm2, w3, b3, B_ * N1, 512, 256, fbuf);
  conv_combine_kernel<<<dim3(B_ * N1), dim3(256), 0, stream>>>(
      fbuf, nb2, d3, vp1, N1, 256, 1, fm3);

  // ---- pool 2 -> 256 ----
  gather_verts_kernel<<<dim3((B_ * N2 * 3 + 255) / 256), blk256, 0, stream>>>(vp1, sidx2, N1, N2, vp2);
  knn_wave_kernel<4><<<dim3(N2 / 4, B_), blk256, 0, stream>>>(vp1, sidx2, N2, N1, nbp2);
  pool_kernel<<<dim3((B_ * N2 * 256 + 255) / 256), blk256, 0, stream>>>(fm3, nbp2, N2, N1, 256, fmp2);

  // ---- level 2 (256 verts) ----
  knn_wave_kernel<32><<<dim3(N2 / 4, B_), blk256, 0, stream>>>(vp2, nullptr, N2, N2, nb3);
  gemm_kernel<false, false, true><<<dim3(1024 / 64, (B_ * N2) / 64), blk256, 0, stream>>>(
      fmp2, w4, b4, B_ * N2, 1024, 256, fbuf);
  conv_combine_kernel<<<dim3(B_ * N2), dim3(512), 0, stream>>>(
      fbuf, nb3, d4, vp2, N2, 512, 0, fm4);          // no relu on fm_4
  global_max_kernel<<<dim3((B_ * 512 + 255) / 256), blk256, 0, stream>>>(fm4, fglob);

  // ---- upsample indices ----
  nearest_kernel<<<dim3((B_ * N0 + 255) / 256), blk256, 0, stream>>>(vertices, vp1, N0, N1, near1);
  nearest_kernel<<<dim3((B_ * N0 + 255) / 256), blk256, 0, stream>>>(vertices, vp2, N0, N2, near2);

  // ---- split fp32 -> hi/lo bf16 planes ----
  splitN(fm0, f0h, f0l, nF0);
  splitN(fm1, f1h, f1l, nF0);
  splitN(fm2, f2h, f2l, nF2);
  splitN(fm3, f3h, f3l, nF2);
  splitN(fm4, f4h, f4l, nF4);
  splitN(fglob, fgh, fgl, nFg);
  splitN(cw1, w1h, w1l, nW1);
  splitN(cw2, w2h, w2l, nW2);

  // ---- head MLP: split-bf16 MFMA GEMMs ----
  mfma_gemm_kernel<true, true><<<dim3(512 / 128, (B_ * N0) / 128), blk256, 0, stream>>>(
      nullptr, nullptr,
      f0h, f0l, f1h, f1l, f2h, f2l, f3h, f3l, f4h, f4l, fgh, fgl,
      near1, near2, w1h, w1l, cb1, 1792, nullptr, h1h, h1l, 512);
  mfma_gemm_kernel<false, false><<<dim3(512 / 128, (B_ * N0) / 128), blk256, 0, stream>>>(
      h1h, h1l,
      nullptr, nullptr, nullptr, nullptr, nullptr, nullptr, nullptr, nullptr,
      nullptr, nullptr, nullptr, nullptr,
      nullptr, nullptr, w2h, w2l, cb2, 512, h2, nullptr, nullptr, 512);
  head_kernel<<<dim3((B_ * N0 * 13 + 255) / 256), blk256, 0, stream>>>(h2, cw3, cb3, (float*)d_out);
}

// Round 5
// 896.947 us; speedup vs baseline: 13.9617x; 1.1171x over previous
//
#include <hip/hip_runtime.h>
#include <cstdint>
#include <cstddef>

namespace {

typedef unsigned short ushort_t;
typedef __bf16 bf16x8 __attribute__((ext_vector_type(8)));
typedef float  f32x4  __attribute__((ext_vector_type(4)));

constexpr int B_ = 4;
constexpr int N0 = 4096;   // vertices per batch
constexpr int N1 = 1024;   // after pool1
constexpr int N2 = 256;    // after pool2

// ----------------------------------------------------- bf16 split utils ----
__device__ __forceinline__ ushort_t f2bf_rne(float x) {
  uint32_t b = __float_as_uint(x);
  b += 0x7FFFu + ((b >> 16) & 1u);
  return (ushort_t)(b >> 16);
}
__device__ __forceinline__ float bf2f(ushort_t h) {
  return __uint_as_float(((uint32_t)h) << 16);
}

// src fp32 -> hi/lo bf16 planes (x = hi + lo up to ~2^-18 rel)
__global__ void split_kernel(const float* __restrict__ src,
                             ushort_t* __restrict__ hi, ushort_t* __restrict__ lo,
                             int n) {
  const int i = blockIdx.x * blockDim.x + threadIdx.x;
  if (i >= n) return;
  const float x = src[i];
  const ushort_t h = f2bf_rne(x);
  hi[i] = h;
  lo[i] = f2bf_rne(x - bf2f(h));
}

// src fp32 (K, N) -> hi/lo bf16 planes transposed to (N, K)
__global__ void transpose_split_kernel(const float* __restrict__ src,
                                       ushort_t* __restrict__ hi,
                                       ushort_t* __restrict__ lo,
                                       int K, int N) {
  const int i = blockIdx.x * blockDim.x + threadIdx.x;
  if (i >= K * N) return;
  const int k = i % K, n = i / K;          // consecutive k -> coalesced write
  const float x = src[(size_t)k * N + n];
  const ushort_t h = f2bf_rne(x);
  hi[(size_t)n * K + k] = h;
  lo[(size_t)n * K + k] = f2bf_rne(x - bf2f(h));
}

// ------------------------------------------------- wave-cooperative KNN ----
// One 64-lane wave per query. First 64-candidate batch initializes the
// distributed sorted list via a 21-stage bitonic sort on (d, idx) keys
// (stable -> lowest-index-first on ties, matching lax.top_k). Remaining
// batches: ballot(d < tau) filter + O(1) wave-parallel insertion.
template<int K>
__launch_bounds__(256)
__global__ void knn_wave_kernel(const float* __restrict__ pts,   // (B, C, 3)
                                const int*   __restrict__ qidx,  // (Q,) or null
                                int Q, int C,
                                int* __restrict__ out)           // (B, Q, K)
{
  constexpr int TILE = 256;
  __shared__ float sx[TILE], sy[TILE], sz[TILE];
  const int b    = blockIdx.y;
  const int lane = threadIdx.x & 63;
  const int wid  = threadIdx.x >> 6;
  const int q    = blockIdx.x * 4 + wid;
  const int self = qidx ? qidx[q] : q;
  const float* pb = pts + (size_t)b * C * 3;
  const float qx = pb[self * 3 + 0];
  const float qy = pb[self * 3 + 1];
  const float qz = pb[self * 3 + 2];

  float ld = INFINITY; int li = 0;
  float tau = INFINITY;

  for (int t0 = 0; t0 < C; t0 += TILE) {
    const int nt = (C - t0 < TILE) ? (C - t0) : TILE;
    __syncthreads();
    for (int i = threadIdx.x; i < nt; i += 256) {
      sx[i] = pb[(t0 + i) * 3 + 0];
      sy[i] = pb[(t0 + i) * 3 + 1];
      sz[i] = pb[(t0 + i) * 3 + 2];
    }
    __syncthreads();
    for (int base = 0; base < nt; base += 64) {
      const int ci = t0 + base + lane;
      const float dx = qx - sx[base + lane];
      const float dy = qy - sy[base + lane];
      const float dz = qz - sz[base + lane];
      const float d = dx * dx + dy * dy + dz * dz;
      const bool valid = (base + lane < nt) && (ci != self);
      if (t0 == 0 && base == 0) {
        // ---- bitonic init: sort 64 (d, idx) keys ascending across lanes ----
        float sd = valid ? d : INFINITY;
        int   si = ci;
#pragma unroll
        for (int kk = 2; kk <= 64; kk <<= 1) {
#pragma unroll
          for (int j = kk >> 1; j > 0; j >>= 1) {
            const float od = __shfl_xor(sd, j);
            const int   oi = __shfl_xor(si, j);
            const bool less    = (sd < od) || (sd == od && si < oi);
            const bool wantMin = ((lane & j) == 0) == ((lane & kk) == 0);
            if (wantMin != less) { sd = od; si = oi; }
          }
        }
        ld = sd; li = si;
        tau = __shfl(ld, K - 1);
      } else {
        const bool cand = valid && (d < tau);
        unsigned long long m = __ballot(cand);
        while (m) {
          const int l = __ffsll((long long)m) - 1;
          m &= m - 1;
          const float dd = __shfl(d, l);
          if (dd < tau) {
            const int ii = t0 + base + l;
            const bool le = (lane < K) && (ld <= dd);
            const int p = __popcll(__ballot(le));
            const float pld = __shfl_up(ld, 1);
            const int   pli = __shfl_up(li, 1);
            if (lane == p)                 { ld = dd;  li = ii;  }
            else if (lane > p && lane < K) { ld = pld; li = pli; }
            tau = __shfl(ld, K - 1);
          }
        }
      }
    }
  }
  if (lane < K) out[((size_t)b * Q + q) * K + lane] = li;
}

// ------------------------------------------------------------- nearest -----
__global__ void nearest_kernel(const float* __restrict__ qpts,
                               const float* __restrict__ cpts,
                               int Q, int C, int* __restrict__ out) {
  const int i = blockIdx.x * blockDim.x + threadIdx.x;
  if (i >= B_ * Q) return;
  const int b = i / Q;
  const float qx = qpts[(size_t)i * 3 + 0];
  const float qy = qpts[(size_t)i * 3 + 1];
  const float qz = qpts[(size_t)i * 3 + 2];
  const float* cb = cpts + (size_t)b * C * 3;
  float best = INFINITY; int bi = 0;
  for (int j = 0; j < C; ++j) {
    const float dx = qx - cb[j * 3 + 0];
    const float dy = qy - cb[j * 3 + 1];
    const float dz = qz - cb[j * 3 + 2];
    const float d = dx * dx + dy * dy + dz * dz;
    if (d < best) { best = d; bi = j; }
  }
  out[i] = bi;
}

// -------------------------------------------------------- conv_surface -----
__global__ void conv_surface_kernel(const float* __restrict__ verts,
                                    const int*   __restrict__ nb,
                                    const float* __restrict__ dir,
                                    int V, int C, float* __restrict__ out) {
  __shared__ float ux[32], uy[32], uz[32];
  const int bv = blockIdx.x;
  const int b = bv / V;
  const int v = bv - b * V;
  const float* vb = verts + (size_t)b * V * 3;
  if (threadIdx.x < 32) {
    const float cx = vb[v * 3 + 0], cy = vb[v * 3 + 1], cz = vb[v * 3 + 2];
    const int nidx = nb[(size_t)bv * 32 + threadIdx.x];
    const float dx = vb[nidx * 3 + 0] - cx;
    const float dy = vb[nidx * 3 + 1] - cy;
    const float dz = vb[nidx * 3 + 2] - cz;
    const float rn = 1.0f / fmaxf(sqrtf(dx * dx + dy * dy + dz * dz), 1e-12f);
    ux[threadIdx.x] = dx * rn; uy[threadIdx.x] = dy * rn; uz[threadIdx.x] = dz * rn;
  }
  __syncthreads();
  const int o = threadIdx.x;
  float d0 = dir[o], d1 = dir[C + o], d2 = dir[2 * C + o];
  const float rn = 1.0f / fmaxf(sqrtf(d0 * d0 + d1 * d1 + d2 * d2), 1e-12f);
  d0 *= rn; d1 *= rn; d2 *= rn;
  float m = -INFINITY;
#pragma unroll
  for (int n = 0; n < 32; ++n) {
    const float t = fmaxf(0.0f, fmaf(d2, uz[n], fmaf(d1, uy[n], d0 * ux[n])));
    m = fmaxf(m, t);
  }
  out[(size_t)bv * C + o] = fmaxf(0.0f, m);
}

// -------------------------------------------------------- conv_combine -----
__global__ void conv_combine_kernel(const float* __restrict__ f,     // (B, V, 2C)
                                    const int*   __restrict__ nb,
                                    const float* __restrict__ dir,
                                    const float* __restrict__ verts,
                                    int V, int C, int relu,
                                    float* __restrict__ out) {
  __shared__ float ux[32], uy[32], uz[32];
  __shared__ int snb[32];
  const int bv = blockIdx.x;
  const int b = bv / V;
  const int v = bv - b * V;
  const float* vb = verts + (size_t)b * V * 3;
  if (threadIdx.x < 32) {
    const float cx = vb[v * 3 + 0], cy = vb[v * 3 + 1], cz = vb[v * 3 + 2];
    const int nidx = nb[(size_t)bv * 32 + threadIdx.x];
    snb[threadIdx.x] = nidx;
    const float dx = vb[nidx * 3 + 0] - cx;
    const float dy = vb[nidx * 3 + 1] - cy;
    const float dz = vb[nidx * 3 + 2] - cz;
    const float rn = 1.0f / fmaxf(sqrtf(dx * dx + dy * dy + dz * dz), 1e-12f);
    ux[threadIdx.x] = dx * rn; uy[threadIdx.x] = dy * rn; uz[threadIdx.x] = dz * rn;
  }
  __syncthreads();
  const int o = threadIdx.x;
  float d0 = dir[o], d1 = dir[C + o], d2 = dir[2 * C + o];
  const float rn = 1.0f / fmaxf(sqrtf(d0 * d0 + d1 * d1 + d2 * d2), 1e-12f);
  d0 *= rn; d1 *= rn; d2 *= rn;
  const float* fb = f + (size_t)b * V * 2 * C;
  float m = -INFINITY;
#pragma unroll 8
  for (int n = 0; n < 32; ++n) {
    const float t = fmaxf(0.0f, fmaf(d2, uz[n], fmaf(d1, uy[n], d0 * ux[n])));
    const float s = fb[(size_t)snb[n] * 2 * C + C + o];
    m = fmaxf(m, t * s);
  }
  const float r = fb[(size_t)v * 2 * C + o] + m;
  out[(size_t)bv * C + o] = relu ? fmaxf(r, 0.0f) : r;
}

// ---------------------------------------------------------------- pool -----
// Pool-KNN(k=4) == first 4 of the level's top-32 (same points, same metric,
// same lax.top_k ordering) -> index nb(stride 32) at sampled rows directly.
__global__ void pool_kernel(const float* __restrict__ fm,   // (B, Vsrc, C)
                            const int*   __restrict__ nb,   // (B, Vsrc, 32)
                            const int*   __restrict__ sidx, // (Q,)
                            int Q, int Vsrc, int C, float* __restrict__ out) {
  const int i = blockIdx.x * blockDim.x + threadIdx.x;
  if (i >= B_ * Q * C) return;
  const int c = i % C;
  const int q = (i / C) % Q;
  const int b = i / (C * Q);
  const int* nn = nb + ((size_t)b * Vsrc + sidx[q]) * 32;
  const float* fb = fm + (size_t)b * Vsrc * C;
  const float m = fmaxf(fmaxf(fb[(size_t)nn[0] * C + c], fb[(size_t)nn[1] * C + c]),
                        fmaxf(fb[(size_t)nn[2] * C + c], fb[(size_t)nn[3] * C + c]));
  out[i] = m;
}

__global__ void gather_verts_kernel(const float* __restrict__ src,
                                    const int* __restrict__ idx,
                                    int Vsrc, int Q, float* __restrict__ dst) {
  const int i = blockIdx.x * blockDim.x + threadIdx.x;
  if (i >= B_ * Q * 3) return;
  const int c = i % 3;
  const int q = (i / 3) % Q;
  const int b = i / (3 * Q);
  dst[i] = src[((size_t)b * Vsrc + idx[q]) * 3 + c];
}

__global__ void global_max_kernel(const float* __restrict__ fm4,
                                  float* __restrict__ out) {
  const int i = blockIdx.x * blockDim.x + threadIdx.x;
  if (i >= B_ * 512) return;
  const int c = i % 512;
  const int b = i / 512;
  const float* p = fm4 + (size_t)b * 256 * 512 + c;
  float m = -INFINITY;
  for (int v = 0; v < 256; ++v) m = fmaxf(m, p[(size_t)v * 512]);
  out[i] = m;
}

// ------------------------------------------- split-bf16 MFMA GEMM ----------
// C = act(A @ B^T + bias): A (M,K) hi/lo bf16 planes, B (N,K) hi/lo planes.
// acc += Al*Bh + Ah*Bl + Ah*Bh (3 MFMA, shared fp32 accumulator) ~ fp32.
// 64M x 128N tile, BK=32, 256 thr = 4 waves 2x2; wave = 2x4 16x16x32 frags.
// Grids: M/64 x N/128 -> >=256 blocks for every call here except tiny L2.
// FUSE: A gathered on the fly from the 1792-ch concat (segment boundaries
// all multiples of 8 -> each 8-elem staging chunk is segment-uniform).
constexpr int LDT = 40;  // LDS row stride in ushorts (32 + 8 pad)

template<bool FUSE, bool SPLITOUT, bool RELU>
__launch_bounds__(256)
__global__ void mfma_gemm_kernel(
    const ushort_t* __restrict__ Ahi, const ushort_t* __restrict__ Alo,
    const ushort_t* __restrict__ f0h, const ushort_t* __restrict__ f0l,
    const ushort_t* __restrict__ f1h, const ushort_t* __restrict__ f1l,
    const ushort_t* __restrict__ f2h, const ushort_t* __restrict__ f2l,
    const ushort_t* __restrict__ f3h, const ushort_t* __restrict__ f3l,
    const ushort_t* __restrict__ f4h, const ushort_t* __restrict__ f4l,
    const ushort_t* __restrict__ fgh, const ushort_t* __restrict__ fgl,
    const int* __restrict__ near1, const int* __restrict__ near2,
    const ushort_t* __restrict__ Bhi, const ushort_t* __restrict__ Blo,
    const float* __restrict__ bias, int K,
    float* __restrict__ outF, ushort_t* __restrict__ outHi,
    ushort_t* __restrict__ outLo, int Nn)
{
  __shared__ ushort_t As_h[64 * LDT];
  __shared__ ushort_t As_l[64 * LDT];
  __shared__ ushort_t Bs_h[128 * LDT];
  __shared__ ushort_t Bs_l[128 * LDT];

  const int tid  = threadIdx.x;
  const int lane = tid & 63;
  const int wv   = tid >> 6;
  const int wr   = wv >> 1, wc = wv & 1;
  const int quad = lane >> 4, ml = lane & 15;
  const int m0 = blockIdx.y * 64, n0 = blockIdx.x * 128;

  const int ar = tid >> 2;         // staging row 0..63 (A; B rows ar, 64+ar)
  const int s8 = (tid & 3) * 8;    // 8-elem chunk offset within BK=32

  // FUSE gather rows (constant over k0)
  int fb = 0, r1 = 0, r2 = 0;
  if (FUSE) {
    const int m = m0 + ar;
    fb = m >> 12;                  // / 4096
    r1 = near1[m];
    r2 = near2[m];
  }

  f32x4 acc[2][4];
#pragma unroll
  for (int i = 0; i < 2; ++i)
#pragma unroll
    for (int j = 0; j < 4; ++j) acc[i][j] = f32x4{0.f, 0.f, 0.f, 0.f};

  for (int k0 = 0; k0 < K; k0 += 32) {
    uint4 avh, avl;
    {
      const int m = m0 + ar;
      const int k = k0 + s8;
      const ushort_t *sh, *sl; size_t off;
      if (FUSE) {
        if (k < 128)       { sh = f0h; sl = f0l; off = (size_t)m * 128 + k; }
        else if (k < 256)  { sh = f1h; sl = f1l; off = (size_t)m * 128 + (k - 128); }
        else if (k < 512)  { sh = f2h; sl = f2l; off = ((size_t)fb * 1024 + r1) * 256 + (k - 256); }
        else if (k < 768)  { sh = f3h; sl = f3l; off = ((size_t)fb * 1024 + r1) * 256 + (k - 512); }
        else if (k < 1280) { sh = f4h; sl = f4l; off = ((size_t)fb * 256 + r2) * 512 + (k - 768); }
        else               { sh = fgh; sl = fgl; off = (size_t)fb * 512 + (k - 1280); }
      } else {
        sh = Ahi; sl = Alo; off = (size_t)m * K + k;
      }
      avh = *(const uint4*)(sh + off);
      avl = *(const uint4*)(sl + off);
    }
    uint4 bvh0, bvl0, bvh1, bvl1;
    {
      const size_t off0 = (size_t)(n0 + ar) * K + k0 + s8;
      const size_t off1 = (size_t)(n0 + 64 + ar) * K + k0 + s8;
      bvh0 = *(const uint4*)(Bhi + off0);
      bvl0 = *(const uint4*)(Blo + off0);
      bvh1 = *(const uint4*)(Bhi + off1);
      bvl1 = *(const uint4*)(Blo + off1);
    }
    __syncthreads();   // previous iteration's fragment reads complete
    *(uint4*)&As_h[ar * LDT + s8] = avh;
    *(uint4*)&As_l[ar * LDT + s8] = avl;
    *(uint4*)&Bs_h[ar * LDT + s8] = bvh0;
    *(uint4*)&Bs_l[ar * LDT + s8] = bvl0;
    *(uint4*)&Bs_h[(64 + ar) * LDT + s8] = bvh1;
    *(uint4*)&Bs_l[(64 + ar) * LDT + s8] = bvl1;
    __syncthreads();

    bf16x8 ah[2], al[2], bh[4], bl[4];
#pragma unroll
    for (int i = 0; i < 2; ++i) {
      const int row = wr * 32 + i * 16 + ml;
      ah[i] = *(const bf16x8*)&As_h[row * LDT + quad * 8];
      al[i] = *(const bf16x8*)&As_l[row * LDT + quad * 8];
    }
#pragma unroll
    for (int j = 0; j < 4; ++j) {
      const int row = wc * 64 + j * 16 + ml;
      bh[j] = *(const bf16x8*)&Bs_h[row * LDT + quad * 8];
      bl[j] = *(const bf16x8*)&Bs_l[row * LDT + quad * 8];
    }
#pragma unroll
    for (int i = 0; i < 2; ++i)
#pragma unroll
      for (int j = 0; j < 4; ++j) {
        acc[i][j] = __builtin_amdgcn_mfma_f32_16x16x32_bf16(al[i], bh[j], acc[i][j], 0, 0, 0);
        acc[i][j] = __builtin_amdgcn_mfma_f32_16x16x32_bf16(ah[i], bl[j], acc[i][j], 0, 0, 0);
        acc[i][j] = __builtin_amdgcn_mfma_f32_16x16x32_bf16(ah[i], bh[j], acc[i][j], 0, 0, 0);
      }
  }

  // epilogue: C/D mapping col=lane&15, row=quad*4+reg (m89)
#pragma unroll
  for (int i = 0; i < 2; ++i)
#pragma unroll
    for (int j = 0; j < 4; ++j) {
      const int n = n0 + wc * 64 + j * 16 + ml;
      const float bv = bias[n];
#pragma unroll
      for (int reg = 0; reg < 4; ++reg) {
        const int m = m0 + wr * 32 + i * 16 + quad * 4 + reg;
        float r = acc[i][j][reg] + bv;
        if (RELU) r = fmaxf(r, 0.0f);
        if (SPLITOUT) {
          const ushort_t h = f2bf_rne(r);
          outHi[(size_t)m * Nn + n] = h;
          outLo[(size_t)m * Nn + n] = f2bf_rne(r - bf2f(h));
        } else {
          outF[(size_t)m * Nn + n] = r;
        }
      }
    }
}

// ---------------------------------------------------------------- head -----
__global__ void head_kernel(const float* __restrict__ h,
                            const float* __restrict__ cw,
                            const float* __restrict__ cb,
                            float* __restrict__ out) {
  const int i = blockIdx.x * blockDim.x + threadIdx.x;
  if (i >= B_ * N0 * 13) return;
  const int o = i % 13;
  const int row = i / 13;
  const float* hr = h + (size_t)row * 512;
  const float* wr = cw + (size_t)o * 512;
  float acc = cb[o];
  for (int k = 0; k < 512; ++k) acc = fmaf(hr[k], wr[k], acc);
  out[i] = acc;
}

} // namespace

extern "C" void kernel_launch(void* const* d_in, const int* in_sizes, int n_in,
                              void* d_out, int out_size, void* d_ws, size_t ws_size,
                              hipStream_t stream)
{
  const float* vertices = (const float*)d_in[0];
  const int*   sidx1    = (const int*)  d_in[1];
  const int*   sidx2    = (const int*)  d_in[2];
  const float* dir0     = (const float*)d_in[3];
  const float* w1 = (const float*)d_in[4];
  const float* b1 = (const float*)d_in[5];
  const float* d1 = (const float*)d_in[6];
  const float* w2 = (const float*)d_in[7];
  const float* b2 = (const float*)d_in[8];
  const float* d2 = (const float*)d_in[9];
  const float* w3 = (const float*)d_in[10];
  const float* b3 = (const float*)d_in[11];
  const float* d3 = (const float*)d_in[12];
  const float* w4 = (const float*)d_in[13];
  const float* b4 = (const float*)d_in[14];
  const float* d4 = (const float*)d_in[15];
  const float* cw1 = (const float*)d_in[16];
  const float* cb1 = (const float*)d_in[17];
  const float* cw2 = (const float*)d_in[18];
  const float* cb2 = (const float*)d_in[19];
  const float* cw3 = (const float*)d_in[20];
  const float* cb3 = (const float*)d_in[21];
  (void)in_sizes; (void)n_in; (void)out_size; (void)ws_size;

  char* ws = (char*)d_ws;
  size_t off = 0;
  auto alloc = [&](size_t bytes) -> void* {
    void* p = ws + off;
    off += (bytes + 255) & ~(size_t)255;
    return p;
  };

  int*   nb1   = (int*)  alloc((size_t)B_ * N0 * 32 * 4);
  float* fm0   = (float*)alloc((size_t)B_ * N0 * 128 * 4);
  float* fm1   = (float*)alloc((size_t)B_ * N0 * 128 * 4);
  float* vp1   = (float*)alloc((size_t)B_ * N1 * 3 * 4);
  float* fmp1  = (float*)alloc((size_t)B_ * N1 * 128 * 4);
  int*   nb2   = (int*)  alloc((size_t)B_ * N1 * 32 * 4);
  float* fm2   = (float*)alloc((size_t)B_ * N1 * 256 * 4);
  float* fm3   = (float*)alloc((size_t)B_ * N1 * 256 * 4);
  float* vp2   = (float*)alloc((size_t)B_ * N2 * 3 * 4);
  float* fmp2  = (float*)alloc((size_t)B_ * N2 * 256 * 4);
  int*   nb3   = (int*)  alloc((size_t)B_ * N2 * 32 * 4);
  float* fm4   = (float*)alloc((size_t)B_ * N2 * 512 * 4);
  float* fglob = (float*)alloc((size_t)B_ * 512 * 4);
  int*   near1 = (int*)  alloc((size_t)B_ * N0 * 4);
  int*   near2 = (int*)  alloc((size_t)B_ * N0 * 4);
  float* h2    = (float*)alloc((size_t)B_ * N0 * 512 * 4);   // 32 MB
  float* fbuf  = (float*)alloc((size_t)B_ * N0 * 256 * 4);   // 16 MB

  // bf16 hi/lo planes
  const size_t nF0 = (size_t)B_ * N0 * 128;   // fm0 / fm1
  const size_t nP1 = (size_t)B_ * N1 * 128;   // fmp1
  const size_t nF2 = (size_t)B_ * N1 * 256;   // fm2 / fm3
  const size_t nP2 = (size_t)B_ * N2 * 256;   // fmp2
  const size_t nF4 = (size_t)B_ * N2 * 512;
  const size_t nFg = (size_t)B_ * 512;
  const size_t nW1 = (size_t)512 * 1792;
  const size_t nW2 = (size_t)512 * 512;
  const size_t nH1 = (size_t)B_ * N0 * 512;
  ushort_t* f0h = (ushort_t*)alloc(nF0 * 2); ushort_t* f0l = (ushort_t*)alloc(nF0 * 2);
  ushort_t* f1h = (ushort_t*)alloc(nF0 * 2); ushort_t* f1l = (ushort_t*)alloc(nF0 * 2);
  ushort_t* p1h = (ushort_t*)alloc(nP1 * 2); ushort_t* p1l = (ushort_t*)alloc(nP1 * 2);
  ushort_t* f2h = (ushort_t*)alloc(nF2 * 2); ushort_t* f2l = (ushort_t*)alloc(nF2 * 2);
  ushort_t* f3h = (ushort_t*)alloc(nF2 * 2); ushort_t* f3l = (ushort_t*)alloc(nF2 * 2);
  ushort_t* p2h = (ushort_t*)alloc(nP2 * 2); ushort_t* p2l = (ushort_t*)alloc(nP2 * 2);
  ushort_t* f4h = (ushort_t*)alloc(nF4 * 2); ushort_t* f4l = (ushort_t*)alloc(nF4 * 2);
  ushort_t* fgh = (ushort_t*)alloc(nFg * 2); ushort_t* fgl = (ushort_t*)alloc(nFg * 2);
  ushort_t* w1h = (ushort_t*)alloc(nW1 * 2); ushort_t* w1l = (ushort_t*)alloc(nW1 * 2);
  ushort_t* w2h = (ushort_t*)alloc(nW2 * 2); ushort_t* w2l = (ushort_t*)alloc(nW2 * 2);
  ushort_t* h1h = (ushort_t*)alloc(nH1 * 2); ushort_t* h1l = (ushort_t*)alloc(nH1 * 2);
  // transposed conv weights: (N, K) planes
  ushort_t* w1th = (ushort_t*)alloc((size_t)256 * 128 * 2);
  ushort_t* w1tl = (ushort_t*)alloc((size_t)256 * 128 * 2);
  ushort_t* w2th = (ushort_t*)alloc((size_t)512 * 128 * 2);
  ushort_t* w2tl = (ushort_t*)alloc((size_t)512 * 128 * 2);
  ushort_t* w3th = (ushort_t*)alloc((size_t)512 * 256 * 2);
  ushort_t* w3tl = (ushort_t*)alloc((size_t)512 * 256 * 2);
  ushort_t* w4th = (ushort_t*)alloc((size_t)1024 * 256 * 2);
  ushort_t* w4tl = (ushort_t*)alloc((size_t)1024 * 256 * 2);

  const dim3 blk256(256);
  auto splitN = [&](const float* s, ushort_t* h, ushort_t* l, size_t n) {
    split_kernel<<<dim3((unsigned)((n + 255) / 256)), blk256, 0, stream>>>(s, h, l, (int)n);
  };
  auto tsplit = [&](const float* s, ushort_t* h, ushort_t* l, int K, int N) {
    transpose_split_kernel<<<dim3((K * N + 255) / 256), blk256, 0, stream>>>(s, h, l, K, N);
  };
  // plain split-bf16 MFMA GEMM: C(M,Nn) = act(A @ B^T + bias)
  auto mgemm = [&](const ushort_t* Ah, const ushort_t* Al,
                   const ushort_t* Bh, const ushort_t* Bl, const float* bias,
                   int M, int Nn, int K, float* outF, bool relu) {
    const dim3 grid(Nn / 128, M / 64);
    if (relu)
      mfma_gemm_kernel<false, false, true><<<grid, blk256, 0, stream>>>(
          Ah, Al, nullptr, nullptr, nullptr, nullptr, nullptr, nullptr, nullptr,
          nullptr, nullptr, nullptr, nullptr, nullptr, nullptr, nullptr,
          Bh, Bl, bias, K, outF, nullptr, nullptr, Nn);
    else
      mfma_gemm_kernel<false, false, false><<<grid, blk256, 0, stream>>>(
          Ah, Al, nullptr, nullptr, nullptr, nullptr, nullptr, nullptr, nullptr,
          nullptr, nullptr, nullptr, nullptr, nullptr, nullptr, nullptr,
          Bh, Bl, bias, K, outF, nullptr, nullptr, Nn);
  };

  // ---- weight prep (independent of everything) ----
  tsplit(w1, w1th, w1tl, 128, 256);
  tsplit(w2, w2th, w2tl, 128, 512);
  tsplit(w3, w3th, w3tl, 256, 512);
  tsplit(w4, w4th, w4tl, 256, 1024);
  splitN(cw1, w1h, w1l, nW1);   // cw1 already (N, K)
  splitN(cw2, w2h, w2l, nW2);

  // ---- level 0 (4096 verts) ----
  knn_wave_kernel<32><<<dim3(N0 / 4, B_), blk256, 0, stream>>>(vertices, nullptr, N0, N0, nb1);
  conv_surface_kernel<<<dim3(B_ * N0), dim3(128), 0, stream>>>(vertices, nb1, dir0, N0, 128, fm0);
  splitN(fm0, f0h, f0l, nF0);
  mgemm(f0h, f0l, w1th, w1tl, b1, B_ * N0, 256, 128, fbuf, false);
  conv_combine_kernel<<<dim3(B_ * N0), dim3(128), 0, stream>>>(
      fbuf, nb1, d1, vertices, N0, 128, 1, fm1);
  splitN(fm1, f1h, f1l, nF0);

  // ---- pool 1 -> 1024 (top-4 = first 4 of nb1 rows at sidx1) ----
  gather_verts_kernel<<<dim3((B_ * N1 * 3 + 255) / 256), blk256, 0, stream>>>(vertices, sidx1, N0, N1, vp1);
  pool_kernel<<<dim3((B_ * N1 * 128 + 255) / 256), blk256, 0, stream>>>(fm1, nb1, sidx1, N1, N0, 128, fmp1);
  splitN(fmp1, p1h, p1l, nP1);

  // ---- level 1 (1024 verts) ----
  knn_wave_kernel<32><<<dim3(N1 / 4, B_), blk256, 0, stream>>>(vp1, nullptr, N1, N1, nb2);
  mgemm(p1h, p1l, w2th, w2tl, b2, B_ * N1, 512, 128, fbuf, false);
  conv_combine_kernel<<<dim3(B_ * N1), dim3(256), 0, stream>>>(
      fbuf, nb2, d2, vp1, N1, 256, 1, fm2);
  splitN(fm2, f2h, f2l, nF2);
  mgemm(f2h, f2l, w3th, w3tl, b3, B_ * N1, 512, 256, fbuf, false);
  conv_combine_kernel<<<dim3(B_ * N1), dim3(256), 0, stream>>>(
      fbuf, nb2, d3, vp1, N1, 256, 1, fm3);
  splitN(fm3, f3h, f3l, nF2);

  // ---- pool 2 -> 256 ----
  gather_verts_kernel<<<dim3((B_ * N2 * 3 + 255) / 256), blk256, 0, stream>>>(vp1, sidx2, N1, N2, vp2);
  pool_kernel<<<dim3((B_ * N2 * 256 + 255) / 256), blk256, 0, stream>>>(fm3, nb2, sidx2, N2, N1, 256, fmp2);
  splitN(fmp2, p2h, p2l, nP2);

  // ---- level 2 (256 verts) ----
  knn_wave_kernel<32><<<dim3(N2 / 4, B_), blk256, 0, stream>>>(vp2, nullptr, N2, N2, nb3);
  mgemm(p2h, p2l, w4th, w4tl, b4, B_ * N2, 1024, 256, fbuf, false);
  conv_combine_kernel<<<dim3(B_ * N2), dim3(512), 0, stream>>>(
      fbuf, nb3, d4, vp2, N2, 512, 0, fm4);          // no relu on fm_4
  splitN(fm4, f4h, f4l, nF4);
  global_max_kernel<<<dim3((B_ * 512 + 255) / 256), blk256, 0, stream>>>(fm4, fglob);
  splitN(fglob, fgh, fgl, nFg);

  // ---- upsample indices ----
  nearest_kernel<<<dim3((B_ * N0 + 255) / 256), blk256, 0, stream>>>(vertices, vp1, N0, N1, near1);
  nearest_kernel<<<dim3((B_ * N0 + 255) / 256), blk256, 0, stream>>>(vertices, vp2, N0, N2, near2);

  // ---- head MLP: split-bf16 MFMA GEMMs (full-GPU grids) ----
  mfma_gemm_kernel<true, true, true><<<dim3(512 / 128, (B_ * N0) / 64), blk256, 0, stream>>>(
      nullptr, nullptr,
      f0h, f0l, f1h, f1l, f2h, f2l, f3h, f3l, f4h, f4l, fgh, fgl,
      near1, near2, w1h, w1l, cb1, 1792, nullptr, h1h, h1l, 512);
  mfma_gemm_kernel<false, false, true><<<dim3(512 / 128, (B_ * N0) / 64), blk256, 0, stream>>>(
      h1h, h1l,
      nullptr, nullptr, nullptr, nullptr, nullptr, nullptr, nullptr, nullptr,
      nullptr, nullptr, nullptr, nullptr,
      nullptr, nullptr, w2h, w2l, cb2, 512, h2, nullptr, nullptr, 512);
  head_kernel<<<dim3((B_ * N0 * 13 + 255) / 256), blk256, 0, stream>>>(h2, cw3, cb3, (float*)d_out);
}

// Round 6
// 829.118 us; speedup vs baseline: 15.1039x; 1.0818x over previous
//
#include <hip/hip_runtime.h>
#include <cstdint>
#include <cstddef>

namespace {

typedef unsigned short ushort_t;
typedef __bf16 bf16x8 __attribute__((ext_vector_type(8)));
typedef float  f32x4  __attribute__((ext_vector_type(4)));

constexpr int B_ = 4;
constexpr int N0 = 4096;   // vertices per batch
constexpr int N1 = 1024;   // after pool1
constexpr int N2 = 256;    // after pool2

// ----------------------------------------------------- bf16 split utils ----
__device__ __forceinline__ ushort_t f2bf_rne(float x) {
  uint32_t b = __float_as_uint(x);
  b += 0x7FFFu + ((b >> 16) & 1u);
  return (ushort_t)(b >> 16);
}
__device__ __forceinline__ float bf2f(ushort_t h) {
  return __uint_as_float(((uint32_t)h) << 16);
}
__device__ __forceinline__ void split_store(float x, ushort_t* hi, ushort_t* lo,
                                            size_t i) {
  const ushort_t h = f2bf_rne(x);
  hi[i] = h;
  lo[i] = f2bf_rne(x - bf2f(h));
}

// src fp32 -> hi/lo bf16 planes
__global__ void split_kernel(const float* __restrict__ src,
                             ushort_t* __restrict__ hi, ushort_t* __restrict__ lo,
                             int n) {
  const int i = blockIdx.x * blockDim.x + threadIdx.x;
  if (i >= n) return;
  split_store(src[i], hi, lo, i);
}

// src fp32 (K, N) -> hi/lo planes transposed to (N, K)
__global__ void transpose_split_kernel(const float* __restrict__ src,
                                       ushort_t* __restrict__ hi,
                                       ushort_t* __restrict__ lo,
                                       int K, int N) {
  const int i = blockIdx.x * blockDim.x + threadIdx.x;
  if (i >= K * N) return;
  const int k = i % K, n = i / K;
  split_store(src[(size_t)k * N + n], hi, lo, (size_t)n * K + k);
}

// ------------------------------------------------- wave-cooperative KNN ----
__device__ __forceinline__ void bitonic_sort64(float& sd, int& si, int lane) {
#pragma unroll
  for (int kk = 2; kk <= 64; kk <<= 1) {
#pragma unroll
    for (int j = kk >> 1; j > 0; j >>= 1) {
      const float od = __shfl_xor(sd, j);
      const int   oi = __shfl_xor(si, j);
      const bool less    = (sd < od) || (sd == od && si < oi);
      const bool wantMin = ((lane & j) == 0) == ((lane & kk) == 0);
      if (wantMin != less) { sd = od; si = oi; }
    }
  }
}

// Merge LDS buffer (cnt valid entries, unsorted) into the sorted 64-wide
// distributed list (ld, li ascending by (d, idx)); tighten tau.
__device__ __forceinline__ void knn_flush(float& ld, int& li, float& tau,
                                          int cnt, const float* bufd,
                                          const int* bufi, int lane, int Km1) {
  float sd = (lane < cnt) ? bufd[lane] : INFINITY;
  int   si = (lane < cnt) ? bufi[lane] : 0x7fffffff;
  bitonic_sort64(sd, si, lane);
  // keep lowest 64 of (list ++ buf): reverse buf, elementwise min, clean
  const float rd = __shfl(sd, 63 - lane);
  const int   ri = __shfl(si, 63 - lane);
  const bool keep = (ld < rd) || (ld == rd && li < ri);
  float md = keep ? ld : rd;
  int   mi = keep ? li : ri;
#pragma unroll
  for (int j = 32; j > 0; j >>= 1) {
    const float od = __shfl_xor(md, j);
    const int   oi = __shfl_xor(mi, j);
    const bool less    = (md < od) || (md == od && mi < oi);
    const bool wantMin = ((lane & j) == 0);
    if (wantMin != less) { md = od; mi = oi; }
  }
  ld = md; li = mi;
  tau = __shfl(ld, Km1);
}

// One wave per query. Batch of 64 distances -> ballot filter vs tau ->
// append survivors to per-wave LDS buffer (prefix-popcount positions, no
// serial chain); bitonic flush when full. First batch seeds the list via
// full bitonic sort. (d, idx) lexicographic order == lax.top_k ties.
template<int K>
__launch_bounds__(256)
__global__ void knn_wave_kernel(const float* __restrict__ pts,   // (B, C, 3)
                                const int*   __restrict__ qidx,  // (Q,) or null
                                int Q, int C,
                                int* __restrict__ out)           // (B, Q, K)
{
  constexpr int TILE = 256;
  __shared__ float sx[TILE], sy[TILE], sz[TILE];
  __shared__ float sbd[4][64];
  __shared__ int   sbi[4][64];
  const int b    = blockIdx.y;
  const int lane = threadIdx.x & 63;
  const int wid  = threadIdx.x >> 6;
  const int q    = blockIdx.x * 4 + wid;
  const int self = qidx ? qidx[q] : q;
  const float* pb = pts + (size_t)b * C * 3;
  const float qx = pb[self * 3 + 0];
  const float qy = pb[self * 3 + 1];
  const float qz = pb[self * 3 + 2];

  float ld = INFINITY; int li = 0x7fffffff;
  float tau = INFINITY;
  int cnt = 0;
  float* bufd = sbd[wid];
  int*   bufi = sbi[wid];

  for (int t0 = 0; t0 < C; t0 += TILE) {
    const int nt = (C - t0 < TILE) ? (C - t0) : TILE;
    __syncthreads();
    for (int i = threadIdx.x; i < nt; i += 256) {
      sx[i] = pb[(t0 + i) * 3 + 0];
      sy[i] = pb[(t0 + i) * 3 + 1];
      sz[i] = pb[(t0 + i) * 3 + 2];
    }
    __syncthreads();
    for (int base = 0; base < nt; base += 64) {
      const int ci = t0 + base + lane;
      const float dx = qx - sx[base + lane];
      const float dy = qy - sy[base + lane];
      const float dz = qz - sz[base + lane];
      const float d = dx * dx + dy * dy + dz * dz;
      const bool valid = (base + lane < nt) && (ci != self);
      if (t0 == 0 && base == 0) {
        float sd = valid ? d : INFINITY;
        int   si = valid ? ci : 0x7fffffff;
        bitonic_sort64(sd, si, lane);
        ld = sd; li = si;
        tau = __shfl(ld, K - 1);
      } else {
        const bool cand = valid && (d < tau);
        const unsigned long long m = __ballot(cand);
        if (m) {
          const int c = __popcll(m);
          if (cnt + c > 64) {
            knn_flush(ld, li, tau, cnt, bufd, bufi, lane, K - 1);
            cnt = 0;
          }
          const int prefix = __popcll(m & ((1ull << lane) - 1ull));
          if (cand) { bufd[cnt + prefix] = d; bufi[cnt + prefix] = ci; }
          cnt += c;
        }
      }
    }
  }
  if (cnt > 0) knn_flush(ld, li, tau, cnt, bufd, bufi, lane, K - 1);
  if (lane < K) out[((size_t)b * Q + q) * K + lane] = li;
}

// ------------------------------------------------------------- nearest -----
__global__ void nearest_kernel(const float* __restrict__ qpts,
                               const float* __restrict__ cpts,
                               int Q, int C, int* __restrict__ out) {
  const int i = blockIdx.x * blockDim.x + threadIdx.x;
  if (i >= B_ * Q) return;
  const int b = i / Q;
  const float qx = qpts[(size_t)i * 3 + 0];
  const float qy = qpts[(size_t)i * 3 + 1];
  const float qz = qpts[(size_t)i * 3 + 2];
  const float* cb = cpts + (size_t)b * C * 3;
  float best = INFINITY; int bi = 0;
  for (int j = 0; j < C; ++j) {
    const float dx = qx - cb[j * 3 + 0];
    const float dy = qy - cb[j * 3 + 1];
    const float dz = qz - cb[j * 3 + 2];
    const float d = dx * dx + dy * dy + dz * dz;
    if (d < best) { best = d; bi = j; }
  }
  out[i] = bi;
}

// -------------------------------------------------------- conv_surface -----
__global__ void conv_surface_kernel(const float* __restrict__ verts,
                                    const int*   __restrict__ nb,
                                    const float* __restrict__ dir,
                                    int V, int C,
                                    ushort_t* __restrict__ outH,
                                    ushort_t* __restrict__ outL) {
  __shared__ float ux[32], uy[32], uz[32];
  const int bv = blockIdx.x;
  const int b = bv / V;
  const int v = bv - b * V;
  const float* vb = verts + (size_t)b * V * 3;
  if (threadIdx.x < 32) {
    const float cx = vb[v * 3 + 0], cy = vb[v * 3 + 1], cz = vb[v * 3 + 2];
    const int nidx = nb[(size_t)bv * 32 + threadIdx.x];
    const float dx = vb[nidx * 3 + 0] - cx;
    const float dy = vb[nidx * 3 + 1] - cy;
    const float dz = vb[nidx * 3 + 2] - cz;
    const float rn = 1.0f / fmaxf(sqrtf(dx * dx + dy * dy + dz * dz), 1e-12f);
    ux[threadIdx.x] = dx * rn; uy[threadIdx.x] = dy * rn; uz[threadIdx.x] = dz * rn;
  }
  __syncthreads();
  const int o = threadIdx.x;
  float d0 = dir[o], d1 = dir[C + o], d2 = dir[2 * C + o];
  const float rn = 1.0f / fmaxf(sqrtf(d0 * d0 + d1 * d1 + d2 * d2), 1e-12f);
  d0 *= rn; d1 *= rn; d2 *= rn;
  float m = -INFINITY;
#pragma unroll
  for (int n = 0; n < 32; ++n) {
    const float t = fmaxf(0.0f, fmaf(d2, uz[n], fmaf(d1, uy[n], d0 * ux[n])));
    m = fmaxf(m, t);
  }
  split_store(fmaxf(0.0f, m), outH, outL, (size_t)bv * C + o);
}

// -------------------------------------------------------- conv_combine -----
__global__ void conv_combine_kernel(const float* __restrict__ f,    // (B,V,2C)
                                    const int*   __restrict__ nb,
                                    const float* __restrict__ dir,
                                    const float* __restrict__ verts,
                                    int V, int C, int relu,
                                    ushort_t* __restrict__ outH,
                                    ushort_t* __restrict__ outL) {
  __shared__ float ux[32], uy[32], uz[32];
  __shared__ int snb[32];
  const int bv = blockIdx.x;
  const int b = bv / V;
  const int v = bv - b * V;
  const float* vb = verts + (size_t)b * V * 3;
  if (threadIdx.x < 32) {
    const float cx = vb[v * 3 + 0], cy = vb[v * 3 + 1], cz = vb[v * 3 + 2];
    const int nidx = nb[(size_t)bv * 32 + threadIdx.x];
    snb[threadIdx.x] = nidx;
    const float dx = vb[nidx * 3 + 0] - cx;
    const float dy = vb[nidx * 3 + 1] - cy;
    const float dz = vb[nidx * 3 + 2] - cz;
    const float rn = 1.0f / fmaxf(sqrtf(dx * dx + dy * dy + dz * dz), 1e-12f);
    ux[threadIdx.x] = dx * rn; uy[threadIdx.x] = dy * rn; uz[threadIdx.x] = dz * rn;
  }
  __syncthreads();
  const int o = threadIdx.x;
  float d0 = dir[o], d1 = dir[C + o], d2 = dir[2 * C + o];
  const float rn = 1.0f / fmaxf(sqrtf(d0 * d0 + d1 * d1 + d2 * d2), 1e-12f);
  d0 *= rn; d1 *= rn; d2 *= rn;
  const float* fb = f + (size_t)b * V * 2 * C;
  float m = -INFINITY;
#pragma unroll 8
  for (int n = 0; n < 32; ++n) {
    const float t = fmaxf(0.0f, fmaf(d2, uz[n], fmaf(d1, uy[n], d0 * ux[n])));
    const float s = fb[(size_t)snb[n] * 2 * C + C + o];
    m = fmaxf(m, t * s);
  }
  float r = fb[(size_t)v * 2 * C + o] + m;
  if (relu) r = fmaxf(r, 0.0f);
  split_store(r, outH, outL, (size_t)bv * C + o);
}

// ---------------------------------------------------------------- pool -----
// Pool-KNN(k=4) == first 4 of the level's top-32. Reads hi/lo planes,
// reconstructs, maxes, re-splits.
__global__ void pool_kernel(const ushort_t* __restrict__ fmH,
                            const ushort_t* __restrict__ fmL,
                            const int*   __restrict__ nb,   // (B, Vsrc, 32)
                            const int*   __restrict__ sidx, // (Q,)
                            int Q, int Vsrc, int C,
                            ushort_t* __restrict__ outH,
                            ushort_t* __restrict__ outL) {
  const int i = blockIdx.x * blockDim.x + threadIdx.x;
  if (i >= B_ * Q * C) return;
  const int c = i % C;
  const int q = (i / C) % Q;
  const int b = i / (C * Q);
  const int* nn = nb + ((size_t)b * Vsrc + sidx[q]) * 32;
  const size_t fb = (size_t)b * Vsrc * C;
  float m = -INFINITY;
#pragma unroll
  for (int t = 0; t < 4; ++t) {
    const size_t idx = fb + (size_t)nn[t] * C + c;
    m = fmaxf(m, bf2f(fmH[idx]) + bf2f(fmL[idx]));
  }
  split_store(m, outH, outL, (size_t)i);
}

__global__ void gather_verts_kernel(const float* __restrict__ src,
                                    const int* __restrict__ idx,
                                    int Vsrc, int Q, float* __restrict__ dst) {
  const int i = blockIdx.x * blockDim.x + threadIdx.x;
  if (i >= B_ * Q * 3) return;
  const int c = i % 3;
  const int q = (i / 3) % Q;
  const int b = i / (3 * Q);
  dst[i] = src[((size_t)b * Vsrc + idx[q]) * 3 + c];
}

__global__ void global_max_kernel(const ushort_t* __restrict__ fmH,
                                  const ushort_t* __restrict__ fmL,
                                  ushort_t* __restrict__ outH,
                                  ushort_t* __restrict__ outL) {
  const int i = blockIdx.x * blockDim.x + threadIdx.x;
  if (i >= B_ * 512) return;
  const int c = i % 512;
  const int b = i / 512;
  const size_t base = (size_t)b * 256 * 512 + c;
  float m = -INFINITY;
  for (int v = 0; v < 256; ++v) {
    const size_t idx = base + (size_t)v * 512;
    m = fmaxf(m, bf2f(fmH[idx]) + bf2f(fmL[idx]));
  }
  split_store(m, outH, outL, (size_t)i);
}

// ------------------------------------------- split-bf16 MFMA GEMM ----------
// C = act(A @ B^T + bias); A (M,K), B (N,K) as hi/lo bf16 planes.
// acc += Al*Bh + Ah*Bl + Ah*Bh (3 MFMA shared fp32 accumulator) ~ fp32.
// 128x128 tile, BK=32, 256 thr = 4 waves 2x2, each wave 4x4 16x16x32 frags:
// 48 MFMA (~233 cyc) vs 16 ds_read_b128 (~192 cyc) per wave-iter -> MFMA-bound.
// FUSE: A gathered from the 1792-ch concat; 16-elem slices start at multiples
// of 16 and all segment boundaries are multiples of 16 -> segment-uniform.
constexpr int LDT = 40;  // LDS row stride in ushorts (32 + 8 pad)

template<bool FUSE, bool SPLITOUT, bool RELU>
__launch_bounds__(256)
__global__ void mfma_gemm_kernel(
    const ushort_t* __restrict__ Ahi, const ushort_t* __restrict__ Alo,
    const ushort_t* __restrict__ f0h, const ushort_t* __restrict__ f0l,
    const ushort_t* __restrict__ f1h, const ushort_t* __restrict__ f1l,
    const ushort_t* __restrict__ f2h, const ushort_t* __restrict__ f2l,
    const ushort_t* __restrict__ f3h, const ushort_t* __restrict__ f3l,
    const ushort_t* __restrict__ f4h, const ushort_t* __restrict__ f4l,
    const ushort_t* __restrict__ fgh, const ushort_t* __restrict__ fgl,
    const int* __restrict__ near1, const int* __restrict__ near2,
    const ushort_t* __restrict__ Bhi, const ushort_t* __restrict__ Blo,
    const float* __restrict__ bias, int K,
    float* __restrict__ outF, ushort_t* __restrict__ outHi,
    ushort_t* __restrict__ outLo, int Nn)
{
  __shared__ ushort_t As_h[128 * LDT];
  __shared__ ushort_t As_l[128 * LDT];
  __shared__ ushort_t Bs_h[128 * LDT];
  __shared__ ushort_t Bs_l[128 * LDT];

  const int tid  = threadIdx.x;
  const int lane = tid & 63;
  const int wv   = tid >> 6;
  const int wr   = wv >> 1, wc = wv & 1;
  const int quad = lane >> 4, ml = lane & 15;
  const int m0 = blockIdx.y * 128, n0 = blockIdx.x * 128;

  const int r  = tid >> 1;         // staging row 0..127
  const int hh = (tid & 1) * 16;   // 16-elem half of BK=32

  int fb = 0, r1 = 0, r2 = 0;
  if (FUSE) {
    const int m = m0 + r;
    fb = m >> 12;                  // / 4096
    r1 = near1[m];
    r2 = near2[m];
  }

  f32x4 acc[4][4];
#pragma unroll
  for (int i = 0; i < 4; ++i)
#pragma unroll
    for (int j = 0; j < 4; ++j) acc[i][j] = f32x4{0.f, 0.f, 0.f, 0.f};

  for (int k0 = 0; k0 < K; k0 += 32) {
    const int k = k0 + hh;
    uint4 a0h, a1h, a0l, a1l;
    {
      const ushort_t *sh, *sl; size_t off;
      if (FUSE) {
        const int m = m0 + r;
        if (k < 128)       { sh = f0h; sl = f0l; off = (size_t)m * 128 + k; }
        else if (k < 256)  { sh = f1h; sl = f1l; off = (size_t)m * 128 + (k - 128); }
        else if (k < 512)  { sh = f2h; sl = f2l; off = ((size_t)fb * 1024 + r1) * 256 + (k - 256); }
        else if (k < 768)  { sh = f3h; sl = f3l; off = ((size_t)fb * 1024 + r1) * 256 + (k - 512); }
        else if (k < 1280) { sh = f4h; sl = f4l; off = ((size_t)fb * 256 + r2) * 512 + (k - 768); }
        else               { sh = fgh; sl = fgl; off = (size_t)fb * 512 + (k - 1280); }
      } else {
        sh = Ahi; sl = Alo; off = (size_t)(m0 + r) * K + k;
      }
      a0h = *(const uint4*)(sh + off); a1h = *(const uint4*)(sh + off + 8);
      a0l = *(const uint4*)(sl + off); a1l = *(const uint4*)(sl + off + 8);
    }
    uint4 b0h, b1h, b0l, b1l;
    {
      const size_t off = (size_t)(n0 + r) * K + k;
      b0h = *(const uint4*)(Bhi + off); b1h = *(const uint4*)(Bhi + off + 8);
      b0l = *(const uint4*)(Blo + off); b1l = *(const uint4*)(Blo + off + 8);
    }
    __syncthreads();   // previous iteration's fragment reads complete
    *(uint4*)&As_h[r * LDT + hh]     = a0h;
    *(uint4*)&As_h[r * LDT + hh + 8] = a1h;
    *(uint4*)&As_l[r * LDT + hh]     = a0l;
    *(uint4*)&As_l[r * LDT + hh + 8] = a1l;
    *(uint4*)&Bs_h[r * LDT + hh]     = b0h;
    *(uint4*)&Bs_h[r * LDT + hh + 8] = b1h;
    *(uint4*)&Bs_l[r * LDT + hh]     = b0l;
    *(uint4*)&Bs_l[r * LDT + hh + 8] = b1l;
    __syncthreads();

    bf16x8 ah[4], al[4], bh[4], bl[4];
#pragma unroll
    for (int i = 0; i < 4; ++i) {
      const int row = wr * 64 + i * 16 + ml;
      ah[i] = *(const bf16x8*)&As_h[row * LDT + quad * 8];
      al[i] = *(const bf16x8*)&As_l[row * LDT + quad * 8];
    }
#pragma unroll
    for (int j = 0; j < 4; ++j) {
      const int row = wc * 64 + j * 16 + ml;
      bh[j] = *(const bf16x8*)&Bs_h[row * LDT + quad * 8];
      bl[j] = *(const bf16x8*)&Bs_l[row * LDT + quad * 8];
    }
#pragma unroll
    for (int i = 0; i < 4; ++i)
#pragma unroll
      for (int j = 0; j < 4; ++j) {
        acc[i][j] = __builtin_amdgcn_mfma_f32_16x16x32_bf16(al[i], bh[j], acc[i][j], 0, 0, 0);
        acc[i][j] = __builtin_amdgcn_mfma_f32_16x16x32_bf16(ah[i], bl[j], acc[i][j], 0, 0, 0);
        acc[i][j] = __builtin_amdgcn_mfma_f32_16x16x32_bf16(ah[i], bh[j], acc[i][j], 0, 0, 0);
      }
  }

  // epilogue: C/D mapping col=lane&15, row=quad*4+reg (m89)
#pragma unroll
  for (int i = 0; i < 4; ++i)
#pragma unroll
    for (int j = 0; j < 4; ++j) {
      const int n = n0 + wc * 64 + j * 16 + ml;
      const float bv = bias[n];
#pragma unroll
      for (int reg = 0; reg < 4; ++reg) {
        const int m = m0 + wr * 64 + i * 16 + quad * 4 + reg;
        float r = acc[i][j][reg] + bv;
        if (RELU) r = fmaxf(r, 0.0f);
        if (SPLITOUT) {
          const ushort_t h = f2bf_rne(r);
          outHi[(size_t)m * Nn + n] = h;
          outLo[(size_t)m * Nn + n] = f2bf_rne(r - bf2f(h));
        } else {
          outF[(size_t)m * Nn + n] = r;
        }
      }
    }
}

// ---------------------------------------------------------------- head -----
__global__ void head_kernel(const float* __restrict__ h,
                            const float* __restrict__ cw,
                            const float* __restrict__ cb,
                            float* __restrict__ out) {
  const int i = blockIdx.x * blockDim.x + threadIdx.x;
  if (i >= B_ * N0 * 13) return;
  const int o = i % 13;
  const int row = i / 13;
  const float* hr = h + (size_t)row * 512;
  const float* wr = cw + (size_t)o * 512;
  float acc = cb[o];
  for (int k = 0; k < 512; ++k) acc = fmaf(hr[k], wr[k], acc);
  out[i] = acc;
}

} // namespace

extern "C" void kernel_launch(void* const* d_in, const int* in_sizes, int n_in,
                              void* d_out, int out_size, void* d_ws, size_t ws_size,
                              hipStream_t stream)
{
  const float* vertices = (const float*)d_in[0];
  const int*   sidx1    = (const int*)  d_in[1];
  const int*   sidx2    = (const int*)  d_in[2];
  const float* dir0     = (const float*)d_in[3];
  const float* w1 = (const float*)d_in[4];
  const float* b1 = (const float*)d_in[5];
  const float* d1 = (const float*)d_in[6];
  const float* w2 = (const float*)d_in[7];
  const float* b2 = (const float*)d_in[8];
  const float* d2 = (const float*)d_in[9];
  const float* w3 = (const float*)d_in[10];
  const float* b3 = (const float*)d_in[11];
  const float* d3 = (const float*)d_in[12];
  const float* w4 = (const float*)d_in[13];
  const float* b4 = (const float*)d_in[14];
  const float* d4 = (const float*)d_in[15];
  const float* cw1 = (const float*)d_in[16];
  const float* cb1 = (const float*)d_in[17];
  const float* cw2 = (const float*)d_in[18];
  const float* cb2 = (const float*)d_in[19];
  const float* cw3 = (const float*)d_in[20];
  const float* cb3 = (const float*)d_in[21];
  (void)in_sizes; (void)n_in; (void)out_size; (void)ws_size;

  char* ws = (char*)d_ws;
  size_t off = 0;
  auto alloc = [&](size_t bytes) -> void* {
    void* p = ws + off;
    off += (bytes + 255) & ~(size_t)255;
    return p;
  };

  int*   nb1   = (int*)  alloc((size_t)B_ * N0 * 32 * 4);
  int*   nb2   = (int*)  alloc((size_t)B_ * N1 * 32 * 4);
  int*   nb3   = (int*)  alloc((size_t)B_ * N2 * 32 * 4);
  float* vp1   = (float*)alloc((size_t)B_ * N1 * 3 * 4);
  float* vp2   = (float*)alloc((size_t)B_ * N2 * 3 * 4);
  int*   near1 = (int*)  alloc((size_t)B_ * N0 * 4);
  int*   near2 = (int*)  alloc((size_t)B_ * N0 * 4);
  float* h2    = (float*)alloc((size_t)B_ * N0 * 512 * 4);   // 32 MB
  float* fbuf  = (float*)alloc((size_t)B_ * N0 * 256 * 4);   // 16 MB

  const size_t nF0 = (size_t)B_ * N0 * 128;   // fm0 / fm1
  const size_t nP1 = (size_t)B_ * N1 * 128;   // fmp1
  const size_t nF2 = (size_t)B_ * N1 * 256;   // fm2 / fm3
  const size_t nP2 = (size_t)B_ * N2 * 256;   // fmp2
  const size_t nF4 = (size_t)B_ * N2 * 512;
  const size_t nFg = (size_t)B_ * 512;
  const size_t nW1 = (size_t)512 * 1792;
  const size_t nW2 = (size_t)512 * 512;
  const size_t nH1 = (size_t)B_ * N0 * 512;
  ushort_t* f0h = (ushort_t*)alloc(nF0 * 2); ushort_t* f0l = (ushort_t*)alloc(nF0 * 2);
  ushort_t* f1h = (ushort_t*)alloc(nF0 * 2); ushort_t* f1l = (ushort_t*)alloc(nF0 * 2);
  ushort_t* p1h = (ushort_t*)alloc(nP1 * 2); ushort_t* p1l = (ushort_t*)alloc(nP1 * 2);
  ushort_t* f2h = (ushort_t*)alloc(nF2 * 2); ushort_t* f2l = (ushort_t*)alloc(nF2 * 2);
  ushort_t* f3h = (ushort_t*)alloc(nF2 * 2); ushort_t* f3l = (ushort_t*)alloc(nF2 * 2);
  ushort_t* p2h = (ushort_t*)alloc(nP2 * 2); ushort_t* p2l = (ushort_t*)alloc(nP2 * 2);
  ushort_t* f4h = (ushort_t*)alloc(nF4 * 2); ushort_t* f4l = (ushort_t*)alloc(nF4 * 2);
  ushort_t* fgh = (ushort_t*)alloc(nFg * 2); ushort_t* fgl = (ushort_t*)alloc(nFg * 2);
  ushort_t* w1h = (ushort_t*)alloc(nW1 * 2); ushort_t* w1l = (ushort_t*)alloc(nW1 * 2);
  ushort_t* w2h = (ushort_t*)alloc(nW2 * 2); ushort_t* w2l = (ushort_t*)alloc(nW2 * 2);
  ushort_t* h1h = (ushort_t*)alloc(nH1 * 2); ushort_t* h1l = (ushort_t*)alloc(nH1 * 2);
  ushort_t* w1th = (ushort_t*)alloc((size_t)256 * 128 * 2);
  ushort_t* w1tl = (ushort_t*)alloc((size_t)256 * 128 * 2);
  ushort_t* w2th = (ushort_t*)alloc((size_t)512 * 128 * 2);
  ushort_t* w2tl = (ushort_t*)alloc((size_t)512 * 128 * 2);
  ushort_t* w3th = (ushort_t*)alloc((size_t)512 * 256 * 2);
  ushort_t* w3tl = (ushort_t*)alloc((size_t)512 * 256 * 2);
  ushort_t* w4th = (ushort_t*)alloc((size_t)1024 * 256 * 2);
  ushort_t* w4tl = (ushort_t*)alloc((size_t)1024 * 256 * 2);

  const dim3 blk256(256);
  auto splitN = [&](const float* s, ushort_t* h, ushort_t* l, size_t n) {
    split_kernel<<<dim3((unsigned)((n + 255) / 256)), blk256, 0, stream>>>(s, h, l, (int)n);
  };
  auto tsplit = [&](const float* s, ushort_t* h, ushort_t* l, int K, int N) {
    transpose_split_kernel<<<dim3((K * N + 255) / 256), blk256, 0, stream>>>(s, h, l, K, N);
  };
  auto mgemm = [&](const ushort_t* Ah, const ushort_t* Al,
                   const ushort_t* Bh, const ushort_t* Bl, const float* bias,
                   int M, int Nn, int K, float* outF) {
    const dim3 grid(Nn / 128, M / 128);
    mfma_gemm_kernel<false, false, false><<<grid, blk256, 0, stream>>>(
        Ah, Al, nullptr, nullptr, nullptr, nullptr, nullptr, nullptr, nullptr,
        nullptr, nullptr, nullptr, nullptr, nullptr, nullptr, nullptr,
        Bh, Bl, bias, K, outF, nullptr, nullptr, Nn);
  };

  // ---- weight prep ----
  tsplit(w1, w1th, w1tl, 128, 256);
  tsplit(w2, w2th, w2tl, 128, 512);
  tsplit(w3, w3th, w3tl, 256, 512);
  tsplit(w4, w4th, w4tl, 256, 1024);
  splitN(cw1, w1h, w1l, nW1);   // cw1 already (N, K)
  splitN(cw2, w2h, w2l, nW2);

  // ---- level 0 (4096 verts) ----
  knn_wave_kernel<32><<<dim3(N0 / 4, B_), blk256, 0, stream>>>(vertices, nullptr, N0, N0, nb1);
  conv_surface_kernel<<<dim3(B_ * N0), dim3(128), 0, stream>>>(
      vertices, nb1, dir0, N0, 128, f0h, f0l);
  mgemm(f0h, f0l, w1th, w1tl, b1, B_ * N0, 256, 128, fbuf);
  conv_combine_kernel<<<dim3(B_ * N0), dim3(128), 0, stream>>>(
      fbuf, nb1, d1, vertices, N0, 128, 1, f1h, f1l);

  // ---- pool 1 -> 1024 (top-4 = first 4 of nb1 rows at sidx1) ----
  gather_verts_kernel<<<dim3((B_ * N1 * 3 + 255) / 256), blk256, 0, stream>>>(vertices, sidx1, N0, N1, vp1);
  pool_kernel<<<dim3((B_ * N1 * 128 + 255) / 256), blk256, 0, stream>>>(
      f1h, f1l, nb1, sidx1, N1, N0, 128, p1h, p1l);

  // ---- level 1 (1024 verts) ----
  knn_wave_kernel<32><<<dim3(N1 / 4, B_), blk256, 0, stream>>>(vp1, nullptr, N1, N1, nb2);
  mgemm(p1h, p1l, w2th, w2tl, b2, B_ * N1, 512, 128, fbuf);
  conv_combine_kernel<<<dim3(B_ * N1), dim3(256), 0, stream>>>(
      fbuf, nb2, d2, vp1, N1, 256, 1, f2h, f2l);
  mgemm(f2h, f2l, w3th, w3tl, b3, B_ * N1, 512, 256, fbuf);
  conv_combine_kernel<<<dim3(B_ * N1), dim3(256), 0, stream>>>(
      fbuf, nb2, d3, vp1, N1, 256, 1, f3h, f3l);

  // ---- pool 2 -> 256 ----
  gather_verts_kernel<<<dim3((B_ * N2 * 3 + 255) / 256), blk256, 0, stream>>>(vp1, sidx2, N1, N2, vp2);
  pool_kernel<<<dim3((B_ * N2 * 256 + 255) / 256), blk256, 0, stream>>>(
      f3h, f3l, nb2, sidx2, N2, N1, 256, p2h, p2l);

  // ---- level 2 (256 verts) ----
  knn_wave_kernel<32><<<dim3(N2 / 4, B_), blk256, 0, stream>>>(vp2, nullptr, N2, N2, nb3);
  mgemm(p2h, p2l, w4th, w4tl, b4, B_ * N2, 1024, 256, fbuf);
  conv_combine_kernel<<<dim3(B_ * N2), dim3(512), 0, stream>>>(
      fbuf, nb3, d4, vp2, N2, 512, 0, f4h, f4l);     // no relu on fm_4
  global_max_kernel<<<dim3((B_ * 512 + 255) / 256), blk256, 0, stream>>>(
      f4h, f4l, fgh, fgl);

  // ---- upsample indices ----
  nearest_kernel<<<dim3((B_ * N0 + 255) / 256), blk256, 0, stream>>>(vertices, vp1, N0, N1, near1);
  nearest_kernel<<<dim3((B_ * N0 + 255) / 256), blk256, 0, stream>>>(vertices, vp2, N0, N2, near2);

  // ---- head MLP ----
  mfma_gemm_kernel<true, true, true><<<dim3(512 / 128, (B_ * N0) / 128), blk256, 0, stream>>>(
      nullptr, nullptr,
      f0h, f0l, f1h, f1l, f2h, f2l, f3h, f3l, f4h, f4l, fgh, fgl,
      near1, near2, w1h, w1l, cb1, 1792, nullptr, h1h, h1l, 512);
  mfma_gemm_kernel<false, false, true><<<dim3(512 / 128, (B_ * N0) / 128), blk256, 0, stream>>>(
      h1h, h1l,
      nullptr, nullptr, nullptr, nullptr, nullptr, nullptr, nullptr, nullptr,
      nullptr, nullptr, nullptr, nullptr,
      nullptr, nullptr, w2h, w2l, cb2, 512, h2, nullptr, nullptr, 512);
  head_kernel<<<dim3((B_ * N0 * 13 + 255) / 256), blk256, 0, stream>>>(h2, cw3, cb3, (float*)d_out);
}

// Round 7
// 705.947 us; speedup vs baseline: 17.7392x; 1.1745x over previous
//
#include <hip/hip_runtime.h>
#include <cstdint>
#include <cstddef>

namespace {

typedef unsigned short ushort_t;
typedef __bf16 bf16x8 __attribute__((ext_vector_type(8)));
typedef float  f32x4  __attribute__((ext_vector_type(4)));

constexpr int B_ = 4;
constexpr int N0 = 4096;   // vertices per batch
constexpr int N1 = 1024;   // after pool1
constexpr int N2 = 256;    // after pool2

// ----------------------------------------------------- bf16 split utils ----
__device__ __forceinline__ ushort_t f2bf_rne(float x) {
  uint32_t b = __float_as_uint(x);
  b += 0x7FFFu + ((b >> 16) & 1u);
  return (ushort_t)(b >> 16);
}
__device__ __forceinline__ float bf2f(ushort_t h) {
  return __uint_as_float(((uint32_t)h) << 16);
}
__device__ __forceinline__ void split_store(float x, ushort_t* hi, ushort_t* lo,
                                            size_t i) {
  const ushort_t h = f2bf_rne(x);
  hi[i] = h;
  lo[i] = f2bf_rne(x - bf2f(h));
}

// src fp32 -> hi/lo bf16 planes
__global__ void split_kernel(const float* __restrict__ src,
                             ushort_t* __restrict__ hi, ushort_t* __restrict__ lo,
                             int n) {
  const int i = blockIdx.x * blockDim.x + threadIdx.x;
  if (i >= n) return;
  split_store(src[i], hi, lo, i);
}

// --------------------------------------- fused weight prep (one dispatch) --
// Segments: w1..w4 transposed-split (K,N)->(N,K); cw1/cw2 straight split.
__global__ void weight_prep_kernel(
    const float* __restrict__ w1, const float* __restrict__ w2,
    const float* __restrict__ w3, const float* __restrict__ w4,
    const float* __restrict__ cw1, const float* __restrict__ cw2,
    ushort_t* __restrict__ w1th, ushort_t* __restrict__ w1tl,
    ushort_t* __restrict__ w2th, ushort_t* __restrict__ w2tl,
    ushort_t* __restrict__ w3th, ushort_t* __restrict__ w3tl,
    ushort_t* __restrict__ w4th, ushort_t* __restrict__ w4tl,
    ushort_t* __restrict__ w1h, ushort_t* __restrict__ w1l,
    ushort_t* __restrict__ w2h, ushort_t* __restrict__ w2l)
{
  const int i = blockIdx.x * blockDim.x + threadIdx.x;
  // cumulative: 32768, 98304, 229376, 491520, 1409024, 1671168
  if (i < 32768) {                       // w1: K=128, N=256
    const int j = i, k = j % 128, n = j / 128;
    split_store(w1[(size_t)k * 256 + n], w1th, w1tl, (size_t)n * 128 + k);
  } else if (i < 98304) {                // w2: K=128, N=512
    const int j = i - 32768, k = j % 128, n = j / 128;
    split_store(w2[(size_t)k * 512 + n], w2th, w2tl, (size_t)n * 128 + k);
  } else if (i < 229376) {               // w3: K=256, N=512
    const int j = i - 98304, k = j % 256, n = j / 256;
    split_store(w3[(size_t)k * 512 + n], w3th, w3tl, (size_t)n * 256 + k);
  } else if (i < 491520) {               // w4: K=256, N=1024
    const int j = i - 229376, k = j % 256, n = j / 256;
    split_store(w4[(size_t)k * 1024 + n], w4th, w4tl, (size_t)n * 256 + k);
  } else if (i < 1409024) {              // cw1: already (N,K)
    const int j = i - 491520;
    split_store(cw1[j], w1h, w1l, j);
  } else if (i < 1671168) {              // cw2
    const int j = i - 1409024;
    split_store(cw2[j], w2h, w2l, j);
  }
}

// ------------------------------------------------- wave-cooperative KNN ----
__device__ __forceinline__ void bitonic_sort64(float& sd, int& si, int lane) {
#pragma unroll
  for (int kk = 2; kk <= 64; kk <<= 1) {
#pragma unroll
    for (int j = kk >> 1; j > 0; j >>= 1) {
      const float od = __shfl_xor(sd, j);
      const int   oi = __shfl_xor(si, j);
      const bool less    = (sd < od) || (sd == od && si < oi);
      const bool wantMin = ((lane & j) == 0) == ((lane & kk) == 0);
      if (wantMin != less) { sd = od; si = oi; }
    }
  }
}

// Merge LDS buffer (cnt valid, unsorted) into the sorted 64-wide list.
__device__ __forceinline__ void knn_flush(float& ld, int& li, float& tau,
                                          int cnt, const float* bufd,
                                          const int* bufi, int lane, int Km1) {
  float sd = (lane < cnt) ? bufd[lane] : INFINITY;
  int   si = (lane < cnt) ? bufi[lane] : 0x7fffffff;
  bitonic_sort64(sd, si, lane);
  const float rd = __shfl(sd, 63 - lane);
  const int   ri = __shfl(si, 63 - lane);
  const bool keep = (ld < rd) || (ld == rd && li < ri);
  float md = keep ? ld : rd;
  int   mi = keep ? li : ri;
#pragma unroll
  for (int j = 32; j > 0; j >>= 1) {
    const float od = __shfl_xor(md, j);
    const int   oi = __shfl_xor(mi, j);
    const bool less    = (md < od) || (md == od && mi < oi);
    const bool wantMin = ((lane & j) == 0);
    if (wantMin != less) { md = od; mi = oi; }
  }
  ld = md; li = mi;
  tau = __shfl(ld, Km1);
}

// One wave per query. LDS tiles hold (x,y,z,|p|^2); distance in the
// reference's inner-product form: d = |q|^2 + |p|^2 - 2 q.p  (3 FMA).
// Ballot filter vs tau -> buffered append -> bitonic flush (round-5 scheme).
template<int K>
__launch_bounds__(256)
__global__ void knn_wave_kernel(const float* __restrict__ pts,   // (B, C, 3)
                                const int*   __restrict__ qidx,  // (Q,) or null
                                int Q, int C,
                                int* __restrict__ out)           // (B, Q, K)
{
  constexpr int TILE = 512;
  __shared__ float4 sp[TILE];
  __shared__ float sbd[4][64];
  __shared__ int   sbi[4][64];
  const int b    = blockIdx.y;
  const int lane = threadIdx.x & 63;
  const int wid  = threadIdx.x >> 6;
  const int q    = blockIdx.x * 4 + wid;
  const int self = qidx ? qidx[q] : q;
  const float* pb = pts + (size_t)b * C * 3;
  const float qx = pb[self * 3 + 0];
  const float qy = pb[self * 3 + 1];
  const float qz = pb[self * 3 + 2];
  const float q2   = qx * qx + qy * qy + qz * qz;
  const float m2qx = -2.0f * qx, m2qy = -2.0f * qy, m2qz = -2.0f * qz;

  float ld = INFINITY; int li = 0x7fffffff;
  float tau = INFINITY;
  int cnt = 0;
  float* bufd = sbd[wid];
  int*   bufi = sbi[wid];

  for (int t0 = 0; t0 < C; t0 += TILE) {
    const int nt = (C - t0 < TILE) ? (C - t0) : TILE;
    __syncthreads();
    for (int i = threadIdx.x; i < nt; i += 256) {
      const float x = pb[(t0 + i) * 3 + 0];
      const float y = pb[(t0 + i) * 3 + 1];
      const float z = pb[(t0 + i) * 3 + 2];
      sp[i] = make_float4(x, y, z, x * x + y * y + z * z);
    }
    __syncthreads();
    for (int base = 0; base < nt; base += 64) {
      const int ci = t0 + base + lane;
      const float4 p = sp[base + lane];
      const float d = fmaf(m2qx, p.x, fmaf(m2qy, p.y, fmaf(m2qz, p.z, p.w + q2)));
      const bool valid = (base + lane < nt) && (ci != self);
      if (t0 == 0 && base == 0) {
        float sd = valid ? d : INFINITY;
        int   si = valid ? ci : 0x7fffffff;
        bitonic_sort64(sd, si, lane);
        ld = sd; li = si;
        tau = __shfl(ld, K - 1);
      } else {
        const bool cand = valid && (d < tau);
        const unsigned long long m = __ballot(cand);
        if (m) {
          const int c = __popcll(m);
          if (cnt + c > 64) {
            knn_flush(ld, li, tau, cnt, bufd, bufi, lane, K - 1);
            cnt = 0;
          }
          const int prefix = __popcll(m & ((1ull << lane) - 1ull));
          if (cand) { bufd[cnt + prefix] = d; bufi[cnt + prefix] = ci; }
          cnt += c;
        }
      }
    }
  }
  if (cnt > 0) knn_flush(ld, li, tau, cnt, bufd, bufi, lane, K - 1);
  if (lane < K) out[((size_t)b * Q + q) * K + lane] = li;
}

// -------------------------------------------------- wave-based nearest -----
// One wave per query; lane-local (d, idx) lexicographic min over candidate
// batches (no cross-lane work in the loop), 6-stage shfl reduce at the end.
// Ties -> lowest index == jnp.argmin.
__launch_bounds__(256)
__global__ void nearest_wave_kernel(const float* __restrict__ qpts, // (B*Q, 3)
                                    const float* __restrict__ cpts, // (B, C, 3)
                                    int Q, int C,
                                    int* __restrict__ out)          // (B*Q,)
{
  constexpr int TILE = 512;
  __shared__ float4 sp[TILE];
  const int lane = threadIdx.x & 63;
  const int wid  = threadIdx.x >> 6;
  const int q    = blockIdx.x * 4 + wid;        // global over B*Q
  const int b    = q / Q;                       // block-uniform (Q%4==0, aligned)
  const float qx = qpts[(size_t)q * 3 + 0];
  const float qy = qpts[(size_t)q * 3 + 1];
  const float qz = qpts[(size_t)q * 3 + 2];
  const float q2   = qx * qx + qy * qy + qz * qz;
  const float m2qx = -2.0f * qx, m2qy = -2.0f * qy, m2qz = -2.0f * qz;
  const float* pb = cpts + (size_t)b * C * 3;

  float best = INFINITY; int bi = 0x7fffffff;
  for (int t0 = 0; t0 < C; t0 += TILE) {
    const int nt = (C - t0 < TILE) ? (C - t0) : TILE;
    __syncthreads();
    for (int i = threadIdx.x; i < nt; i += 256) {
      const float x = pb[(t0 + i) * 3 + 0];
      const float y = pb[(t0 + i) * 3 + 1];
      const float z = pb[(t0 + i) * 3 + 2];
      sp[i] = make_float4(x, y, z, x * x + y * y + z * z);
    }
    __syncthreads();
    for (int base = 0; base < nt; base += 64) {
      if (base + lane < nt) {
        const float4 p = sp[base + lane];
        const float d = fmaf(m2qx, p.x, fmaf(m2qy, p.y, fmaf(m2qz, p.z, p.w + q2)));
        if (d < best) { best = d; bi = t0 + base + lane; }  // idx increases -> first min kept
      }
    }
  }
#pragma unroll
  for (int j = 1; j < 64; j <<= 1) {
    const float od = __shfl_xor(best, j);
    const int   oi = __shfl_xor(bi, j);
    if (od < best || (od == best && oi < bi)) { best = od; bi = oi; }
  }
  if (lane == 0) out[q] = bi;
}

// -------------------------------------------------------- conv_surface -----
__global__ void conv_surface_kernel(const float* __restrict__ verts,
                                    const int*   __restrict__ nb,
                                    const float* __restrict__ dir,
                                    int V, int C,
                                    ushort_t* __restrict__ outH,
                                    ushort_t* __restrict__ outL) {
  __shared__ float ux[32], uy[32], uz[32];
  const int bv = blockIdx.x;
  const int b = bv / V;
  const int v = bv - b * V;
  const float* vb = verts + (size_t)b * V * 3;
  if (threadIdx.x < 32) {
    const float cx = vb[v * 3 + 0], cy = vb[v * 3 + 1], cz = vb[v * 3 + 2];
    const int nidx = nb[(size_t)bv * 32 + threadIdx.x];
    const float dx = vb[nidx * 3 + 0] - cx;
    const float dy = vb[nidx * 3 + 1] - cy;
    const float dz = vb[nidx * 3 + 2] - cz;
    const float rn = 1.0f / fmaxf(sqrtf(dx * dx + dy * dy + dz * dz), 1e-12f);
    ux[threadIdx.x] = dx * rn; uy[threadIdx.x] = dy * rn; uz[threadIdx.x] = dz * rn;
  }
  __syncthreads();
  const int o = threadIdx.x;
  float d0 = dir[o], d1 = dir[C + o], d2 = dir[2 * C + o];
  const float rn = 1.0f / fmaxf(sqrtf(d0 * d0 + d1 * d1 + d2 * d2), 1e-12f);
  d0 *= rn; d1 *= rn; d2 *= rn;
  float m = -INFINITY;
#pragma unroll
  for (int n = 0; n < 32; ++n) {
    const float t = fmaxf(0.0f, fmaf(d2, uz[n], fmaf(d1, uy[n], d0 * ux[n])));
    m = fmaxf(m, t);
  }
  split_store(fmaxf(0.0f, m), outH, outL, (size_t)bv * C + o);
}

// -------------------------------------------------------- conv_combine -----
__global__ void conv_combine_kernel(const float* __restrict__ f,    // (B,V,2C)
                                    const int*   __restrict__ nb,
                                    const float* __restrict__ dir,
                                    const float* __restrict__ verts,
                                    int V, int C, int relu,
                                    ushort_t* __restrict__ outH,
                                    ushort_t* __restrict__ outL) {
  __shared__ float ux[32], uy[32], uz[32];
  __shared__ int snb[32];
  const int bv = blockIdx.x;
  const int b = bv / V;
  const int v = bv - b * V;
  const float* vb = verts + (size_t)b * V * 3;
  if (threadIdx.x < 32) {
    const float cx = vb[v * 3 + 0], cy = vb[v * 3 + 1], cz = vb[v * 3 + 2];
    const int nidx = nb[(size_t)bv * 32 + threadIdx.x];
    snb[threadIdx.x] = nidx;
    const float dx = vb[nidx * 3 + 0] - cx;
    const float dy = vb[nidx * 3 + 1] - cy;
    const float dz = vb[nidx * 3 + 2] - cz;
    const float rn = 1.0f / fmaxf(sqrtf(dx * dx + dy * dy + dz * dz), 1e-12f);
    ux[threadIdx.x] = dx * rn; uy[threadIdx.x] = dy * rn; uz[threadIdx.x] = dz * rn;
  }
  __syncthreads();
  const int o = threadIdx.x;
  float d0 = dir[o], d1 = dir[C + o], d2 = dir[2 * C + o];
  const float rn = 1.0f / fmaxf(sqrtf(d0 * d0 + d1 * d1 + d2 * d2), 1e-12f);
  d0 *= rn; d1 *= rn; d2 *= rn;
  const float* fb = f + (size_t)b * V * 2 * C;
  float m = -INFINITY;
#pragma unroll 8
  for (int n = 0; n < 32; ++n) {
    const float t = fmaxf(0.0f, fmaf(d2, uz[n], fmaf(d1, uy[n], d0 * ux[n])));
    const float s = fb[(size_t)snb[n] * 2 * C + C + o];
    m = fmaxf(m, t * s);
  }
  float r = fb[(size_t)v * 2 * C + o] + m;
  if (relu) r = fmaxf(r, 0.0f);
  split_store(r, outH, outL, (size_t)bv * C + o);
}

// ---------------------------------------------------------------- pool -----
__global__ void pool_kernel(const ushort_t* __restrict__ fmH,
                            const ushort_t* __restrict__ fmL,
                            const int*   __restrict__ nb,   // (B, Vsrc, 32)
                            const int*   __restrict__ sidx, // (Q,)
                            int Q, int Vsrc, int C,
                            ushort_t* __restrict__ outH,
                            ushort_t* __restrict__ outL) {
  const int i = blockIdx.x * blockDim.x + threadIdx.x;
  if (i >= B_ * Q * C) return;
  const int c = i % C;
  const int q = (i / C) % Q;
  const int b = i / (C * Q);
  const int* nn = nb + ((size_t)b * Vsrc + sidx[q]) * 32;
  const size_t fb = (size_t)b * Vsrc * C;
  float m = -INFINITY;
#pragma unroll
  for (int t = 0; t < 4; ++t) {
    const size_t idx = fb + (size_t)nn[t] * C + c;
    m = fmaxf(m, bf2f(fmH[idx]) + bf2f(fmL[idx]));
  }
  split_store(m, outH, outL, (size_t)i);
}

__global__ void gather_verts_kernel(const float* __restrict__ src,
                                    const int* __restrict__ idx,
                                    int Vsrc, int Q, float* __restrict__ dst) {
  const int i = blockIdx.x * blockDim.x + threadIdx.x;
  if (i >= B_ * Q * 3) return;
  const int c = i % 3;
  const int q = (i / 3) % Q;
  const int b = i / (3 * Q);
  dst[i] = src[((size_t)b * Vsrc + idx[q]) * 3 + c];
}

__global__ void global_max_kernel(const ushort_t* __restrict__ fmH,
                                  const ushort_t* __restrict__ fmL,
                                  ushort_t* __restrict__ outH,
                                  ushort_t* __restrict__ outL) {
  const int i = blockIdx.x * blockDim.x + threadIdx.x;
  if (i >= B_ * 512) return;
  const int c = i % 512;
  const int b = i / 512;
  const size_t base = (size_t)b * 256 * 512 + c;
  float m = -INFINITY;
  for (int v = 0; v < 256; ++v) {
    const size_t idx = base + (size_t)v * 512;
    m = fmaxf(m, bf2f(fmH[idx]) + bf2f(fmL[idx]));
  }
  split_store(m, outH, outL, (size_t)i);
}

// ------------------------------------------- split-bf16 MFMA GEMM ----------
constexpr int LDT = 40;  // LDS row stride in ushorts (32 + 8 pad)

template<bool FUSE, bool SPLITOUT, bool RELU>
__launch_bounds__(256)
__global__ void mfma_gemm_kernel(
    const ushort_t* __restrict__ Ahi, const ushort_t* __restrict__ Alo,
    const ushort_t* __restrict__ f0h, const ushort_t* __restrict__ f0l,
    const ushort_t* __restrict__ f1h, const ushort_t* __restrict__ f1l,
    const ushort_t* __restrict__ f2h, const ushort_t* __restrict__ f2l,
    const ushort_t* __restrict__ f3h, const ushort_t* __restrict__ f3l,
    const ushort_t* __restrict__ f4h, const ushort_t* __restrict__ f4l,
    const ushort_t* __restrict__ fgh, const ushort_t* __restrict__ fgl,
    const int* __restrict__ near1, const int* __restrict__ near2,
    const ushort_t* __restrict__ Bhi, const ushort_t* __restrict__ Blo,
    const float* __restrict__ bias, int K,
    float* __restrict__ outF, ushort_t* __restrict__ outHi,
    ushort_t* __restrict__ outLo, int Nn)
{
  __shared__ ushort_t As_h[128 * LDT];
  __shared__ ushort_t As_l[128 * LDT];
  __shared__ ushort_t Bs_h[128 * LDT];
  __shared__ ushort_t Bs_l[128 * LDT];

  const int tid  = threadIdx.x;
  const int lane = tid & 63;
  const int wv   = tid >> 6;
  const int wr   = wv >> 1, wc = wv & 1;
  const int quad = lane >> 4, ml = lane & 15;
  const int m0 = blockIdx.y * 128, n0 = blockIdx.x * 128;

  const int r  = tid >> 1;         // staging row 0..127
  const int hh = (tid & 1) * 16;   // 16-elem half of BK=32

  int fb = 0, r1 = 0, r2 = 0;
  if (FUSE) {
    const int m = m0 + r;
    fb = m >> 12;                  // / 4096
    r1 = near1[m];
    r2 = near2[m];
  }

  f32x4 acc[4][4];
#pragma unroll
  for (int i = 0; i < 4; ++i)
#pragma unroll
    for (int j = 0; j < 4; ++j) acc[i][j] = f32x4{0.f, 0.f, 0.f, 0.f};

  for (int k0 = 0; k0 < K; k0 += 32) {
    const int k = k0 + hh;
    uint4 a0h, a1h, a0l, a1l;
    {
      const ushort_t *sh, *sl; size_t off;
      if (FUSE) {
        const int m = m0 + r;
        if (k < 128)       { sh = f0h; sl = f0l; off = (size_t)m * 128 + k; }
        else if (k < 256)  { sh = f1h; sl = f1l; off = (size_t)m * 128 + (k - 128); }
        else if (k < 512)  { sh = f2h; sl = f2l; off = ((size_t)fb * 1024 + r1) * 256 + (k - 256); }
        else if (k < 768)  { sh = f3h; sl = f3l; off = ((size_t)fb * 1024 + r1) * 256 + (k - 512); }
        else if (k < 1280) { sh = f4h; sl = f4l; off = ((size_t)fb * 256 + r2) * 512 + (k - 768); }
        else               { sh = fgh; sl = fgl; off = (size_t)fb * 512 + (k - 1280); }
      } else {
        sh = Ahi; sl = Alo; off = (size_t)(m0 + r) * K + k;
      }
      a0h = *(const uint4*)(sh + off); a1h = *(const uint4*)(sh + off + 8);
      a0l = *(const uint4*)(sl + off); a1l = *(const uint4*)(sl + off + 8);
    }
    uint4 b0h, b1h, b0l, b1l;
    {
      const size_t off = (size_t)(n0 + r) * K + k;
      b0h = *(const uint4*)(Bhi + off); b1h = *(const uint4*)(Bhi + off + 8);
      b0l = *(const uint4*)(Blo + off); b1l = *(const uint4*)(Blo + off + 8);
    }
    __syncthreads();   // previous iteration's fragment reads complete
    *(uint4*)&As_h[r * LDT + hh]     = a0h;
    *(uint4*)&As_h[r * LDT + hh + 8] = a1h;
    *(uint4*)&As_l[r * LDT + hh]     = a0l;
    *(uint4*)&As_l[r * LDT + hh + 8] = a1l;
    *(uint4*)&Bs_h[r * LDT + hh]     = b0h;
    *(uint4*)&Bs_h[r * LDT + hh + 8] = b1h;
    *(uint4*)&Bs_l[r * LDT + hh]     = b0l;
    *(uint4*)&Bs_l[r * LDT + hh + 8] = b1l;
    __syncthreads();

    bf16x8 ah[4], al[4], bh[4], bl[4];
#pragma unroll
    for (int i = 0; i < 4; ++i) {
      const int row = wr * 64 + i * 16 + ml;
      ah[i] = *(const bf16x8*)&As_h[row * LDT + quad * 8];
      al[i] = *(const bf16x8*)&As_l[row * LDT + quad * 8];
    }
#pragma unroll
    for (int j = 0; j < 4; ++j) {
      const int row = wc * 64 + j * 16 + ml;
      bh[j] = *(const bf16x8*)&Bs_h[row * LDT + quad * 8];
      bl[j] = *(const bf16x8*)&Bs_l[row * LDT + quad * 8];
    }
#pragma unroll
    for (int i = 0; i < 4; ++i)
#pragma unroll
      for (int j = 0; j < 4; ++j) {
        acc[i][j] = __builtin_amdgcn_mfma_f32_16x16x32_bf16(al[i], bh[j], acc[i][j], 0, 0, 0);
        acc[i][j] = __builtin_amdgcn_mfma_f32_16x16x32_bf16(ah[i], bl[j], acc[i][j], 0, 0, 0);
        acc[i][j] = __builtin_amdgcn_mfma_f32_16x16x32_bf16(ah[i], bh[j], acc[i][j], 0, 0, 0);
      }
  }

  // epilogue: C/D mapping col=lane&15, row=quad*4+reg (m89)
#pragma unroll
  for (int i = 0; i < 4; ++i)
#pragma unroll
    for (int j = 0; j < 4; ++j) {
      const int n = n0 + wc * 64 + j * 16 + ml;
      const float bv = bias[n];
#pragma unroll
      for (int reg = 0; reg < 4; ++reg) {
        const int m = m0 + wr * 64 + i * 16 + quad * 4 + reg;
        float r = acc[i][j][reg] + bv;
        if (RELU) r = fmaxf(r, 0.0f);
        if (SPLITOUT) {
          const ushort_t h = f2bf_rne(r);
          outHi[(size_t)m * Nn + n] = h;
          outLo[(size_t)m * Nn + n] = f2bf_rne(r - bf2f(h));
        } else {
          outF[(size_t)m * Nn + n] = r;
        }
      }
    }
}

// ---------------------------------------------------------------- head -----
__global__ void head_kernel(const float* __restrict__ h,
                            const float* __restrict__ cw,
                            const float* __restrict__ cb,
                            float* __restrict__ out) {
  const int i = blockIdx.x * blockDim.x + threadIdx.x;
  if (i >= B_ * N0 * 13) return;
  const int o = i % 13;
  const int row = i / 13;
  const float* hr = h + (size_t)row * 512;
  const float* wr = cw + (size_t)o * 512;
  float acc = cb[o];
  for (int k = 0; k < 512; ++k) acc = fmaf(hr[k], wr[k], acc);
  out[i] = acc;
}

} // namespace

extern "C" void kernel_launch(void* const* d_in, const int* in_sizes, int n_in,
                              void* d_out, int out_size, void* d_ws, size_t ws_size,
                              hipStream_t stream)
{
  const float* vertices = (const float*)d_in[0];
  const int*   sidx1    = (const int*)  d_in[1];
  const int*   sidx2    = (const int*)  d_in[2];
  const float* dir0     = (const float*)d_in[3];
  const float* w1 = (const float*)d_in[4];
  const float* b1 = (const float*)d_in[5];
  const float* d1 = (const float*)d_in[6];
  const float* w2 = (const float*)d_in[7];
  const float* b2 = (const float*)d_in[8];
  const float* d2 = (const float*)d_in[9];
  const float* w3 = (const float*)d_in[10];
  const float* b3 = (const float*)d_in[11];
  const float* d3 = (const float*)d_in[12];
  const float* w4 = (const float*)d_in[13];
  const float* b4 = (const float*)d_in[14];
  const float* d4 = (const float*)d_in[15];
  const float* cw1 = (const float*)d_in[16];
  const float* cb1 = (const float*)d_in[17];
  const float* cw2 = (const float*)d_in[18];
  const float* cb2 = (const float*)d_in[19];
  const float* cw3 = (const float*)d_in[20];
  const float* cb3 = (const float*)d_in[21];
  (void)in_sizes; (void)n_in; (void)out_size; (void)ws_size;

  char* ws = (char*)d_ws;
  size_t off = 0;
  auto alloc = [&](size_t bytes) -> void* {
    void* p = ws + off;
    off += (bytes + 255) & ~(size_t)255;
    return p;
  };

  int*   nb1   = (int*)  alloc((size_t)B_ * N0 * 32 * 4);
  int*   nb2   = (int*)  alloc((size_t)B_ * N1 * 32 * 4);
  int*   nb3   = (int*)  alloc((size_t)B_ * N2 * 32 * 4);
  float* vp1   = (float*)alloc((size_t)B_ * N1 * 3 * 4);
  float* vp2   = (float*)alloc((size_t)B_ * N2 * 3 * 4);
  int*   near1 = (int*)  alloc((size_t)B_ * N0 * 4);
  int*   near2 = (int*)  alloc((size_t)B_ * N0 * 4);
  float* h2    = (float*)alloc((size_t)B_ * N0 * 512 * 4);   // 32 MB
  float* fbuf  = (float*)alloc((size_t)B_ * N0 * 256 * 4);   // 16 MB

  const size_t nF0 = (size_t)B_ * N0 * 128;   // fm0 / fm1
  const size_t nP1 = (size_t)B_ * N1 * 128;   // fmp1
  const size_t nF2 = (size_t)B_ * N1 * 256;   // fm2 / fm3
  const size_t nP2 = (size_t)B_ * N2 * 256;   // fmp2
  const size_t nF4 = (size_t)B_ * N2 * 512;
  const size_t nFg = (size_t)B_ * 512;
  const size_t nW1 = (size_t)512 * 1792;
  const size_t nW2 = (size_t)512 * 512;
  const size_t nH1 = (size_t)B_ * N0 * 512;
  ushort_t* f0h = (ushort_t*)alloc(nF0 * 2); ushort_t* f0l = (ushort_t*)alloc(nF0 * 2);
  ushort_t* f1h = (ushort_t*)alloc(nF0 * 2); ushort_t* f1l = (ushort_t*)alloc(nF0 * 2);
  ushort_t* p1h = (ushort_t*)alloc(nP1 * 2); ushort_t* p1l = (ushort_t*)alloc(nP1 * 2);
  ushort_t* f2h = (ushort_t*)alloc(nF2 * 2); ushort_t* f2l = (ushort_t*)alloc(nF2 * 2);
  ushort_t* f3h = (ushort_t*)alloc(nF2 * 2); ushort_t* f3l = (ushort_t*)alloc(nF2 * 2);
  ushort_t* p2h = (ushort_t*)alloc(nP2 * 2); ushort_t* p2l = (ushort_t*)alloc(nP2 * 2);
  ushort_t* f4h = (ushort_t*)alloc(nF4 * 2); ushort_t* f4l = (ushort_t*)alloc(nF4 * 2);
  ushort_t* fgh = (ushort_t*)alloc(nFg * 2); ushort_t* fgl = (ushort_t*)alloc(nFg * 2);
  ushort_t* w1h = (ushort_t*)alloc(nW1 * 2); ushort_t* w1l = (ushort_t*)alloc(nW1 * 2);
  ushort_t* w2h = (ushort_t*)alloc(nW2 * 2); ushort_t* w2l = (ushort_t*)alloc(nW2 * 2);
  ushort_t* h1h = (ushort_t*)alloc(nH1 * 2); ushort_t* h1l = (ushort_t*)alloc(nH1 * 2);
  ushort_t* w1th = (ushort_t*)alloc((size_t)256 * 128 * 2);
  ushort_t* w1tl = (ushort_t*)alloc((size_t)256 * 128 * 2);
  ushort_t* w2th = (ushort_t*)alloc((size_t)512 * 128 * 2);
  ushort_t* w2tl = (ushort_t*)alloc((size_t)512 * 128 * 2);
  ushort_t* w3th = (ushort_t*)alloc((size_t)512 * 256 * 2);
  ushort_t* w3tl = (ushort_t*)alloc((size_t)512 * 256 * 2);
  ushort_t* w4th = (ushort_t*)alloc((size_t)1024 * 256 * 2);
  ushort_t* w4tl = (ushort_t*)alloc((size_t)1024 * 256 * 2);

  const dim3 blk256(256);
  auto mgemm = [&](const ushort_t* Ah, const ushort_t* Al,
                   const ushort_t* Bh, const ushort_t* Bl, const float* bias,
                   int M, int Nn, int K, float* outF) {
    const dim3 grid(Nn / 128, M / 128);
    mfma_gemm_kernel<false, false, false><<<grid, blk256, 0, stream>>>(
        Ah, Al, nullptr, nullptr, nullptr, nullptr, nullptr, nullptr, nullptr,
        nullptr, nullptr, nullptr, nullptr, nullptr, nullptr, nullptr,
        Bh, Bl, bias, K, outF, nullptr, nullptr, Nn);
  };

  // ---- weight prep: single fused dispatch ----
  weight_prep_kernel<<<dim3(6528), blk256, 0, stream>>>(
      w1, w2, w3, w4, cw1, cw2,
      w1th, w1tl, w2th, w2tl, w3th, w3tl, w4th, w4tl,
      w1h, w1l, w2h, w2l);

  // ---- level 0 (4096 verts) ----
  knn_wave_kernel<32><<<dim3(N0 / 4, B_), blk256, 0, stream>>>(vertices, nullptr, N0, N0, nb1);
  conv_surface_kernel<<<dim3(B_ * N0), dim3(128), 0, stream>>>(
      vertices, nb1, dir0, N0, 128, f0h, f0l);
  mgemm(f0h, f0l, w1th, w1tl, b1, B_ * N0, 256, 128, fbuf);
  conv_combine_kernel<<<dim3(B_ * N0), dim3(128), 0, stream>>>(
      fbuf, nb1, d1, vertices, N0, 128, 1, f1h, f1l);

  // ---- pool 1 -> 1024 (top-4 = first 4 of nb1 rows at sidx1) ----
  gather_verts_kernel<<<dim3((B_ * N1 * 3 + 255) / 256), blk256, 0, stream>>>(vertices, sidx1, N0, N1, vp1);
  pool_kernel<<<dim3((B_ * N1 * 128 + 255) / 256), blk256, 0, stream>>>(
      f1h, f1l, nb1, sidx1, N1, N0, 128, p1h, p1l);

  // ---- level 1 (1024 verts) ----
  knn_wave_kernel<32><<<dim3(N1 / 4, B_), blk256, 0, stream>>>(vp1, nullptr, N1, N1, nb2);
  mgemm(p1h, p1l, w2th, w2tl, b2, B_ * N1, 512, 128, fbuf);
  conv_combine_kernel<<<dim3(B_ * N1), dim3(256), 0, stream>>>(
      fbuf, nb2, d2, vp1, N1, 256, 1, f2h, f2l);
  mgemm(f2h, f2l, w3th, w3tl, b3, B_ * N1, 512, 256, fbuf);
  conv_combine_kernel<<<dim3(B_ * N1), dim3(256), 0, stream>>>(
      fbuf, nb2, d3, vp1, N1, 256, 1, f3h, f3l);

  // ---- pool 2 -> 256 ----
  gather_verts_kernel<<<dim3((B_ * N2 * 3 + 255) / 256), blk256, 0, stream>>>(vp1, sidx2, N1, N2, vp2);
  pool_kernel<<<dim3((B_ * N2 * 256 + 255) / 256), blk256, 0, stream>>>(
      f3h, f3l, nb2, sidx2, N2, N1, 256, p2h, p2l);

  // ---- level 2 (256 verts) ----
  knn_wave_kernel<32><<<dim3(N2 / 4, B_), blk256, 0, stream>>>(vp2, nullptr, N2, N2, nb3);
  mgemm(p2h, p2l, w4th, w4tl, b4, B_ * N2, 1024, 256, fbuf);
  conv_combine_kernel<<<dim3(B_ * N2), dim3(512), 0, stream>>>(
      fbuf, nb3, d4, vp2, N2, 512, 0, f4h, f4l);     // no relu on fm_4
  global_max_kernel<<<dim3((B_ * 512 + 255) / 256), blk256, 0, stream>>>(
      f4h, f4l, fgh, fgl);

  // ---- upsample indices (wave-based argmin) ----
  nearest_wave_kernel<<<dim3((B_ * N0) / 4), blk256, 0, stream>>>(vertices, vp1, N0, N1, near1);
  nearest_wave_kernel<<<dim3((B_ * N0) / 4), blk256, 0, stream>>>(vertices, vp2, N0, N2, near2);

  // ---- head MLP ----
  mfma_gemm_kernel<true, true, true><<<dim3(512 / 128, (B_ * N0) / 128), blk256, 0, stream>>>(
      nullptr, nullptr,
      f0h, f0l, f1h, f1l, f2h, f2l, f3h, f3l, f4h, f4l, fgh, fgl,
      near1, near2, w1h, w1l, cb1, 1792, nullptr, h1h, h1l, 512);
  mfma_gemm_kernel<false, false, true><<<dim3(512 / 128, (B_ * N0) / 128), blk256, 0, stream>>>(
      h1h, h1l,
      nullptr, nullptr, nullptr, nullptr, nullptr, nullptr, nullptr, nullptr,
      nullptr, nullptr, nullptr, nullptr,
      nullptr, nullptr, w2h, w2l, cb2, 512, h2, nullptr, nullptr, 512);
  head_kernel<<<dim3((B_ * N0 * 13 + 255) / 256), blk256, 0, stream>>>(h2, cw3, cb3, (float*)d_out);
}

// Round 8
// 690.215 us; speedup vs baseline: 18.1435x; 1.0228x over previous
//
#include <hip/hip_runtime.h>
#include <cstdint>
#include <cstddef>

namespace {

typedef unsigned short ushort_t;
typedef __bf16 bf16x8 __attribute__((ext_vector_type(8)));
typedef float  f32x4  __attribute__((ext_vector_type(4)));

constexpr int B_ = 4;
constexpr int N0 = 4096;   // vertices per batch
constexpr int N1 = 1024;   // after pool1
constexpr int N2 = 256;    // after pool2

// ----------------------------------------------------- bf16 split utils ----
__device__ __forceinline__ ushort_t f2bf_rne(float x) {
  uint32_t b = __float_as_uint(x);
  b += 0x7FFFu + ((b >> 16) & 1u);
  return (ushort_t)(b >> 16);
}
__device__ __forceinline__ float bf2f(ushort_t h) {
  return __uint_as_float(((uint32_t)h) << 16);
}
__device__ __forceinline__ void split_store(float x, ushort_t* hi, ushort_t* lo,
                                            size_t i) {
  const ushort_t h = f2bf_rne(x);
  hi[i] = h;
  lo[i] = f2bf_rne(x - bf2f(h));
}

// --------------------------------------- fused weight prep (one dispatch) --
__global__ void weight_prep_kernel(
    const float* __restrict__ w1, const float* __restrict__ w2,
    const float* __restrict__ w3, const float* __restrict__ w4,
    const float* __restrict__ cw1, const float* __restrict__ cw2,
    ushort_t* __restrict__ w1th, ushort_t* __restrict__ w1tl,
    ushort_t* __restrict__ w2th, ushort_t* __restrict__ w2tl,
    ushort_t* __restrict__ w3th, ushort_t* __restrict__ w3tl,
    ushort_t* __restrict__ w4th, ushort_t* __restrict__ w4tl,
    ushort_t* __restrict__ w1h, ushort_t* __restrict__ w1l,
    ushort_t* __restrict__ w2h, ushort_t* __restrict__ w2l)
{
  const int i = blockIdx.x * blockDim.x + threadIdx.x;
  if (i < 32768) {                       // w1: K=128, N=256
    const int j = i, k = j % 128, n = j / 128;
    split_store(w1[(size_t)k * 256 + n], w1th, w1tl, (size_t)n * 128 + k);
  } else if (i < 98304) {                // w2: K=128, N=512
    const int j = i - 32768, k = j % 128, n = j / 128;
    split_store(w2[(size_t)k * 512 + n], w2th, w2tl, (size_t)n * 128 + k);
  } else if (i < 229376) {               // w3: K=256, N=512
    const int j = i - 98304, k = j % 256, n = j / 256;
    split_store(w3[(size_t)k * 512 + n], w3th, w3tl, (size_t)n * 256 + k);
  } else if (i < 491520) {               // w4: K=256, N=1024
    const int j = i - 229376, k = j % 256, n = j / 256;
    split_store(w4[(size_t)k * 1024 + n], w4th, w4tl, (size_t)n * 256 + k);
  } else if (i < 1409024) {              // cw1: already (N,K)
    const int j = i - 491520;
    split_store(cw1[j], w1h, w1l, j);
  } else if (i < 1671168) {              // cw2
    const int j = i - 1409024;
    split_store(cw2[j], w2h, w2l, j);
  }
}

// ------------------------------------------------- wave-cooperative KNN ----
__device__ __forceinline__ void bitonic_sort64(float& sd, int& si, int lane) {
#pragma unroll
  for (int kk = 2; kk <= 64; kk <<= 1) {
#pragma unroll
    for (int j = kk >> 1; j > 0; j >>= 1) {
      const float od = __shfl_xor(sd, j);
      const int   oi = __shfl_xor(si, j);
      const bool less    = (sd < od) || (sd == od && si < oi);
      const bool wantMin = ((lane & j) == 0) == ((lane & kk) == 0);
      if (wantMin != less) { sd = od; si = oi; }
    }
  }
}

// Merge LDS buffer (cnt valid, unsorted) into the sorted 64-wide list.
__device__ __forceinline__ void knn_flush(float& ld, int& li, float& tau,
                                          int cnt, const float* bufd,
                                          const int* bufi, int lane, int Km1) {
  float sd = (lane < cnt) ? bufd[lane] : INFINITY;
  int   si = (lane < cnt) ? bufi[lane] : 0x7fffffff;
  bitonic_sort64(sd, si, lane);
  const float rd = __shfl(sd, 63 - lane);
  const int   ri = __shfl(si, 63 - lane);
  const bool keep = (ld < rd) || (ld == rd && li < ri);
  float md = keep ? ld : rd;
  int   mi = keep ? li : ri;
#pragma unroll
  for (int j = 32; j > 0; j >>= 1) {
    const float od = __shfl_xor(md, j);
    const int   oi = __shfl_xor(mi, j);
    const bool less    = (md < od) || (md == od && mi < oi);
    const bool wantMin = ((lane & j) == 0);
    if (wantMin != less) { md = od; mi = oi; }
  }
  ld = md; li = mi;
  tau = __shfl(ld, Km1);
}

// 8 waves/block (one query each); LDS tiles of (x,y,z,|p|^2) shared by all 8.
// Inner scan unrolled x2 (128 candidates/iter, paired ballots). C % TILE == 0
// and TILE % 128 == 0 for every call -> no tails except the peeled seed batch.
template<int K, int TILE>
__launch_bounds__(512)
__global__ void knn_wave_kernel(const float* __restrict__ pts,   // (B, C, 3)
                                int Q, int C,
                                int* __restrict__ out)           // (B, Q, K)
{
  __shared__ float4 sp[TILE];
  __shared__ float sbd[8][64];
  __shared__ int   sbi[8][64];
  const int b    = blockIdx.y;
  const int lane = threadIdx.x & 63;
  const int wid  = threadIdx.x >> 6;
  const int q    = blockIdx.x * 8 + wid;
  const int self = q;
  const float* pb = pts + (size_t)b * C * 3;
  const float qx = pb[self * 3 + 0];
  const float qy = pb[self * 3 + 1];
  const float qz = pb[self * 3 + 2];
  const float q2   = qx * qx + qy * qy + qz * qz;
  const float m2qx = -2.0f * qx, m2qy = -2.0f * qy, m2qz = -2.0f * qz;

  float ld = INFINITY; int li = 0x7fffffff;
  float tau = INFINITY;
  int cnt = 0;
  float* bufd = sbd[wid];
  int*   bufi = sbi[wid];

  auto append = [&](unsigned long long m, bool cand, float d, int ci) {
    const int c = __popcll(m);
    if (cnt + c > 64) {
      knn_flush(ld, li, tau, cnt, bufd, bufi, lane, K - 1);
      cnt = 0;
    }
    const int prefix = __popcll(m & ((1ull << lane) - 1ull));
    if (cand) { bufd[cnt + prefix] = d; bufi[cnt + prefix] = ci; }
    cnt += c;
  };

  for (int t0 = 0; t0 < C; t0 += TILE) {
    __syncthreads();
    for (int i = threadIdx.x; i < TILE; i += 512) {
      const float x = pb[(t0 + i) * 3 + 0];
      const float y = pb[(t0 + i) * 3 + 1];
      const float z = pb[(t0 + i) * 3 + 2];
      sp[i] = make_float4(x, y, z, x * x + y * y + z * z);
    }
    __syncthreads();
    int base = 0;
    if (t0 == 0) {
      // peeled seed batch: bitonic sort of first 64 (stable lowest-index ties)
      const float4 p = sp[lane];
      const float d = fmaf(m2qx, p.x, fmaf(m2qy, p.y, fmaf(m2qz, p.z, p.w + q2)));
      const bool valid = (lane != self);
      float sd = valid ? d : INFINITY;
      int   si = valid ? lane : 0x7fffffff;
      bitonic_sort64(sd, si, lane);
      ld = sd; li = si;
      tau = __shfl(ld, K - 1);
      base = 64;
    }
    for (; base + 128 <= TILE; base += 128) {
      const int ci0 = t0 + base + lane;
      const int ci1 = ci0 + 64;
      const float4 p0 = sp[base + lane];
      const float4 p1 = sp[base + 64 + lane];
      const float d0 = fmaf(m2qx, p0.x, fmaf(m2qy, p0.y, fmaf(m2qz, p0.z, p0.w + q2)));
      const float d1 = fmaf(m2qx, p1.x, fmaf(m2qy, p1.y, fmaf(m2qz, p1.z, p1.w + q2)));
      const bool c0 = (ci0 != self) && (d0 < tau);
      const bool c1 = (ci1 != self) && (d1 < tau);
      const unsigned long long m0 = __ballot(c0);
      const unsigned long long m1 = __ballot(c1);
      if (m0) append(m0, c0, d0, ci0);
      if (m1) append(m1, c1, d1, ci1);   // stale-tau entries pruned at flush
    }
    if (base < TILE) {                   // single 64-tail (first tile only)
      const int ci = t0 + base + lane;
      const float4 p = sp[base + lane];
      const float d = fmaf(m2qx, p.x, fmaf(m2qy, p.y, fmaf(m2qz, p.z, p.w + q2)));
      const bool c = (ci != self) && (d < tau);
      const unsigned long long m = __ballot(c);
      if (m) append(m, c, d, ci);
    }
  }
  if (cnt > 0) knn_flush(ld, li, tau, cnt, bufd, bufi, lane, K - 1);
  if (lane < K) out[((size_t)b * Q + q) * K + lane] = li;
}

// -------------------------------------------- dual-level wave argmin -------
// blockIdx.y = 0: candidates vp1 (C=1024); 1: vp2 (C=256). One wave/query,
// whole candidate set staged once; ties -> lowest index == jnp.argmin.
__launch_bounds__(256)
__global__ void nearest_dual_kernel(const float* __restrict__ qpts, // (B*N0,3)
                                    const float* __restrict__ cpts1,
                                    const float* __restrict__ cpts2,
                                    int* __restrict__ out1,
                                    int* __restrict__ out2)
{
  __shared__ float4 sp[1024];
  const int lvl = blockIdx.y;
  const int C = lvl ? N2 : N1;
  const float* cpts = lvl ? cpts2 : cpts1;
  int* out = lvl ? out2 : out1;
  const int lane = threadIdx.x & 63;
  const int wid  = threadIdx.x >> 6;
  const int q    = blockIdx.x * 4 + wid;        // over B_*N0
  const int b    = q >> 12;                     // / 4096
  const float qx = qpts[(size_t)q * 3 + 0];
  const float qy = qpts[(size_t)q * 3 + 1];
  const float qz = qpts[(size_t)q * 3 + 2];
  const float q2   = qx * qx + qy * qy + qz * qz;
  const float m2qx = -2.0f * qx, m2qy = -2.0f * qy, m2qz = -2.0f * qz;
  const float* pb = cpts + (size_t)b * C * 3;

  for (int i = threadIdx.x; i < C; i += 256) {
    const float x = pb[i * 3 + 0];
    const float y = pb[i * 3 + 1];
    const float z = pb[i * 3 + 2];
    sp[i] = make_float4(x, y, z, x * x + y * y + z * z);
  }
  __syncthreads();
  float best = INFINITY; int bi = 0x7fffffff;
  for (int base = 0; base < C; base += 64) {
    const float4 p = sp[base + lane];
    const float d = fmaf(m2qx, p.x, fmaf(m2qy, p.y, fmaf(m2qz, p.z, p.w + q2)));
    if (d < best) { best = d; bi = base + lane; }  // idx ascends -> first min kept
  }
#pragma unroll
  for (int j = 1; j < 64; j <<= 1) {
    const float od = __shfl_xor(best, j);
    const int   oi = __shfl_xor(bi, j);
    if (od < best || (od == best && oi < bi)) { best = od; bi = oi; }
  }
  if (lane == 0) out[q] = bi;
}

// -------------------------------------------------------- conv_surface -----
__global__ void conv_surface_kernel(const float* __restrict__ verts,
                                    const int*   __restrict__ nb,
                                    const float* __restrict__ dir,
                                    int V, int C,
                                    ushort_t* __restrict__ outH,
                                    ushort_t* __restrict__ outL) {
  __shared__ float ux[32], uy[32], uz[32];
  const int bv = blockIdx.x;
  const int b = bv / V;
  const int v = bv - b * V;
  const float* vb = verts + (size_t)b * V * 3;
  if (threadIdx.x < 32) {
    const float cx = vb[v * 3 + 0], cy = vb[v * 3 + 1], cz = vb[v * 3 + 2];
    const int nidx = nb[(size_t)bv * 32 + threadIdx.x];
    const float dx = vb[nidx * 3 + 0] - cx;
    const float dy = vb[nidx * 3 + 1] - cy;
    const float dz = vb[nidx * 3 + 2] - cz;
    const float rn = 1.0f / fmaxf(sqrtf(dx * dx + dy * dy + dz * dz), 1e-12f);
    ux[threadIdx.x] = dx * rn; uy[threadIdx.x] = dy * rn; uz[threadIdx.x] = dz * rn;
  }
  __syncthreads();
  const int o = threadIdx.x;
  float d0 = dir[o], d1 = dir[C + o], d2 = dir[2 * C + o];
  const float rn = 1.0f / fmaxf(sqrtf(d0 * d0 + d1 * d1 + d2 * d2), 1e-12f);
  d0 *= rn; d1 *= rn; d2 *= rn;
  float m = -INFINITY;
#pragma unroll
  for (int n = 0; n < 32; ++n) {
    const float t = fmaxf(0.0f, fmaf(d2, uz[n], fmaf(d1, uy[n], d0 * ux[n])));
    m = fmaxf(m, t);
  }
  split_store(fmaxf(0.0f, m), outH, outL, (size_t)bv * C + o);
}

// -------------------------------------------------------- conv_combine -----
__global__ void conv_combine_kernel(const float* __restrict__ f,    // (B,V,2C)
                                    const int*   __restrict__ nb,
                                    const float* __restrict__ dir,
                                    const float* __restrict__ verts,
                                    int V, int C, int relu,
                                    ushort_t* __restrict__ outH,
                                    ushort_t* __restrict__ outL) {
  __shared__ float ux[32], uy[32], uz[32];
  __shared__ int snb[32];
  const int bv = blockIdx.x;
  const int b = bv / V;
  const int v = bv - b * V;
  const float* vb = verts + (size_t)b * V * 3;
  if (threadIdx.x < 32) {
    const float cx = vb[v * 3 + 0], cy = vb[v * 3 + 1], cz = vb[v * 3 + 2];
    const int nidx = nb[(size_t)bv * 32 + threadIdx.x];
    snb[threadIdx.x] = nidx;
    const float dx = vb[nidx * 3 + 0] - cx;
    const float dy = vb[nidx * 3 + 1] - cy;
    const float dz = vb[nidx * 3 + 2] - cz;
    const float rn = 1.0f / fmaxf(sqrtf(dx * dx + dy * dy + dz * dz), 1e-12f);
    ux[threadIdx.x] = dx * rn; uy[threadIdx.x] = dy * rn; uz[threadIdx.x] = dz * rn;
  }
  __syncthreads();
  const int o = threadIdx.x;
  float d0 = dir[o], d1 = dir[C + o], d2 = dir[2 * C + o];
  const float rn = 1.0f / fmaxf(sqrtf(d0 * d0 + d1 * d1 + d2 * d2), 1e-12f);
  d0 *= rn; d1 *= rn; d2 *= rn;
  const float* fb = f + (size_t)b * V * 2 * C;
  float m = -INFINITY;
#pragma unroll 8
  for (int n = 0; n < 32; ++n) {
    const float t = fmaxf(0.0f, fmaf(d2, uz[n], fmaf(d1, uy[n], d0 * ux[n])));
    const float s = fb[(size_t)snb[n] * 2 * C + C + o];
    m = fmaxf(m, t * s);
  }
  float r = fb[(size_t)v * 2 * C + o] + m;
  if (relu) r = fmaxf(r, 0.0f);
  split_store(r, outH, outL, (size_t)bv * C + o);
}

// ---------------------------------------------------------------- pool -----
__global__ void pool_kernel(const ushort_t* __restrict__ fmH,
                            const ushort_t* __restrict__ fmL,
                            const int*   __restrict__ nb,   // (B, Vsrc, 32)
                            const int*   __restrict__ sidx, // (Q,)
                            int Q, int Vsrc, int C,
                            ushort_t* __restrict__ outH,
                            ushort_t* __restrict__ outL) {
  const int i = blockIdx.x * blockDim.x + threadIdx.x;
  if (i >= B_ * Q * C) return;
  const int c = i % C;
  const int q = (i / C) % Q;
  const int b = i / (C * Q);
  const int* nn = nb + ((size_t)b * Vsrc + sidx[q]) * 32;
  const size_t fb = (size_t)b * Vsrc * C;
  float m = -INFINITY;
#pragma unroll
  for (int t = 0; t < 4; ++t) {
    const size_t idx = fb + (size_t)nn[t] * C + c;
    m = fmaxf(m, bf2f(fmH[idx]) + bf2f(fmL[idx]));
  }
  split_store(m, outH, outL, (size_t)i);
}

__global__ void gather_verts_kernel(const float* __restrict__ src,
                                    const int* __restrict__ idx,
                                    int Vsrc, int Q, float* __restrict__ dst) {
  const int i = blockIdx.x * blockDim.x + threadIdx.x;
  if (i >= B_ * Q * 3) return;
  const int c = i % 3;
  const int q = (i / 3) % Q;
  const int b = i / (3 * Q);
  dst[i] = src[((size_t)b * Vsrc + idx[q]) * 3 + c];
}

__global__ void global_max_kernel(const ushort_t* __restrict__ fmH,
                                  const ushort_t* __restrict__ fmL,
                                  ushort_t* __restrict__ outH,
                                  ushort_t* __restrict__ outL) {
  const int i = blockIdx.x * blockDim.x + threadIdx.x;
  if (i >= B_ * 512) return;
  const int c = i % 512;
  const int b = i / 512;
  const size_t base = (size_t)b * 256 * 512 + c;
  float m = -INFINITY;
  for (int v = 0; v < 256; ++v) {
    const size_t idx = base + (size_t)v * 512;
    m = fmaxf(m, bf2f(fmH[idx]) + bf2f(fmL[idx]));
  }
  split_store(m, outH, outL, (size_t)i);
}

// ------------------------------------------- split-bf16 MFMA GEMM ----------
constexpr int LDT = 40;  // LDS row stride in ushorts (32 + 8 pad)

template<bool FUSE, bool SPLITOUT, bool RELU>
__launch_bounds__(256)
__global__ void mfma_gemm_kernel(
    const ushort_t* __restrict__ Ahi, const ushort_t* __restrict__ Alo,
    const ushort_t* __restrict__ f0h, const ushort_t* __restrict__ f0l,
    const ushort_t* __restrict__ f1h, const ushort_t* __restrict__ f1l,
    const ushort_t* __restrict__ f2h, const ushort_t* __restrict__ f2l,
    const ushort_t* __restrict__ f3h, const ushort_t* __restrict__ f3l,
    const ushort_t* __restrict__ f4h, const ushort_t* __restrict__ f4l,
    const ushort_t* __restrict__ fgh, const ushort_t* __restrict__ fgl,
    const int* __restrict__ near1, const int* __restrict__ near2,
    const ushort_t* __restrict__ Bhi, const ushort_t* __restrict__ Blo,
    const float* __restrict__ bias, int K,
    float* __restrict__ outF, ushort_t* __restrict__ outHi,
    ushort_t* __restrict__ outLo, int Nn)
{
  __shared__ ushort_t As_h[128 * LDT];
  __shared__ ushort_t As_l[128 * LDT];
  __shared__ ushort_t Bs_h[128 * LDT];
  __shared__ ushort_t Bs_l[128 * LDT];

  const int tid  = threadIdx.x;
  const int lane = tid & 63;
  const int wv   = tid >> 6;
  const int wr   = wv >> 1, wc = wv & 1;
  const int quad = lane >> 4, ml = lane & 15;
  const int m0 = blockIdx.y * 128, n0 = blockIdx.x * 128;

  const int r  = tid >> 1;         // staging row 0..127
  const int hh = (tid & 1) * 16;   // 16-elem half of BK=32

  int fb = 0, r1 = 0, r2 = 0;
  if (FUSE) {
    const int m = m0 + r;
    fb = m >> 12;                  // / 4096
    r1 = near1[m];
    r2 = near2[m];
  }

  f32x4 acc[4][4];
#pragma unroll
  for (int i = 0; i < 4; ++i)
#pragma unroll
    for (int j = 0; j < 4; ++j) acc[i][j] = f32x4{0.f, 0.f, 0.f, 0.f};

  for (int k0 = 0; k0 < K; k0 += 32) {
    const int k = k0 + hh;
    uint4 a0h, a1h, a0l, a1l;
    {
      const ushort_t *sh, *sl; size_t off;
      if (FUSE) {
        const int m = m0 + r;
        if (k < 128)       { sh = f0h; sl = f0l; off = (size_t)m * 128 + k; }
        else if (k < 256)  { sh = f1h; sl = f1l; off = (size_t)m * 128 + (k - 128); }
        else if (k < 512)  { sh = f2h; sl = f2l; off = ((size_t)fb * 1024 + r1) * 256 + (k - 256); }
        else if (k < 768)  { sh = f3h; sl = f3l; off = ((size_t)fb * 1024 + r1) * 256 + (k - 512); }
        else if (k < 1280) { sh = f4h; sl = f4l; off = ((size_t)fb * 256 + r2) * 512 + (k - 768); }
        else               { sh = fgh; sl = fgl; off = (size_t)fb * 512 + (k - 1280); }
      } else {
        sh = Ahi; sl = Alo; off = (size_t)(m0 + r) * K + k;
      }
      a0h = *(const uint4*)(sh + off); a1h = *(const uint4*)(sh + off + 8);
      a0l = *(const uint4*)(sl + off); a1l = *(const uint4*)(sl + off + 8);
    }
    uint4 b0h, b1h, b0l, b1l;
    {
      const size_t off = (size_t)(n0 + r) * K + k;
      b0h = *(const uint4*)(Bhi + off); b1h = *(const uint4*)(Bhi + off + 8);
      b0l = *(const uint4*)(Blo + off); b1l = *(const uint4*)(Blo + off + 8);
    }
    __syncthreads();   // previous iteration's fragment reads complete
    *(uint4*)&As_h[r * LDT + hh]     = a0h;
    *(uint4*)&As_h[r * LDT + hh + 8] = a1h;
    *(uint4*)&As_l[r * LDT + hh]     = a0l;
    *(uint4*)&As_l[r * LDT + hh + 8] = a1l;
    *(uint4*)&Bs_h[r * LDT + hh]     = b0h;
    *(uint4*)&Bs_h[r * LDT + hh + 8] = b1h;
    *(uint4*)&Bs_l[r * LDT + hh]     = b0l;
    *(uint4*)&Bs_l[r * LDT + hh + 8] = b1l;
    __syncthreads();

    bf16x8 ah[4], al[4], bh[4], bl[4];
#pragma unroll
    for (int i = 0; i < 4; ++i) {
      const int row = wr * 64 + i * 16 + ml;
      ah[i] = *(const bf16x8*)&As_h[row * LDT + quad * 8];
      al[i] = *(const bf16x8*)&As_l[row * LDT + quad * 8];
    }
#pragma unroll
    for (int j = 0; j < 4; ++j) {
      const int row = wc * 64 + j * 16 + ml;
      bh[j] = *(const bf16x8*)&Bs_h[row * LDT + quad * 8];
      bl[j] = *(const bf16x8*)&Bs_l[row * LDT + quad * 8];
    }
#pragma unroll
    for (int i = 0; i < 4; ++i)
#pragma unroll
      for (int j = 0; j < 4; ++j) {
        acc[i][j] = __builtin_amdgcn_mfma_f32_16x16x32_bf16(al[i], bh[j], acc[i][j], 0, 0, 0);
        acc[i][j] = __builtin_amdgcn_mfma_f32_16x16x32_bf16(ah[i], bl[j], acc[i][j], 0, 0, 0);
        acc[i][j] = __builtin_amdgcn_mfma_f32_16x16x32_bf16(ah[i], bh[j], acc[i][j], 0, 0, 0);
      }
  }

  // epilogue: C/D mapping col=lane&15, row=quad*4+reg (m89)
#pragma unroll
  for (int i = 0; i < 4; ++i)
#pragma unroll
    for (int j = 0; j < 4; ++j) {
      const int n = n0 + wc * 64 + j * 16 + ml;
      const float bv = bias[n];
#pragma unroll
      for (int reg = 0; reg < 4; ++reg) {
        const int m = m0 + wr * 64 + i * 16 + quad * 4 + reg;
        float r = acc[i][j][reg] + bv;
        if (RELU) r = fmaxf(r, 0.0f);
        if (SPLITOUT) {
          const ushort_t h = f2bf_rne(r);
          outHi[(size_t)m * Nn + n] = h;
          outLo[(size_t)m * Nn + n] = f2bf_rne(r - bf2f(h));
        } else {
          outF[(size_t)m * Nn + n] = r;
        }
      }
    }
}

// ---------------------------------------------------------------- head -----
__global__ void head_kernel(const float* __restrict__ h,
                            const float* __restrict__ cw,
                            const float* __restrict__ cb,
                            float* __restrict__ out) {
  const int i = blockIdx.x * blockDim.x + threadIdx.x;
  if (i >= B_ * N0 * 13) return;
  const int o = i % 13;
  const int row = i / 13;
  const float* hr = h + (size_t)row * 512;
  const float* wr = cw + (size_t)o * 512;
  float acc = cb[o];
  for (int k = 0; k < 512; ++k) acc = fmaf(hr[k], wr[k], acc);
  out[i] = acc;
}

} // namespace

extern "C" void kernel_launch(void* const* d_in, const int* in_sizes, int n_in,
                              void* d_out, int out_size, void* d_ws, size_t ws_size,
                              hipStream_t stream)
{
  const float* vertices = (const float*)d_in[0];
  const int*   sidx1    = (const int*)  d_in[1];
  const int*   sidx2    = (const int*)  d_in[2];
  const float* dir0     = (const float*)d_in[3];
  const float* w1 = (const float*)d_in[4];
  const float* b1 = (const float*)d_in[5];
  const float* d1 = (const float*)d_in[6];
  const float* w2 = (const float*)d_in[7];
  const float* b2 = (const float*)d_in[8];
  const float* d2 = (const float*)d_in[9];
  const float* w3 = (const float*)d_in[10];
  const float* b3 = (const float*)d_in[11];
  const float* d3 = (const float*)d_in[12];
  const float* w4 = (const float*)d_in[13];
  const float* b4 = (const float*)d_in[14];
  const float* d4 = (const float*)d_in[15];
  const float* cw1 = (const float*)d_in[16];
  const float* cb1 = (const float*)d_in[17];
  const float* cw2 = (const float*)d_in[18];
  const float* cb2 = (const float*)d_in[19];
  const float* cw3 = (const float*)d_in[20];
  const float* cb3 = (const float*)d_in[21];
  (void)in_sizes; (void)n_in; (void)out_size; (void)ws_size;

  char* ws = (char*)d_ws;
  size_t off = 0;
  auto alloc = [&](size_t bytes) -> void* {
    void* p = ws + off;
    off += (bytes + 255) & ~(size_t)255;
    return p;
  };

  int*   nb1   = (int*)  alloc((size_t)B_ * N0 * 32 * 4);
  int*   nb2   = (int*)  alloc((size_t)B_ * N1 * 32 * 4);
  int*   nb3   = (int*)  alloc((size_t)B_ * N2 * 32 * 4);
  float* vp1   = (float*)alloc((size_t)B_ * N1 * 3 * 4);
  float* vp2   = (float*)alloc((size_t)B_ * N2 * 3 * 4);
  int*   near1 = (int*)  alloc((size_t)B_ * N0 * 4);
  int*   near2 = (int*)  alloc((size_t)B_ * N0 * 4);
  float* h2    = (float*)alloc((size_t)B_ * N0 * 512 * 4);   // 32 MB
  float* fbuf  = (float*)alloc((size_t)B_ * N0 * 256 * 4);   // 16 MB

  const size_t nF0 = (size_t)B_ * N0 * 128;   // fm0 / fm1
  const size_t nP1 = (size_t)B_ * N1 * 128;   // fmp1
  const size_t nF2 = (size_t)B_ * N1 * 256;   // fm2 / fm3
  const size_t nP2 = (size_t)B_ * N2 * 256;   // fmp2
  const size_t nF4 = (size_t)B_ * N2 * 512;
  const size_t nFg = (size_t)B_ * 512;
  const size_t nW1 = (size_t)512 * 1792;
  const size_t nW2 = (size_t)512 * 512;
  const size_t nH1 = (size_t)B_ * N0 * 512;
  ushort_t* f0h = (ushort_t*)alloc(nF0 * 2); ushort_t* f0l = (ushort_t*)alloc(nF0 * 2);
  ushort_t* f1h = (ushort_t*)alloc(nF0 * 2); ushort_t* f1l = (ushort_t*)alloc(nF0 * 2);
  ushort_t* p1h = (ushort_t*)alloc(nP1 * 2); ushort_t* p1l = (ushort_t*)alloc(nP1 * 2);
  ushort_t* f2h = (ushort_t*)alloc(nF2 * 2); ushort_t* f2l = (ushort_t*)alloc(nF2 * 2);
  ushort_t* f3h = (ushort_t*)alloc(nF2 * 2); ushort_t* f3l = (ushort_t*)alloc(nF2 * 2);
  ushort_t* p2h = (ushort_t*)alloc(nP2 * 2); ushort_t* p2l = (ushort_t*)alloc(nP2 * 2);
  ushort_t* f4h = (ushort_t*)alloc(nF4 * 2); ushort_t* f4l = (ushort_t*)alloc(nF4 * 2);
  ushort_t* fgh = (ushort_t*)alloc(nFg * 2); ushort_t* fgl = (ushort_t*)alloc(nFg * 2);
  ushort_t* w1h = (ushort_t*)alloc(nW1 * 2); ushort_t* w1l = (ushort_t*)alloc(nW1 * 2);
  ushort_t* w2h = (ushort_t*)alloc(nW2 * 2); ushort_t* w2l = (ushort_t*)alloc(nW2 * 2);
  ushort_t* h1h = (ushort_t*)alloc(nH1 * 2); ushort_t* h1l = (ushort_t*)alloc(nH1 * 2);
  ushort_t* w1th = (ushort_t*)alloc((size_t)256 * 128 * 2);
  ushort_t* w1tl = (ushort_t*)alloc((size_t)256 * 128 * 2);
  ushort_t* w2th = (ushort_t*)alloc((size_t)512 * 128 * 2);
  ushort_t* w2tl = (ushort_t*)alloc((size_t)512 * 128 * 2);
  ushort_t* w3th = (ushort_t*)alloc((size_t)512 * 256 * 2);
  ushort_t* w3tl = (ushort_t*)alloc((size_t)512 * 256 * 2);
  ushort_t* w4th = (ushort_t*)alloc((size_t)1024 * 256 * 2);
  ushort_t* w4tl = (ushort_t*)alloc((size_t)1024 * 256 * 2);

  const dim3 blk256(256), blk512(512);
  auto mgemm = [&](const ushort_t* Ah, const ushort_t* Al,
                   const ushort_t* Bh, const ushort_t* Bl, const float* bias,
                   int M, int Nn, int K, float* outF) {
    const dim3 grid(Nn / 128, M / 128);
    mfma_gemm_kernel<false, false, false><<<grid, blk256, 0, stream>>>(
        Ah, Al, nullptr, nullptr, nullptr, nullptr, nullptr, nullptr, nullptr,
        nullptr, nullptr, nullptr, nullptr, nullptr, nullptr, nullptr,
        Bh, Bl, bias, K, outF, nullptr, nullptr, Nn);
  };

  // ---- weight prep: single fused dispatch ----
  weight_prep_kernel<<<dim3(6528), blk256, 0, stream>>>(
      w1, w2, w3, w4, cw1, cw2,
      w1th, w1tl, w2th, w2tl, w3th, w3tl, w4th, w4tl,
      w1h, w1l, w2h, w2l);

  // ---- level 0 (4096 verts) ----
  knn_wave_kernel<32, 2048><<<dim3(N0 / 8, B_), blk512, 0, stream>>>(vertices, N0, N0, nb1);
  conv_surface_kernel<<<dim3(B_ * N0), dim3(128), 0, stream>>>(
      vertices, nb1, dir0, N0, 128, f0h, f0l);
  mgemm(f0h, f0l, w1th, w1tl, b1, B_ * N0, 256, 128, fbuf);
  conv_combine_kernel<<<dim3(B_ * N0), dim3(128), 0, stream>>>(
      fbuf, nb1, d1, vertices, N0, 128, 1, f1h, f1l);

  // ---- pool 1 -> 1024 (top-4 = first 4 of nb1 rows at sidx1) ----
  gather_verts_kernel<<<dim3((B_ * N1 * 3 + 255) / 256), blk256, 0, stream>>>(vertices, sidx1, N0, N1, vp1);
  pool_kernel<<<dim3((B_ * N1 * 128 + 255) / 256), blk256, 0, stream>>>(
      f1h, f1l, nb1, sidx1, N1, N0, 128, p1h, p1l);

  // ---- level 1 (1024 verts) ----
  knn_wave_kernel<32, 1024><<<dim3(N1 / 8, B_), blk512, 0, stream>>>(vp1, N1, N1, nb2);
  mgemm(p1h, p1l, w2th, w2tl, b2, B_ * N1, 512, 128, fbuf);
  conv_combine_kernel<<<dim3(B_ * N1), dim3(256), 0, stream>>>(
      fbuf, nb2, d2, vp1, N1, 256, 1, f2h, f2l);
  mgemm(f2h, f2l, w3th, w3tl, b3, B_ * N1, 512, 256, fbuf);
  conv_combine_kernel<<<dim3(B_ * N1), dim3(256), 0, stream>>>(
      fbuf, nb2, d3, vp1, N1, 256, 1, f3h, f3l);

  // ---- pool 2 -> 256 ----
  gather_verts_kernel<<<dim3((B_ * N2 * 3 + 255) / 256), blk256, 0, stream>>>(vp1, sidx2, N1, N2, vp2);
  pool_kernel<<<dim3((B_ * N2 * 256 + 255) / 256), blk256, 0, stream>>>(
      f3h, f3l, nb2, sidx2, N2, N1, 256, p2h, p2l);

  // ---- level 2 (256 verts) ----
  knn_wave_kernel<32, 256><<<dim3(N2 / 8, B_), blk512, 0, stream>>>(vp2, N2, N2, nb3);
  mgemm(p2h, p2l, w4th, w4tl, b4, B_ * N2, 1024, 256, fbuf);
  conv_combine_kernel<<<dim3(B_ * N2), dim3(512), 0, stream>>>(
      fbuf, nb3, d4, vp2, N2, 512, 0, f4h, f4l);     // no relu on fm_4
  global_max_kernel<<<dim3((B_ * 512 + 255) / 256), blk256, 0, stream>>>(
      f4h, f4l, fgh, fgl);

  // ---- upsample indices: both levels in one dispatch ----
  nearest_dual_kernel<<<dim3((B_ * N0) / 4, 2), blk256, 0, stream>>>(
      vertices, vp1, vp2, near1, near2);

  // ---- head MLP ----
  mfma_gemm_kernel<true, true, true><<<dim3(512 / 128, (B_ * N0) / 128), blk256, 0, stream>>>(
      nullptr, nullptr,
      f0h, f0l, f1h, f1l, f2h, f2l, f3h, f3l, f4h, f4l, fgh, fgl,
      near1, near2, w1h, w1l, cb1, 1792, nullptr, h1h, h1l, 512);
  mfma_gemm_kernel<false, false, true><<<dim3(512 / 128, (B_ * N0) / 128), blk256, 0, stream>>>(
      h1h, h1l,
      nullptr, nullptr, nullptr, nullptr, nullptr, nullptr, nullptr, nullptr,
      nullptr, nullptr, nullptr, nullptr,
      nullptr, nullptr, w2h, w2l, cb2, 512, h2, nullptr, nullptr, 512);
  head_kernel<<<dim3((B_ * N0 * 13 + 255) / 256), blk256, 0, stream>>>(h2, cw3, cb3, (float*)d_out);
}